// Round 6
// baseline (1702.545 us; speedup 1.0000x reference)
//
#include <hip/hip_runtime.h>
#include <math.h>

#define GF_BIAS   1
#define GF_RELU   2
#define GF_RESID  4
#define GF_POSENC 8
#define GF_F32OUT 16
#define GF_STAT   32
#define GF_SWAP   64

namespace {
constexpr int BB = 4, SS = 1024, DD = 224, FFF = 600, VV = 8000, LLl = 8;
constexpr int SD = SS * DD;  // 229376

// workspace layout, bf16 element offsets
constexpr size_t WP   = 0;                         // [256][768]
constexpr size_t WQKV = WP + (size_t)256 * 768;    // L x [704][256]
constexpr size_t WO   = WQKV + (size_t)LLl * 704 * 256;
constexpr size_t W1T  = WO + (size_t)LLl * 256 * 256;
constexpr size_t W2T  = W1T + (size_t)LLl * 640 * 256;
constexpr size_t W3T  = W2T + (size_t)LLl * 640 * 640;
constexpr size_t WFT  = W3T + (size_t)LLl * 256 * 640;   // [8064][256]
constexpr size_t HB   = WFT + (size_t)8064 * 256;
constexpr size_t H2B  = HB + (size_t)4096 * 256;
constexpr size_t OBUF = H2B + (size_t)4096 * 256;
constexpr size_t BIG  = OBUF + (size_t)4096 * 256;       // xb | qkv | f1,f2
constexpr size_t ENDB = BIG + (size_t)2 * 4096 * 640;
constexpr size_t FBYTE = ENDB * 2;                       // float region byte offset
}

using short8 = __attribute__((ext_vector_type(8))) short;
using f32x4  = __attribute__((ext_vector_type(4))) float;

__device__ __forceinline__ float bits2f(unsigned u) {
  union { unsigned u; float f; } v; v.u = u; return v.f;
}
__device__ __forceinline__ unsigned short f2b(float f) {
  union { float f; unsigned u; } v; v.f = f;
  unsigned r = v.u + 0x7FFFu + ((v.u >> 16) & 1u);
  return (unsigned short)(r >> 16);
}
__device__ __forceinline__ float b2f(unsigned short b) {
  return bits2f((unsigned)b << 16);
}

// ---------------------------------------------------------------------------
// bf16 MFMA GEMM: C[M,Npad] = A[M,Kp] @ Bt[Npad,Kp]^T, epilogue fused.
// 256 thr = 4 waves (2x2), 16x16x32 fragments. BK=128: LDS tiles [R][128] bf16
// (256 B row stride), XOR-swizzled (byte ^= (row&7)<<4), reg double-buffer.
// 4 kh sub-steps (32-64 MFMA) per barrier pair. C written via LDS stage.
// ---------------------------------------------------------------------------
template <int BM, int BN, int FLAGS>
__global__ __launch_bounds__(256) void gemm_mfma(
    const unsigned short* __restrict__ A, const unsigned short* __restrict__ Bt,
    const float* __restrict__ bias, const unsigned short* __restrict__ Rz,
    void* __restrict__ Cout, int Kp, int N, int ldc, float* __restrict__ statOut)
{
  constexpr int MR = BM / 32, NR = BN / 32;
  constexpr int APT = BM / 16, BPT = BN / 16;      // uint4 loads per thread
  constexpr int ABY = BM * 256, BBY = BN * 256;    // bytes (BK=128)
  constexpr int CBY = (FLAGS & GF_F32OUT) ? (64 * (BN + 4) * 4) : (BM * (BN + 8) * 2);
  constexpr int SBY = (ABY + BBY) > CBY ? (ABY + BBY) : CBY;
  __shared__ __align__(16) char smem[SBY];
  __shared__ float red[8];
  unsigned short* sA = (unsigned short*)smem;
  unsigned short* sB = (unsigned short*)(smem + ABY);
  const int t = threadIdx.x;
  const int l = t & 63;
  const int w = t >> 6, wr = w >> 1, wc = w & 1;
  const int m0 = ((FLAGS & GF_SWAP) ? blockIdx.x : blockIdx.y) * BM;
  const int n0 = ((FLAGS & GF_SWAP) ? blockIdx.y : blockIdx.x) * BN;
  const int nk = Kp >> 7;

  int aoff[APT], ar[APT], ac[APT];
#pragma unroll
  for (int p = 0; p < APT; ++p) {
    int off = (t + p * 256) * 16;
    int r = off >> 8;
    int cb = (off & 255) ^ ((r & 7) << 4);
    aoff[p] = off; ar[p] = r; ac[p] = cb >> 1;
  }
  int boff[BPT], br[BPT], bc[BPT];
#pragma unroll
  for (int p = 0; p < BPT; ++p) {
    int off = (t + p * 256) * 16;
    int r = off >> 8;
    int cb = (off & 255) ^ ((r & 7) << 4);
    boff[p] = off; br[p] = r; bc[p] = cb >> 1;
  }

  const unsigned short* Ab = A + (size_t)m0 * Kp;
  const unsigned short* Bb = Bt + (size_t)n0 * Kp;

  uint4 ra[APT], rb[BPT];
#pragma unroll
  for (int p = 0; p < APT; ++p) ra[p] = *(const uint4*)(Ab + (size_t)ar[p] * Kp + ac[p]);
#pragma unroll
  for (int p = 0; p < BPT; ++p) rb[p] = *(const uint4*)(Bb + (size_t)br[p] * Kp + bc[p]);

  f32x4 acc[MR][NR];
#pragma unroll
  for (int i = 0; i < MR; ++i)
#pragma unroll
    for (int j = 0; j < NR; ++j) acc[i][j] = {0.f, 0.f, 0.f, 0.f};

  for (int kt = 0; kt < nk; ++kt) {
#pragma unroll
    for (int p = 0; p < APT; ++p) *(uint4*)((char*)sA + aoff[p]) = ra[p];
#pragma unroll
    for (int p = 0; p < BPT; ++p) *(uint4*)((char*)sB + boff[p]) = rb[p];
    __syncthreads();
    if (kt + 1 < nk) {
      const int k1 = (kt + 1) * 128;
#pragma unroll
      for (int p = 0; p < APT; ++p) ra[p] = *(const uint4*)(Ab + (size_t)ar[p] * Kp + k1 + ac[p]);
#pragma unroll
      for (int p = 0; p < BPT; ++p) rb[p] = *(const uint4*)(Bb + (size_t)br[p] * Kp + k1 + bc[p]);
    }
#pragma unroll
    for (int kh = 0; kh < 4; ++kh) {
      short8 af[MR], bfg[NR];
#pragma unroll
      for (int mi = 0; mi < MR; ++mi) {
        const int row = wr * (BM / 2) + mi * 16 + (l & 15);
        const int byte = row * 256 + ((kh * 64 + (l >> 4) * 16) ^ ((row & 7) << 4));
        af[mi] = *(const short8*)((const char*)sA + byte);
      }
#pragma unroll
      for (int ni = 0; ni < NR; ++ni) {
        const int row = wc * (BN / 2) + ni * 16 + (l & 15);
        const int byte = row * 256 + ((kh * 64 + (l >> 4) * 16) ^ ((row & 7) << 4));
        bfg[ni] = *(const short8*)((const char*)sB + byte);
      }
#pragma unroll
      for (int mi = 0; mi < MR; ++mi)
#pragma unroll
        for (int ni = 0; ni < NR; ++ni)
          acc[mi][ni] = __builtin_amdgcn_mfma_f32_16x16x32_bf16(af[mi], bfg[ni], acc[mi][ni], 0, 0, 0);
    }
    __syncthreads();
  }

  const int cl = l & 15, rl0 = (l >> 4) * 4;

  if constexpr ((FLAGS & GF_F32OUT) != 0) {
    constexpr int CST = BN + 4;
    float* Cs = (float*)smem;
    constexpr int NCH = BM / 64;
#pragma unroll
    for (int c = 0; c < NCH; ++c) {
      __syncthreads();
      if ((wr * (BM / 2)) / 64 == c) {
#pragma unroll
        for (int mi = 0; mi < MR; ++mi)
#pragma unroll
          for (int ni = 0; ni < NR; ++ni)
#pragma unroll
            for (int j = 0; j < 4; ++j) {
              const int rl = wr * (BM / 2) + mi * 16 + rl0 + j - c * 64;
              const int cc = wc * (BN / 2) + ni * 16 + cl;
              const int gn = n0 + cc;
              float v = acc[mi][ni][j];
              if ((FLAGS & GF_BIAS) && gn < N) v += bias[gn];
              Cs[rl * CST + cc] = v;
            }
      }
      __syncthreads();
      // conflict-free contiguous-chunk readout (64 consecutive 16B chunks/wave)
      constexpr int CPR = BN / 4;          // 16B chunks per row
      constexpr int NIT = (64 * CPR) / 256;
#pragma unroll
      for (int i = 0; i < NIT; ++i) {
        const int ch = i * 256 + t;
        const int rr = ch / CPR, c4 = ch % CPR;
        const int gn = n0 + c4 * 4;
        const size_t gmr = (size_t)(m0 + c * 64 + rr);
        if (gn + 3 < N) {
          *(float4*)&((float*)Cout)[gmr * ldc + gn] = *(const float4*)&Cs[rr * CST + c4 * 4];
        } else {
#pragma unroll
          for (int c2 = 0; c2 < 4; ++c2)
            if (gn + c2 < N) ((float*)Cout)[gmr * ldc + gn + c2] = Cs[rr * CST + c4 * 4 + c2];
        }
      }
    }
  } else {
    constexpr int CST = BN + 8;
    unsigned short* Cs = (unsigned short*)smem;
    float lsum = 0.f, lsq = 0.f;
#pragma unroll
    for (int mi = 0; mi < MR; ++mi)
#pragma unroll
      for (int ni = 0; ni < NR; ++ni)
#pragma unroll
        for (int j = 0; j < 4; ++j) {
          const int rl = wr * (BM / 2) + mi * 16 + rl0 + j;
          const int cc = wc * (BN / 2) + ni * 16 + cl;
          const int gm = m0 + rl, gn = n0 + cc;
          float v = acc[mi][ni][j];
          if ((FLAGS & GF_BIAS) && gn < N) v += bias[gn];
          if (FLAGS & GF_RESID) v += b2f(Rz[(size_t)gm * ldc + gn]);
          if ((FLAGS & GF_POSENC) && gn < N) {
            const int srow = gm & (SS - 1);
            float freq = expf(-(2.0f * gn / 224.0f) * 9.210340371976184f);
            float ang = (float)srow * freq;
            v += (gn & 1) ? cosf(ang) : sinf(ang);
          }
          if (FLAGS & GF_RELU) v = fmaxf(v, 0.f);
          if ((FLAGS & GF_STAT) && gn < N) { lsum += v; lsq += v * v; }
          Cs[rl * CST + cc] = f2b(v);
        }
    __syncthreads();
#pragma unroll
    for (int it = 0; it < BM / 32; ++it) {
      const int rr = it * 32 + (t >> 3), qq = t & 7;
      const size_t gm = (size_t)(m0 + rr);
      *(uint4*)&((unsigned short*)Cout)[gm * ldc + n0 + qq * 8] =
          *(const uint4*)&Cs[rr * CST + qq * 8];
    }
    if constexpr ((FLAGS & GF_STAT) != 0) {
#pragma unroll
      for (int o2 = 32; o2 > 0; o2 >>= 1) {
        lsum += __shfl_down(lsum, o2); lsq += __shfl_down(lsq, o2);
      }
      if (l == 0) { red[w * 2] = lsum; red[w * 2 + 1] = lsq; }
      __syncthreads();
      if (t == 0) {
        float* so = statOut + ((m0 >> 10) << 1);
        atomicAdd(&so[0], red[0] + red[2] + red[4] + red[6]);
        atomicAdd(&so[1], red[1] + red[3] + red[5] + red[7]);
      }
    }
  }
}

__global__ void zero_stats(float* __restrict__ st)
{
  if (threadIdx.x < 128) st[threadIdx.x] = 0.f;
}

// ---------------------------------------------------------------------------
// Weight prep via LDS 32x32 transpose: fp32 [K][N] -> bf16 [Np][Kp] padded.
// ---------------------------------------------------------------------------
__global__ __launch_bounds__(256) void prep_wt2(
    const float* __restrict__ W, unsigned short* __restrict__ O,
    int K, int N, int Kp, int Np, size_t sW, size_t sO)
{
  const int ll = blockIdx.y;
  const int tx = Np >> 5;
  const int tn = blockIdx.x % tx, tk = blockIdx.x / tx;
  const int n0 = tn * 32, k0 = tk * 32;
  const float* Wl = W + sW * ll;
  unsigned short* Ol = O + sO * ll;
  __shared__ float T[32][36];
  {
    const int r = threadIdx.x >> 3, c4 = (threadIdx.x & 7) * 4;
    const int k = k0 + r, n = n0 + c4;
    float4 v = make_float4(0.f, 0.f, 0.f, 0.f);
    if (k < K) {
      if (n + 3 < N) v = *(const float4*)&Wl[(size_t)k * N + n];
      else {
        if (n + 0 < N) v.x = Wl[(size_t)k * N + n + 0];
        if (n + 1 < N) v.y = Wl[(size_t)k * N + n + 1];
        if (n + 2 < N) v.z = Wl[(size_t)k * N + n + 2];
        if (n + 3 < N) v.w = Wl[(size_t)k * N + n + 3];
      }
    }
    *(float4*)&T[r][c4] = v;
  }
  __syncthreads();
  {
    const int nl = threadIdx.x >> 3, k4 = (threadIdx.x & 7) * 4;
    ushort4 u;
    u.x = f2b(T[k4 + 0][nl]); u.y = f2b(T[k4 + 1][nl]);
    u.z = f2b(T[k4 + 2][nl]); u.w = f2b(T[k4 + 3][nl]);
    *(ushort4*)&Ol[(size_t)(n0 + nl) * Kp + k0 + k4] = u;
  }
}

// Coalesced-read qkv weight repack (thread = source linear index; dest region
// pre-zeroed by hipMemsetAsync so pads stay 0).
__global__ void prep_wqkv(const float* __restrict__ Wq, const float* __restrict__ Wk,
                          const float* __restrict__ Wv, const float* __restrict__ bq,
                          const float* __restrict__ bk, const float* __restrict__ bv,
                          unsigned short* __restrict__ O, float* __restrict__ bcat)
{
  const int idx = blockIdx.x * 256 + threadIdx.x;   // over L*H*224*28
  if (idx < LLl * 8 * 224 * 28) {
    const int kk = idx % 28;
    const int d  = (idx / 28) % 224;
    const int h  = (idx / (28 * 224)) % 8;
    const int ll = idx / (28 * 224 * 8);
    const int col = h * 28 + kk;
    const size_t base = (size_t)ll * (704 * 256);
    O[base + (size_t)col * 256 + d]         = f2b(Wq[idx]);
    O[base + (size_t)(224 + col) * 256 + d] = f2b(Wk[idx]);
    O[base + (size_t)(448 + col) * 256 + d] = f2b(Wv[idx]);
  }
  if (idx < LLl * 8 * 28) {
    const int kk = idx % 28;
    const int h  = (idx / 28) % 8;
    const int ll = idx / (28 * 8);
    const int col = h * 28 + kk;
    bcat[ll * 672 + col]       = bq[idx];
    bcat[ll * 672 + 224 + col] = bk[idx];
    bcat[ll * 672 + 448 + col] = bv[idx];
  }
}

__global__ void prep_x(const float* __restrict__ x, unsigned short* __restrict__ xb)
{
  const size_t i = ((size_t)blockIdx.x * 256 + threadIdx.x) * 4;
  float4 v = *(const float4*)(x + i);
  ushort4 o;
  o.x = f2b(v.x); o.y = f2b(v.y); o.z = f2b(v.z); o.w = f2b(v.w);
  *(ushort4*)(xb + i) = o;
}

// ---------------------------------------------------------------------------
// MFMA flash attention. Grid: (B*H, S/64), heavy-first. 4 waves x 16 q-rows.
// KV tiles of 32; DK=28 padded to one K=32 MFMA step. K/V reg-prefetched one
// tile ahead so HBM latency hides under compute.
// ---------------------------------------------------------------------------
__global__ __launch_bounds__(256) void attn_mfma(const unsigned short* __restrict__ qkv,
                                                 unsigned short* __restrict__ o)
{
  const int bh = blockIdx.x;
  const int qt = (int)gridDim.y - 1 - (int)blockIdx.y;   // heavy blocks first
  const int b = bh >> 3, h = bh & 7;
  const int tid = threadIdx.x;
  const int w = tid >> 6, l = tid & 63;
  const int cl = l & 15, g = l >> 4;
  const int qbase = qt * 64 + w * 16;
  const float scale = 0.1889822365046136f;  // 1/sqrt(28)

  __shared__ unsigned short Ks[32 * 40];
  __shared__ unsigned short Vt[32 * 40];
  __shared__ unsigned short Ps[4][16 * 40];

  // Q A-fragment: q-row = qbase+cl, d = g*8+e (d>=28 zero)
  short8 aq;
  {
    const unsigned short* qp = qkv + ((size_t)(b * SS + qbase + cl)) * 704 + h * 28;
#pragma unroll
    for (int e = 0; e < 8; ++e) {
      const int d = g * 8 + e;
      ((unsigned short*)&aq)[e] = (d < 28) ? qp[d] : (unsigned short)0;
    }
  }

  f32x4 o0 = {0.f, 0.f, 0.f, 0.f}, o1 = {0.f, 0.f, 0.f, 0.f};
  float m[4] = {-INFINITY, -INFINITY, -INFINITY, -INFINITY};
  float lsum[4] = {0.f, 0.f, 0.f, 0.f};

  const int ntiles = qt * 2 + 2;
  const int ntw = ((qbase + 15) >> 5) + 1;   // tiles this wave needs

  // staging lane assignment + prefetch of tile 0
  const int sr = tid >> 3, sc4 = (tid & 7) << 2;
  const bool sact = (sc4 < 28);
  ushort4 ku = make_ushort4(0, 0, 0, 0), vu = make_ushort4(0, 0, 0, 0);
  if (sact) {
    const unsigned short* kp = qkv + ((size_t)(b * SS + sr)) * 704 + 224 + h * 28 + sc4;
    ku = *(const ushort4*)kp;
    vu = *(const ushort4*)(kp + 224);
  }

  for (int tile = 0; tile < ntiles; ++tile) {
    const int t0 = tile * 32;
    __syncthreads();
    *(ushort4*)&Ks[sr * 40 + sc4] = ku;
    Vt[(sc4 + 0) * 40 + sr] = vu.x;
    Vt[(sc4 + 1) * 40 + sr] = vu.y;
    Vt[(sc4 + 2) * 40 + sr] = vu.z;
    Vt[(sc4 + 3) * 40 + sr] = vu.w;
    __syncthreads();
    if (tile + 1 < ntiles && sact) {
      const unsigned short* kp =
          qkv + ((size_t)(b * SS + (tile + 1) * 32 + sr)) * 704 + 224 + h * 28 + sc4;
      ku = *(const ushort4*)kp;
      vu = *(const ushort4*)(kp + 224);
    }
    if (tile >= ntw) continue;

    const short8 bk0 = *(const short8*)&Ks[cl * 40 + g * 8];
    const short8 bk1 = *(const short8*)&Ks[(cl + 16) * 40 + g * 8];
    f32x4 zz = {0.f, 0.f, 0.f, 0.f};
    f32x4 s0 = __builtin_amdgcn_mfma_f32_16x16x32_bf16(aq, bk0, zz, 0, 0, 0);
    f32x4 s1 = __builtin_amdgcn_mfma_f32_16x16x32_bf16(aq, bk1, zz, 0, 0, 0);

    const bool diag = (t0 + 31 > qbase);
#pragma unroll
    for (int jj = 0; jj < 4; ++jj) {
      float v0 = s0[jj] * scale, v1 = s1[jj] * scale;
      if (diag) {
        const int qr = qbase + g * 4 + jj;
        if (t0 + cl > qr)      v0 = -INFINITY;
        if (t0 + 16 + cl > qr) v1 = -INFINITY;
      }
      float rm = fmaxf(v0, v1);
      rm = fmaxf(rm, __shfl_xor(rm, 1));
      rm = fmaxf(rm, __shfl_xor(rm, 2));
      rm = fmaxf(rm, __shfl_xor(rm, 4));
      rm = fmaxf(rm, __shfl_xor(rm, 8));
      const float mnew = fmaxf(m[jj], rm);
      const float r2 = __expf(m[jj] - mnew);   // first tile: exp(-inf)=0
      m[jj] = mnew;
      const float e0 = __expf(v0 - mnew), e1 = __expf(v1 - mnew);
      lsum[jj] = lsum[jj] * r2 + e0 + e1;
      o0[jj] *= r2; o1[jj] *= r2;
      Ps[w][(g * 4 + jj) * 40 + cl]      = f2b(e0);
      Ps[w][(g * 4 + jj) * 40 + cl + 16] = f2b(e1);
    }
    // PV: A = P (q x kv32), B = V^T-stored tile (kv x d)
    const short8 pa  = *(const short8*)&Ps[w][cl * 40 + g * 8];
    const short8 bv0 = *(const short8*)&Vt[cl * 40 + g * 8];
    const short8 bv1 = *(const short8*)&Vt[(cl + 16) * 40 + g * 8];
    o0 = __builtin_amdgcn_mfma_f32_16x16x32_bf16(pa, bv0, o0, 0, 0, 0);
    o1 = __builtin_amdgcn_mfma_f32_16x16x32_bf16(pa, bv1, o1, 0, 0, 0);
  }

#pragma unroll
  for (int jj = 0; jj < 4; ++jj) {
    float ls = lsum[jj];
    ls += __shfl_xor(ls, 1);
    ls += __shfl_xor(ls, 2);
    ls += __shfl_xor(ls, 4);
    ls += __shfl_xor(ls, 8);
    const float inv = 1.0f / ls;
    const int row = qbase + g * 4 + jj;
    unsigned short* op = o + ((size_t)(b * SS + row)) * 256 + h * 28;
    op[cl] = f2b(o0[jj] * inv);
    if (cl < 12) op[16 + cl] = f2b(o1[jj] * inv);
  }
}

// ---------------------------------------------------------------------------
// LayerNorm over (S,D) per batch, bf16 tensors (stride 256, 224 real cols).
// Stats come pre-reduced (2 floats per batch) from GEMM-epilogue atomics.
// ---------------------------------------------------------------------------
__global__ __launch_bounds__(256) void ln_apply(
    const unsigned short* __restrict__ x, const float* __restrict__ w,
    const float* __restrict__ bb, const float* __restrict__ st,
    unsigned short* __restrict__ y)
{
  const int b = blockIdx.x / 112;
  const float s1 = st[b * 2], s2 = st[b * 2 + 1];
  const float mu = s1 / (float)SD;
  const float rstd = rsqrtf(s2 / (float)SD - mu * mu + 1e-5f);
  const int chunk = blockIdx.x * 256 + threadIdx.x;
  const int r = chunk / 28, cc = chunk % 28;
  const int s = r & 1023;
  uint4 u = *(const uint4*)(x + (size_t)r * 256 + cc * 8);
  const float* wp = w + (size_t)s * 224 + cc * 8;
  const float* bp = bb + (size_t)s * 224 + cc * 8;
  float4 w0 = *(const float4*)wp, w1 = *(const float4*)(wp + 4);
  float4 b0 = *(const float4*)bp, b1 = *(const float4*)(bp + 4);
  float wv[8] = {w0.x, w0.y, w0.z, w0.w, w1.x, w1.y, w1.z, w1.w};
  float bv[8] = {b0.x, b0.y, b0.z, b0.w, b1.x, b1.y, b1.z, b1.w};
  const unsigned* up = (const unsigned*)&u;
  uint4 ov;
  unsigned* op = (unsigned*)&ov;
#pragma unroll
  for (int q = 0; q < 4; ++q) {
    float f0 = bits2f(up[q] << 16), f1 = bits2f(up[q] & 0xFFFF0000u);
    float y0 = (f0 - mu) * rstd * wv[q * 2] + bv[q * 2];
    float y1 = (f1 - mu) * rstd * wv[q * 2 + 1] + bv[q * 2 + 1];
    op[q] = (unsigned)f2b(y0) | ((unsigned)f2b(y1) << 16);
  }
  *(uint4*)(y + (size_t)r * 256 + cc * 8) = ov;
}

__global__ __launch_bounds__(256) void ln_part2(
    const unsigned short* __restrict__ x, const float* __restrict__ w,
    const float* __restrict__ bb, const float* __restrict__ stA,
    float* __restrict__ part2)
{
  const int b = blockIdx.y, g = blockIdx.x;
  const float s1 = stA[b * 2], s2 = stA[b * 2 + 1];
  const float mu = s1 / (float)SD;
  const float rstd = rsqrtf(s2 / (float)SD - mu * mu + 1e-5f);
  const unsigned short* base = x + ((size_t)b * 1024 + g * 16) * 256;
  float sum = 0.f, sq = 0.f;
  for (int c = threadIdx.x; c < 448; c += 256) {
    const int r = c / 28, cc = c % 28;
    const int s = g * 16 + r;
    uint4 u = *(const uint4*)(base + (size_t)r * 256 + cc * 8);
    const float* wp = w + (size_t)s * 224 + cc * 8;
    const float* bp = bb + (size_t)s * 224 + cc * 8;
    float4 w0 = *(const float4*)wp, w1 = *(const float4*)(wp + 4);
    float4 b0 = *(const float4*)bp, b1 = *(const float4*)(bp + 4);
    float wv[8] = {w0.x, w0.y, w0.z, w0.w, w1.x, w1.y, w1.z, w1.w};
    float bv[8] = {b0.x, b0.y, b0.z, b0.w, b1.x, b1.y, b1.z, b1.w};
    const unsigned* up = (const unsigned*)&u;
#pragma unroll
    for (int q = 0; q < 4; ++q) {
      float f0 = bits2f(up[q] << 16), f1 = bits2f(up[q] & 0xFFFF0000u);
      float y0 = (f0 - mu) * rstd * wv[q * 2] + bv[q * 2];
      float y1 = (f1 - mu) * rstd * wv[q * 2 + 1] + bv[q * 2 + 1];
      sum += y0 + y1; sq += y0 * y0 + y1 * y1;
    }
  }
  __shared__ float sA[4], sB[4];
#pragma unroll
  for (int o2 = 32; o2 > 0; o2 >>= 1) { sum += __shfl_down(sum, o2); sq += __shfl_down(sq, o2); }
  if ((threadIdx.x & 63) == 0) { sA[threadIdx.x >> 6] = sum; sB[threadIdx.x >> 6] = sq; }
  __syncthreads();
  if (threadIdx.x == 0) {
    part2[((size_t)b * 64 + g) * 2] = sA[0] + sA[1] + sA[2] + sA[3];
    part2[((size_t)b * 64 + g) * 2 + 1] = sB[0] + sB[1] + sB[2] + sB[3];
  }
}

__global__ __launch_bounds__(256) void ln_apply2(
    const unsigned short* __restrict__ x, const float* __restrict__ w,
    const float* __restrict__ bb, const float* __restrict__ stA,
    const float* __restrict__ part2, unsigned short* __restrict__ y)
{
  __shared__ float sh[2];
  const int tid = threadIdx.x;
  const int b = blockIdx.x / 112;
  const float s1 = stA[b * 2], s2 = stA[b * 2 + 1];
  const float mu1 = s1 / (float)SD;
  const float rs1 = rsqrtf(s2 / (float)SD - mu1 * mu1 + 1e-5f);
  if (tid < 64) {
    float p1 = part2[((size_t)b * 64 + tid) * 2];
    float p2 = part2[((size_t)b * 64 + tid) * 2 + 1];
#pragma unroll
    for (int o2 = 32; o2 > 0; o2 >>= 1) { p1 += __shfl_down(p1, o2); p2 += __shfl_down(p2, o2); }
    if (tid == 0) {
      float m2 = p1 / (float)SD;
      sh[0] = m2; sh[1] = rsqrtf(p2 / (float)SD - m2 * m2 + 1e-5f);
    }
  }
  __syncthreads();
  const float mu2 = sh[0], rs2 = sh[1];
  const int chunk = blockIdx.x * 256 + tid;
  const int r = chunk / 28, cc = chunk % 28;
  const int s = r & 1023;
  uint4 u = *(const uint4*)(x + (size_t)r * 256 + cc * 8);
  const float* wp = w + (size_t)s * 224 + cc * 8;
  const float* bp = bb + (size_t)s * 224 + cc * 8;
  float4 w0 = *(const float4*)wp, w1 = *(const float4*)(wp + 4);
  float4 b0 = *(const float4*)bp, b1 = *(const float4*)(bp + 4);
  float wv[8] = {w0.x, w0.y, w0.z, w0.w, w1.x, w1.y, w1.z, w1.w};
  float bv[8] = {b0.x, b0.y, b0.z, b0.w, b1.x, b1.y, b1.z, b1.w};
  const unsigned* up = (const unsigned*)&u;
  uint4 ov;
  unsigned* op = (unsigned*)&ov;
#pragma unroll
  for (int q = 0; q < 4; ++q) {
    float f0 = bits2f(up[q] << 16), f1 = bits2f(up[q] & 0xFFFF0000u);
    float y0 = (f0 - mu1) * rs1 * wv[q * 2] + bv[q * 2];
    float y1 = (f1 - mu1) * rs1 * wv[q * 2 + 1] + bv[q * 2 + 1];
    float z0 = (y0 - mu2) * rs2 * wv[q * 2] + bv[q * 2];
    float z1 = (y1 - mu2) * rs2 * wv[q * 2 + 1] + bv[q * 2 + 1];
    op[q] = (unsigned)f2b(z0) | ((unsigned)f2b(z1) << 16);
  }
  *(uint4*)(y + (size_t)r * 256 + cc * 8) = ov;
}

// ---------------------------------------------------------------------------
// Row softmax over V=8000, in place on d_out (fp32).
// ---------------------------------------------------------------------------
__global__ __launch_bounds__(256) void softmax_rows(float* __restrict__ logits)
{
  const int row = blockIdx.x;
  float* p = logits + (size_t)row * VV;
  __shared__ float buf[VV];
  __shared__ float red[4];
  const int tid = threadIdx.x;

  float mx = -INFINITY;
  for (int i = tid; i < VV; i += 256) { float v = p[i]; buf[i] = v; mx = fmaxf(mx, v); }
#pragma unroll
  for (int o2 = 32; o2 > 0; o2 >>= 1) mx = fmaxf(mx, __shfl_down(mx, o2));
  if ((tid & 63) == 0) red[tid >> 6] = mx;
  __syncthreads();
  mx = fmaxf(fmaxf(red[0], red[1]), fmaxf(red[2], red[3]));
  __syncthreads();

  float s = 0.f;
  for (int i = tid; i < VV; i += 256) { float e = __expf(buf[i] - mx); buf[i] = e; s += e; }
#pragma unroll
  for (int o2 = 32; o2 > 0; o2 >>= 1) s += __shfl_down(s, o2);
  if ((tid & 63) == 0) red[tid >> 6] = s;
  __syncthreads();
  s = red[0] + red[1] + red[2] + red[3];
  const float inv = 1.0f / s;
  for (int i = tid; i < VV; i += 256) p[i] = buf[i] * inv;
}

// ---------------------------------------------------------------------------
extern "C" void kernel_launch(void* const* d_in, const int* in_sizes, int n_in,
                              void* d_out, int out_size, void* d_ws, size_t ws_size,
                              hipStream_t stream) {
  const float* x   = (const float*)d_in[0];
  const float* Wp  = (const float*)d_in[1];
  const float* bp  = (const float*)d_in[2];
  const float* Wq  = (const float*)d_in[3];
  const float* bq  = (const float*)d_in[4];
  const float* Wk  = (const float*)d_in[5];
  const float* bk  = (const float*)d_in[6];
  const float* Wv  = (const float*)d_in[7];
  const float* bv  = (const float*)d_in[8];
  const float* Wo  = (const float*)d_in[9];
  const float* bo  = (const float*)d_in[10];
  const float* W1  = (const float*)d_in[11];
  const float* b1  = (const float*)d_in[12];
  const float* W2  = (const float*)d_in[13];
  const float* b2  = (const float*)d_in[14];
  const float* W3  = (const float*)d_in[15];
  const float* b3  = (const float*)d_in[16];
  const float* lnw = (const float*)d_in[17];
  const float* lnb = (const float*)d_in[18];
  const float* Wf  = (const float*)d_in[19];
  const float* bf  = (const float*)d_in[20];

  unsigned short* wsb = (unsigned short*)d_ws;
  unsigned short* wpT   = wsb + WP;
  unsigned short* wqkvT = wsb + WQKV;
  unsigned short* woT   = wsb + WO;
  unsigned short* w1T   = wsb + W1T;
  unsigned short* w2T   = wsb + W2T;
  unsigned short* w3T   = wsb + W3T;
  unsigned short* wfT   = wsb + WFT;
  unsigned short* h     = wsb + HB;
  unsigned short* h2    = wsb + H2B;
  unsigned short* obuf  = wsb + OBUF;
  unsigned short* xb    = wsb + BIG;
  unsigned short* qkvb  = wsb + BIG;
  unsigned short* f1    = wsb + BIG;
  unsigned short* f2    = wsb + BIG + (size_t)4096 * 640;
  float* bcat  = (float*)((char*)d_ws + FBYTE);
  float* part2 = bcat + LLl * 672;
  float* stats = part2 + 512;     // 128 floats: 8 layers x 2 slots x (4 batches x 2)

  // ---- prep ----
  zero_stats<<<1, 128, 0, stream>>>(stats);
  hipMemsetAsync(wqkvT, 0, (size_t)LLl * 704 * 256 * 2, stream);
  prep_x<<<3072, 256, 0, stream>>>(x, xb);
  prep_wt2<<<dim3(192, 1), 256, 0, stream>>>(Wp, wpT, 768, 224, 768, 256, 0, 0);
  prep_wqkv<<<dim3(1568, 1), 256, 0, stream>>>(Wq, Wk, Wv, bq, bk, bv, wqkvT, bcat);
  prep_wt2<<<dim3(64, 8), 256, 0, stream>>>(Wo, woT, 224, 224, 256, 256,
                                            (size_t)224 * 224, (size_t)256 * 256);
  prep_wt2<<<dim3(160, 8), 256, 0, stream>>>(W1, w1T, 224, 600, 256, 640,
                                             (size_t)224 * 600, (size_t)640 * 256);
  prep_wt2<<<dim3(400, 8), 256, 0, stream>>>(W2, w2T, 600, 600, 640, 640,
                                             (size_t)600 * 600, (size_t)640 * 640);
  prep_wt2<<<dim3(160, 8), 256, 0, stream>>>(W3, w3T, 600, 224, 640, 256,
                                             (size_t)600 * 224, (size_t)256 * 640);
  prep_wt2<<<dim3(2016, 1), 256, 0, stream>>>(Wf, wfT, 224, 8000, 256, 8064, 0, 0);

  // ---- proj + posenc: h = x @ Wp + bp + pe ----
  gemm_mfma<64, 64, GF_BIAS | GF_POSENC><<<dim3(4, 64), 256, 0, stream>>>(
      xb, wpT, bp, nullptr, h, 768, 224, 256, nullptr);

  for (int l = 0; l < LLl; ++l) {
    float* stA = stats + (size_t)(l * 2) * 8;
    float* stB = stats + (size_t)(l * 2 + 1) * 8;
    gemm_mfma<128, 64, GF_BIAS><<<dim3(11, 32), 256, 0, stream>>>(
        h, wqkvT + (size_t)l * 704 * 256, bcat + l * 672, nullptr, qkvb, 256, 672, 704, nullptr);
    attn_mfma<<<dim3(BB * 8, SS / 64), 256, 0, stream>>>(qkvb, obuf);
    gemm_mfma<64, 64, GF_BIAS | GF_RESID | GF_STAT><<<dim3(4, 64), 256, 0, stream>>>(
        obuf, woT + (size_t)l * 256 * 256, bo + (size_t)l * 224, h, h2, 256, 224, 256, stA);
    ln_apply<<<448, 256, 0, stream>>>(h2, lnw + (size_t)l * SD, lnb + (size_t)l * SD, stA, h);
    gemm_mfma<128, 64, GF_BIAS | GF_RELU><<<dim3(10, 32), 256, 0, stream>>>(
        h, w1T + (size_t)l * 640 * 256, b1 + (size_t)l * 600, nullptr, f1, 256, 600, 640, nullptr);
    gemm_mfma<128, 64, GF_BIAS | GF_RELU><<<dim3(10, 32), 256, 0, stream>>>(
        f1, w2T + (size_t)l * 640 * 640, b2 + (size_t)l * 600, nullptr, f2, 640, 600, 640, nullptr);
    gemm_mfma<64, 64, GF_BIAS | GF_RESID | GF_STAT><<<dim3(4, 64), 256, 0, stream>>>(
        f2, w3T + (size_t)l * 256 * 640, b3 + (size_t)l * 224, h, h2, 640, 224, 256, stB);
    ln_part2<<<dim3(64, BB), 256, 0, stream>>>(h2, lnw + (size_t)l * SD, lnb + (size_t)l * SD,
                                               stB, part2);
    ln_apply2<<<448, 256, 0, stream>>>(h2, lnw + (size_t)l * SD, lnb + (size_t)l * SD,
                                       stB, part2, h);
  }

  // ---- logits (fp32 out, m-fastest block order) + softmax ----
  gemm_mfma<128, 128, GF_BIAS | GF_F32OUT | GF_SWAP><<<dim3(32, 63), 256, 0, stream>>>(
      h, wfT, bf, nullptr, (float*)d_out, 256, 8000, 8000, nullptr);
  softmax_rows<<<4096, 256, 0, stream>>>((float*)d_out);
}

// Round 7
// 1671.879 us; speedup vs baseline: 1.0183x; 1.0183x over previous
//
#include <hip/hip_runtime.h>
#include <math.h>

#define GF_BIAS   1
#define GF_RELU   2
#define GF_RESID  4
#define GF_POSENC 8
#define GF_F32OUT 16
#define GF_STAT   32
#define GF_SWAP   64

namespace {
constexpr int BB = 4, SS = 1024, DD = 224, FFF = 600, VV = 8000, LLl = 8;
constexpr int SD = SS * DD;  // 229376

// workspace layout, bf16 element offsets
constexpr size_t WP   = 0;                         // [256][768]
constexpr size_t WQKV = WP + (size_t)256 * 768;    // L x [704][256]
constexpr size_t WO   = WQKV + (size_t)LLl * 704 * 256;
constexpr size_t W1T  = WO + (size_t)LLl * 256 * 256;
constexpr size_t W2T  = W1T + (size_t)LLl * 640 * 256;
constexpr size_t W3T  = W2T + (size_t)LLl * 640 * 640;
constexpr size_t WFT  = W3T + (size_t)LLl * 256 * 640;   // [8064][256]
constexpr size_t HB   = WFT + (size_t)8064 * 256;
constexpr size_t H2B  = HB + (size_t)4096 * 256;
constexpr size_t OBUF = H2B + (size_t)4096 * 256;
constexpr size_t BIG  = OBUF + (size_t)4096 * 256;       // xb | qkv | f1,f2
constexpr size_t ENDB = BIG + (size_t)2 * 4096 * 640;
constexpr size_t FBYTE = ENDB * 2;                       // float region byte offset
}

using short8 = __attribute__((ext_vector_type(8))) short;
using f32x4  = __attribute__((ext_vector_type(4))) float;

__device__ __forceinline__ float bits2f(unsigned u) {
  union { unsigned u; float f; } v; v.u = u; return v.f;
}
__device__ __forceinline__ unsigned short f2b(float f) {
  union { float f; unsigned u; } v; v.f = f;
  unsigned r = v.u + 0x7FFFu + ((v.u >> 16) & 1u);
  return (unsigned short)(r >> 16);
}
__device__ __forceinline__ float b2f(unsigned short b) {
  return bits2f((unsigned)b << 16);
}

// ---------------------------------------------------------------------------
// bf16 MFMA GEMM: C[M,Npad] = A[M,Kp] @ Bt[Npad,Kp]^T, epilogue fused.
// 256 thr = 4 waves (2x2), 16x16x32 fragments. BK=64: LDS tiles [R][64] bf16,
// XOR-swizzled (byte ^= (row&7)<<4), reg double-buffer. C via LDS stage.
// ---------------------------------------------------------------------------
template <int BM, int BN, int FLAGS>
__global__ __launch_bounds__(256) void gemm_mfma(
    const unsigned short* __restrict__ A, const unsigned short* __restrict__ Bt,
    const float* __restrict__ bias, const unsigned short* __restrict__ Rz,
    void* __restrict__ Cout, int Kp, int N, int ldc, float* __restrict__ statOut)
{
  constexpr int MR = BM / 32, NR = BN / 32;
  constexpr int APT = BM / 32, BPT = BN / 32;
  constexpr int ABY = BM * 128, BBY = BN * 128;   // bytes
  constexpr int CBY = (FLAGS & GF_F32OUT) ? (64 * (BN + 4) * 4) : (BM * (BN + 8) * 2);
  constexpr int SBY = (ABY + BBY) > CBY ? (ABY + BBY) : CBY;
  __shared__ __align__(16) char smem[SBY];
  __shared__ float red[8];
  unsigned short* sA = (unsigned short*)smem;
  unsigned short* sB = (unsigned short*)(smem + ABY);
  const int t = threadIdx.x;
  const int l = t & 63;
  const int w = t >> 6, wr = w >> 1, wc = w & 1;
  const int m0 = ((FLAGS & GF_SWAP) ? blockIdx.x : blockIdx.y) * BM;
  const int n0 = ((FLAGS & GF_SWAP) ? blockIdx.y : blockIdx.x) * BN;
  const int nk = Kp >> 6;

  int aoff[APT], ar[APT], ac[APT];
#pragma unroll
  for (int p = 0; p < APT; ++p) {
    int off = (t + p * 256) * 16;
    int r = off >> 7;
    int cb = (off & 127) ^ ((r & 7) << 4);
    aoff[p] = off; ar[p] = r; ac[p] = cb >> 1;
  }
  int boff[BPT], br[BPT], bc[BPT];
#pragma unroll
  for (int p = 0; p < BPT; ++p) {
    int off = (t + p * 256) * 16;
    int r = off >> 7;
    int cb = (off & 127) ^ ((r & 7) << 4);
    boff[p] = off; br[p] = r; bc[p] = cb >> 1;
  }

  const unsigned short* Ab = A + (size_t)m0 * Kp;
  const unsigned short* Bb = Bt + (size_t)n0 * Kp;

  uint4 ra[APT], rb[BPT];
#pragma unroll
  for (int p = 0; p < APT; ++p) ra[p] = *(const uint4*)(Ab + (size_t)ar[p] * Kp + ac[p]);
#pragma unroll
  for (int p = 0; p < BPT; ++p) rb[p] = *(const uint4*)(Bb + (size_t)br[p] * Kp + bc[p]);

  f32x4 acc[MR][NR];
#pragma unroll
  for (int i = 0; i < MR; ++i)
#pragma unroll
    for (int j = 0; j < NR; ++j) acc[i][j] = {0.f, 0.f, 0.f, 0.f};

  for (int kt = 0; kt < nk; ++kt) {
#pragma unroll
    for (int p = 0; p < APT; ++p) *(uint4*)((char*)sA + aoff[p]) = ra[p];
#pragma unroll
    for (int p = 0; p < BPT; ++p) *(uint4*)((char*)sB + boff[p]) = rb[p];
    __syncthreads();
    if (kt + 1 < nk) {
      const int k1 = (kt + 1) * 64;
#pragma unroll
      for (int p = 0; p < APT; ++p) ra[p] = *(const uint4*)(Ab + (size_t)ar[p] * Kp + k1 + ac[p]);
#pragma unroll
      for (int p = 0; p < BPT; ++p) rb[p] = *(const uint4*)(Bb + (size_t)br[p] * Kp + k1 + bc[p]);
    }
#pragma unroll
    for (int kh = 0; kh < 2; ++kh) {
      short8 af[MR], bfg[NR];
#pragma unroll
      for (int mi = 0; mi < MR; ++mi) {
        const int row = wr * (BM / 2) + mi * 16 + (l & 15);
        const int byte = (row * 128 + kh * 64 + (l >> 4) * 16) ^ ((row & 7) << 4);
        af[mi] = *(const short8*)((const char*)sA + byte);
      }
#pragma unroll
      for (int ni = 0; ni < NR; ++ni) {
        const int row = wc * (BN / 2) + ni * 16 + (l & 15);
        const int byte = (row * 128 + kh * 64 + (l >> 4) * 16) ^ ((row & 7) << 4);
        bfg[ni] = *(const short8*)((const char*)sB + byte);
      }
#pragma unroll
      for (int mi = 0; mi < MR; ++mi)
#pragma unroll
        for (int ni = 0; ni < NR; ++ni)
          acc[mi][ni] = __builtin_amdgcn_mfma_f32_16x16x32_bf16(af[mi], bfg[ni], acc[mi][ni], 0, 0, 0);
    }
    __syncthreads();
  }

  const int cl = l & 15, rl0 = (l >> 4) * 4;

  if constexpr ((FLAGS & GF_F32OUT) != 0) {
    constexpr int CST = BN + 4;
    float* Cs = (float*)smem;
    constexpr int NCH = BM / 64;
#pragma unroll
    for (int c = 0; c < NCH; ++c) {
      __syncthreads();
      if ((wr * (BM / 2)) / 64 == c) {
#pragma unroll
        for (int mi = 0; mi < MR; ++mi)
#pragma unroll
          for (int ni = 0; ni < NR; ++ni)
#pragma unroll
            for (int j = 0; j < 4; ++j) {
              const int rl = wr * (BM / 2) + mi * 16 + rl0 + j - c * 64;
              const int cc = wc * (BN / 2) + ni * 16 + cl;
              const int gn = n0 + cc;
              float v = acc[mi][ni][j];
              if ((FLAGS & GF_BIAS) && gn < N) v += bias[gn];
              Cs[rl * CST + cc] = v;
            }
      }
      __syncthreads();
      // conflict-free contiguous-chunk readout (64 consecutive 16B chunks/wave)
      constexpr int CPR = BN / 4;          // 16B chunks per row
      constexpr int NIT = (64 * CPR) / 256;
#pragma unroll
      for (int i = 0; i < NIT; ++i) {
        const int ch = i * 256 + t;
        const int rr = ch / CPR, c4 = ch % CPR;
        const int gn = n0 + c4 * 4;
        const size_t gmr = (size_t)(m0 + c * 64 + rr);
        if (gn + 3 < N) {
          *(float4*)&((float*)Cout)[gmr * ldc + gn] = *(const float4*)&Cs[rr * CST + c4 * 4];
        } else {
#pragma unroll
          for (int c2 = 0; c2 < 4; ++c2)
            if (gn + c2 < N) ((float*)Cout)[gmr * ldc + gn + c2] = Cs[rr * CST + c4 * 4 + c2];
        }
      }
    }
  } else {
    constexpr int CST = BN + 8;
    unsigned short* Cs = (unsigned short*)smem;
    float lsum = 0.f, lsq = 0.f;
#pragma unroll
    for (int mi = 0; mi < MR; ++mi)
#pragma unroll
      for (int ni = 0; ni < NR; ++ni)
#pragma unroll
        for (int j = 0; j < 4; ++j) {
          const int rl = wr * (BM / 2) + mi * 16 + rl0 + j;
          const int cc = wc * (BN / 2) + ni * 16 + cl;
          const int gm = m0 + rl, gn = n0 + cc;
          float v = acc[mi][ni][j];
          if ((FLAGS & GF_BIAS) && gn < N) v += bias[gn];
          if (FLAGS & GF_RESID) v += b2f(Rz[(size_t)gm * ldc + gn]);
          if ((FLAGS & GF_POSENC) && gn < N) {
            const int srow = gm & (SS - 1);
            float freq = expf(-(2.0f * gn / 224.0f) * 9.210340371976184f);
            float ang = (float)srow * freq;
            v += (gn & 1) ? cosf(ang) : sinf(ang);
          }
          if (FLAGS & GF_RELU) v = fmaxf(v, 0.f);
          if ((FLAGS & GF_STAT) && gn < N) { lsum += v; lsq += v * v; }
          Cs[rl * CST + cc] = f2b(v);
        }
    __syncthreads();
#pragma unroll
    for (int it = 0; it < BM / 32; ++it) {
      const int rr = it * 32 + (t >> 3), qq = t & 7;
      const size_t gm = (size_t)(m0 + rr);
      *(uint4*)&((unsigned short*)Cout)[gm * ldc + n0 + qq * 8] =
          *(const uint4*)&Cs[rr * CST + qq * 8];
    }
    if constexpr ((FLAGS & GF_STAT) != 0) {
#pragma unroll
      for (int o2 = 32; o2 > 0; o2 >>= 1) {
        lsum += __shfl_down(lsum, o2); lsq += __shfl_down(lsq, o2);
      }
      if (l == 0) { red[w * 2] = lsum; red[w * 2 + 1] = lsq; }
      __syncthreads();
      if (t == 0) {
        float* so = statOut + ((m0 >> 10) << 1);
        atomicAdd(&so[0], red[0] + red[2] + red[4] + red[6]);
        atomicAdd(&so[1], red[1] + red[3] + red[5] + red[7]);
      }
    }
  }
}

__global__ void zero_stats(float* __restrict__ st)
{
  if (threadIdx.x < 128) st[threadIdx.x] = 0.f;
}

// ---------------------------------------------------------------------------
// Weight prep via LDS 32x32 transpose: fp32 [K][N] -> bf16 [Np][Kp] padded.
// ---------------------------------------------------------------------------
__global__ __launch_bounds__(256) void prep_wt2(
    const float* __restrict__ W, unsigned short* __restrict__ O,
    int K, int N, int Kp, int Np, size_t sW, size_t sO)
{
  const int ll = blockIdx.y;
  const int tx = Np >> 5;
  const int tn = blockIdx.x % tx, tk = blockIdx.x / tx;
  const int n0 = tn * 32, k0 = tk * 32;
  const float* Wl = W + sW * ll;
  unsigned short* Ol = O + sO * ll;
  __shared__ float T[32][36];
  {
    const int r = threadIdx.x >> 3, c4 = (threadIdx.x & 7) * 4;
    const int k = k0 + r, n = n0 + c4;
    float4 v = make_float4(0.f, 0.f, 0.f, 0.f);
    if (k < K) {
      if (n + 3 < N) v = *(const float4*)&Wl[(size_t)k * N + n];
      else {
        if (n + 0 < N) v.x = Wl[(size_t)k * N + n + 0];
        if (n + 1 < N) v.y = Wl[(size_t)k * N + n + 1];
        if (n + 2 < N) v.z = Wl[(size_t)k * N + n + 2];
        if (n + 3 < N) v.w = Wl[(size_t)k * N + n + 3];
      }
    }
    *(float4*)&T[r][c4] = v;
  }
  __syncthreads();
  {
    const int nl = threadIdx.x >> 3, k4 = (threadIdx.x & 7) * 4;
    ushort4 u;
    u.x = f2b(T[k4 + 0][nl]); u.y = f2b(T[k4 + 1][nl]);
    u.z = f2b(T[k4 + 2][nl]); u.w = f2b(T[k4 + 3][nl]);
    *(ushort4*)&Ol[(size_t)(n0 + nl) * Kp + k0 + k4] = u;
  }
}

// Coalesced-read qkv weight repack (dest pre-zeroed so pads stay 0).
__global__ void prep_wqkv(const float* __restrict__ Wq, const float* __restrict__ Wk,
                          const float* __restrict__ Wv, const float* __restrict__ bq,
                          const float* __restrict__ bk, const float* __restrict__ bv,
                          unsigned short* __restrict__ O, float* __restrict__ bcat)
{
  const int idx = blockIdx.x * 256 + threadIdx.x;   // over L*H*224*28
  if (idx < LLl * 8 * 224 * 28) {
    const int kk = idx % 28;
    const int d  = (idx / 28) % 224;
    const int h  = (idx / (28 * 224)) % 8;
    const int ll = idx / (28 * 224 * 8);
    const int col = h * 28 + kk;
    const size_t base = (size_t)ll * (704 * 256);
    O[base + (size_t)col * 256 + d]         = f2b(Wq[idx]);
    O[base + (size_t)(224 + col) * 256 + d] = f2b(Wk[idx]);
    O[base + (size_t)(448 + col) * 256 + d] = f2b(Wv[idx]);
  }
  if (idx < LLl * 8 * 28) {
    const int kk = idx % 28;
    const int h  = (idx / 28) % 8;
    const int ll = idx / (28 * 8);
    const int col = h * 28 + kk;
    bcat[ll * 672 + col]       = bq[idx];
    bcat[ll * 672 + 224 + col] = bk[idx];
    bcat[ll * 672 + 448 + col] = bv[idx];
  }
}

__global__ void prep_x(const float* __restrict__ x, unsigned short* __restrict__ xb)
{
  const size_t i = ((size_t)blockIdx.x * 256 + threadIdx.x) * 4;
  float4 v = *(const float4*)(x + i);
  ushort4 o;
  o.x = f2b(v.x); o.y = f2b(v.y); o.z = f2b(v.z); o.w = f2b(v.w);
  *(ushort4*)(xb + i) = o;
}

// ---------------------------------------------------------------------------
// MFMA flash attention. Grid: (B*H, S/64), heavy-first. 4 waves x 16 q-rows.
// KV tiles of 32; DK=28 padded to one K=32 MFMA step. K/V reg-prefetched one
// tile ahead so HBM latency hides under compute.
// ---------------------------------------------------------------------------
__global__ __launch_bounds__(256) void attn_mfma(const unsigned short* __restrict__ qkv,
                                                 unsigned short* __restrict__ o)
{
  const int bh = blockIdx.x;
  const int qt = (int)gridDim.y - 1 - (int)blockIdx.y;   // heavy blocks first
  const int b = bh >> 3, h = bh & 7;
  const int tid = threadIdx.x;
  const int w = tid >> 6, l = tid & 63;
  const int cl = l & 15, g = l >> 4;
  const int qbase = qt * 64 + w * 16;
  const float scale = 0.1889822365046136f;  // 1/sqrt(28)

  __shared__ unsigned short Ks[32 * 40];
  __shared__ unsigned short Vt[32 * 40];
  __shared__ unsigned short Ps[4][16 * 40];

  // Q A-fragment: q-row = qbase+cl, d = g*8+e (d>=28 zero)
  short8 aq;
  {
    const unsigned short* qp = qkv + ((size_t)(b * SS + qbase + cl)) * 704 + h * 28;
#pragma unroll
    for (int e = 0; e < 8; ++e) {
      const int d = g * 8 + e;
      ((unsigned short*)&aq)[e] = (d < 28) ? qp[d] : (unsigned short)0;
    }
  }

  f32x4 o0 = {0.f, 0.f, 0.f, 0.f}, o1 = {0.f, 0.f, 0.f, 0.f};
  float m[4] = {-INFINITY, -INFINITY, -INFINITY, -INFINITY};
  float lsum[4] = {0.f, 0.f, 0.f, 0.f};

  const int ntiles = qt * 2 + 2;
  const int ntw = ((qbase + 15) >> 5) + 1;   // tiles this wave needs

  // staging lane assignment + prefetch of tile 0
  const int sr = tid >> 3, sc4 = (tid & 7) << 2;
  const bool sact = (sc4 < 28);
  ushort4 ku = make_ushort4(0, 0, 0, 0), vu = make_ushort4(0, 0, 0, 0);
  if (sact) {
    const unsigned short* kp = qkv + ((size_t)(b * SS + sr)) * 704 + 224 + h * 28 + sc4;
    ku = *(const ushort4*)kp;
    vu = *(const ushort4*)(kp + 224);
  }

  for (int tile = 0; tile < ntiles; ++tile) {
    const int t0 = tile * 32;
    __syncthreads();
    *(ushort4*)&Ks[sr * 40 + sc4] = ku;
    Vt[(sc4 + 0) * 40 + sr] = vu.x;
    Vt[(sc4 + 1) * 40 + sr] = vu.y;
    Vt[(sc4 + 2) * 40 + sr] = vu.z;
    Vt[(sc4 + 3) * 40 + sr] = vu.w;
    __syncthreads();
    if (tile + 1 < ntiles && sact) {
      const unsigned short* kp =
          qkv + ((size_t)(b * SS + (tile + 1) * 32 + sr)) * 704 + 224 + h * 28 + sc4;
      ku = *(const ushort4*)kp;
      vu = *(const ushort4*)(kp + 224);
    }
    if (tile >= ntw) continue;

    const short8 bk0 = *(const short8*)&Ks[cl * 40 + g * 8];
    const short8 bk1 = *(const short8*)&Ks[(cl + 16) * 40 + g * 8];
    f32x4 zz = {0.f, 0.f, 0.f, 0.f};
    f32x4 s0 = __builtin_amdgcn_mfma_f32_16x16x32_bf16(aq, bk0, zz, 0, 0, 0);
    f32x4 s1 = __builtin_amdgcn_mfma_f32_16x16x32_bf16(aq, bk1, zz, 0, 0, 0);

    const bool diag = (t0 + 31 > qbase);
#pragma unroll
    for (int jj = 0; jj < 4; ++jj) {
      float v0 = s0[jj] * scale, v1 = s1[jj] * scale;
      if (diag) {
        const int qr = qbase + g * 4 + jj;
        if (t0 + cl > qr)      v0 = -INFINITY;
        if (t0 + 16 + cl > qr) v1 = -INFINITY;
      }
      float rm = fmaxf(v0, v1);
      rm = fmaxf(rm, __shfl_xor(rm, 1));
      rm = fmaxf(rm, __shfl_xor(rm, 2));
      rm = fmaxf(rm, __shfl_xor(rm, 4));
      rm = fmaxf(rm, __shfl_xor(rm, 8));
      const float mnew = fmaxf(m[jj], rm);
      const float r2 = __expf(m[jj] - mnew);   // first tile: exp(-inf)=0
      m[jj] = mnew;
      const float e0 = __expf(v0 - mnew), e1 = __expf(v1 - mnew);
      lsum[jj] = lsum[jj] * r2 + e0 + e1;
      o0[jj] *= r2; o1[jj] *= r2;
      Ps[w][(g * 4 + jj) * 40 + cl]      = f2b(e0);
      Ps[w][(g * 4 + jj) * 40 + cl + 16] = f2b(e1);
    }
    // PV: A = P (q x kv32), B = V^T-stored tile (kv x d)
    const short8 pa  = *(const short8*)&Ps[w][cl * 40 + g * 8];
    const short8 bv0 = *(const short8*)&Vt[cl * 40 + g * 8];
    const short8 bv1 = *(const short8*)&Vt[(cl + 16) * 40 + g * 8];
    o0 = __builtin_amdgcn_mfma_f32_16x16x32_bf16(pa, bv0, o0, 0, 0, 0);
    o1 = __builtin_amdgcn_mfma_f32_16x16x32_bf16(pa, bv1, o1, 0, 0, 0);
  }

#pragma unroll
  for (int jj = 0; jj < 4; ++jj) {
    float ls = lsum[jj];
    ls += __shfl_xor(ls, 1);
    ls += __shfl_xor(ls, 2);
    ls += __shfl_xor(ls, 4);
    ls += __shfl_xor(ls, 8);
    const float inv = 1.0f / ls;
    const int row = qbase + g * 4 + jj;
    unsigned short* op = o + ((size_t)(b * SS + row)) * 256 + h * 28;
    op[cl] = f2b(o0[jj] * inv);
    if (cl < 12) op[16 + cl] = f2b(o1[jj] * inv);
  }
}

// ---------------------------------------------------------------------------
// LayerNorm over (S,D) per batch, bf16 tensors (stride 256, 224 real cols).
// Stats come pre-reduced (2 floats per batch) from GEMM-epilogue atomics.
// ---------------------------------------------------------------------------
__global__ __launch_bounds__(256) void ln_apply(
    const unsigned short* __restrict__ x, const float* __restrict__ w,
    const float* __restrict__ bb, const float* __restrict__ st,
    unsigned short* __restrict__ y)
{
  const int b = blockIdx.x / 112;
  const float s1 = st[b * 2], s2 = st[b * 2 + 1];
  const float mu = s1 / (float)SD;
  const float rstd = rsqrtf(s2 / (float)SD - mu * mu + 1e-5f);
  const int chunk = blockIdx.x * 256 + threadIdx.x;
  const int r = chunk / 28, cc = chunk % 28;
  const int s = r & 1023;
  uint4 u = *(const uint4*)(x + (size_t)r * 256 + cc * 8);
  const float* wp = w + (size_t)s * 224 + cc * 8;
  const float* bp = bb + (size_t)s * 224 + cc * 8;
  float4 w0 = *(const float4*)wp, w1 = *(const float4*)(wp + 4);
  float4 b0 = *(const float4*)bp, b1 = *(const float4*)(bp + 4);
  float wv[8] = {w0.x, w0.y, w0.z, w0.w, w1.x, w1.y, w1.z, w1.w};
  float bv[8] = {b0.x, b0.y, b0.z, b0.w, b1.x, b1.y, b1.z, b1.w};
  const unsigned* up = (const unsigned*)&u;
  uint4 ov;
  unsigned* op = (unsigned*)&ov;
#pragma unroll
  for (int q = 0; q < 4; ++q) {
    float f0 = bits2f(up[q] << 16), f1 = bits2f(up[q] & 0xFFFF0000u);
    float y0 = (f0 - mu) * rstd * wv[q * 2] + bv[q * 2];
    float y1 = (f1 - mu) * rstd * wv[q * 2 + 1] + bv[q * 2 + 1];
    op[q] = (unsigned)f2b(y0) | ((unsigned)f2b(y1) << 16);
  }
  *(uint4*)(y + (size_t)r * 256 + cc * 8) = ov;
}

__global__ __launch_bounds__(256) void ln_part2(
    const unsigned short* __restrict__ x, const float* __restrict__ w,
    const float* __restrict__ bb, const float* __restrict__ stA,
    float* __restrict__ part2)
{
  const int b = blockIdx.y, g = blockIdx.x;
  const float s1 = stA[b * 2], s2 = stA[b * 2 + 1];
  const float mu = s1 / (float)SD;
  const float rstd = rsqrtf(s2 / (float)SD - mu * mu + 1e-5f);
  const unsigned short* base = x + ((size_t)b * 1024 + g * 16) * 256;
  float sum = 0.f, sq = 0.f;
  for (int c = threadIdx.x; c < 448; c += 256) {
    const int r = c / 28, cc = c % 28;
    const int s = g * 16 + r;
    uint4 u = *(const uint4*)(base + (size_t)r * 256 + cc * 8);
    const float* wp = w + (size_t)s * 224 + cc * 8;
    const float* bp = bb + (size_t)s * 224 + cc * 8;
    float4 w0 = *(const float4*)wp, w1 = *(const float4*)(wp + 4);
    float4 b0 = *(const float4*)bp, b1 = *(const float4*)(bp + 4);
    float wv[8] = {w0.x, w0.y, w0.z, w0.w, w1.x, w1.y, w1.z, w1.w};
    float bv[8] = {b0.x, b0.y, b0.z, b0.w, b1.x, b1.y, b1.z, b1.w};
    const unsigned* up = (const unsigned*)&u;
#pragma unroll
    for (int q = 0; q < 4; ++q) {
      float f0 = bits2f(up[q] << 16), f1 = bits2f(up[q] & 0xFFFF0000u);
      float y0 = (f0 - mu) * rstd * wv[q * 2] + bv[q * 2];
      float y1 = (f1 - mu) * rstd * wv[q * 2 + 1] + bv[q * 2 + 1];
      sum += y0 + y1; sq += y0 * y0 + y1 * y1;
    }
  }
  __shared__ float sA[4], sB[4];
#pragma unroll
  for (int o2 = 32; o2 > 0; o2 >>= 1) { sum += __shfl_down(sum, o2); sq += __shfl_down(sq, o2); }
  if ((threadIdx.x & 63) == 0) { sA[threadIdx.x >> 6] = sum; sB[threadIdx.x >> 6] = sq; }
  __syncthreads();
  if (threadIdx.x == 0) {
    part2[((size_t)b * 64 + g) * 2] = sA[0] + sA[1] + sA[2] + sA[3];
    part2[((size_t)b * 64 + g) * 2 + 1] = sB[0] + sB[1] + sB[2] + sB[3];
  }
}

__global__ __launch_bounds__(256) void ln_apply2(
    const unsigned short* __restrict__ x, const float* __restrict__ w,
    const float* __restrict__ bb, const float* __restrict__ stA,
    const float* __restrict__ part2, unsigned short* __restrict__ y)
{
  __shared__ float sh[2];
  const int tid = threadIdx.x;
  const int b = blockIdx.x / 112;
  const float s1 = stA[b * 2], s2 = stA[b * 2 + 1];
  const float mu1 = s1 / (float)SD;
  const float rs1 = rsqrtf(s2 / (float)SD - mu1 * mu1 + 1e-5f);
  if (tid < 64) {
    float p1 = part2[((size_t)b * 64 + tid) * 2];
    float p2 = part2[((size_t)b * 64 + tid) * 2 + 1];
#pragma unroll
    for (int o2 = 32; o2 > 0; o2 >>= 1) { p1 += __shfl_down(p1, o2); p2 += __shfl_down(p2, o2); }
    if (tid == 0) {
      float m2 = p1 / (float)SD;
      sh[0] = m2; sh[1] = rsqrtf(p2 / (float)SD - m2 * m2 + 1e-5f);
    }
  }
  __syncthreads();
  const float mu2 = sh[0], rs2 = sh[1];
  const int chunk = blockIdx.x * 256 + tid;
  const int r = chunk / 28, cc = chunk % 28;
  const int s = r & 1023;
  uint4 u = *(const uint4*)(x + (size_t)r * 256 + cc * 8);
  const float* wp = w + (size_t)s * 224 + cc * 8;
  const float* bp = bb + (size_t)s * 224 + cc * 8;
  float4 w0 = *(const float4*)wp, w1 = *(const float4*)(wp + 4);
  float4 b0 = *(const float4*)bp, b1 = *(const float4*)(bp + 4);
  float wv[8] = {w0.x, w0.y, w0.z, w0.w, w1.x, w1.y, w1.z, w1.w};
  float bv[8] = {b0.x, b0.y, b0.z, b0.w, b1.x, b1.y, b1.z, b1.w};
  const unsigned* up = (const unsigned*)&u;
  uint4 ov;
  unsigned* op = (unsigned*)&ov;
#pragma unroll
  for (int q = 0; q < 4; ++q) {
    float f0 = bits2f(up[q] << 16), f1 = bits2f(up[q] & 0xFFFF0000u);
    float y0 = (f0 - mu1) * rs1 * wv[q * 2] + bv[q * 2];
    float y1 = (f1 - mu1) * rs1 * wv[q * 2 + 1] + bv[q * 2 + 1];
    float z0 = (y0 - mu2) * rs2 * wv[q * 2] + bv[q * 2];
    float z1 = (y1 - mu2) * rs2 * wv[q * 2 + 1] + bv[q * 2 + 1];
    op[q] = (unsigned)f2b(z0) | ((unsigned)f2b(z1) << 16);
  }
  *(uint4*)(y + (size_t)r * 256 + cc * 8) = ov;
}

// ---------------------------------------------------------------------------
// Row softmax over V=8000, in place on d_out (fp32).
// ---------------------------------------------------------------------------
__global__ __launch_bounds__(256) void softmax_rows(float* __restrict__ logits)
{
  const int row = blockIdx.x;
  float* p = logits + (size_t)row * VV;
  __shared__ float buf[VV];
  __shared__ float red[4];
  const int tid = threadIdx.x;

  float mx = -INFINITY;
  for (int i = tid; i < VV; i += 256) { float v = p[i]; buf[i] = v; mx = fmaxf(mx, v); }
#pragma unroll
  for (int o2 = 32; o2 > 0; o2 >>= 1) mx = fmaxf(mx, __shfl_down(mx, o2));
  if ((tid & 63) == 0) red[tid >> 6] = mx;
  __syncthreads();
  mx = fmaxf(fmaxf(red[0], red[1]), fmaxf(red[2], red[3]));
  __syncthreads();

  float s = 0.f;
  for (int i = tid; i < VV; i += 256) { float e = __expf(buf[i] - mx); buf[i] = e; s += e; }
#pragma unroll
  for (int o2 = 32; o2 > 0; o2 >>= 1) s += __shfl_down(s, o2);
  if ((tid & 63) == 0) red[tid >> 6] = s;
  __syncthreads();
  s = red[0] + red[1] + red[2] + red[3];
  const float inv = 1.0f / s;
  for (int i = tid; i < VV; i += 256) p[i] = buf[i] * inv;
}

// ---------------------------------------------------------------------------
extern "C" void kernel_launch(void* const* d_in, const int* in_sizes, int n_in,
                              void* d_out, int out_size, void* d_ws, size_t ws_size,
                              hipStream_t stream) {
  const float* x   = (const float*)d_in[0];
  const float* Wp  = (const float*)d_in[1];
  const float* bp  = (const float*)d_in[2];
  const float* Wq  = (const float*)d_in[3];
  const float* bq  = (const float*)d_in[4];
  const float* Wk  = (const float*)d_in[5];
  const float* bk  = (const float*)d_in[6];
  const float* Wv  = (const float*)d_in[7];
  const float* bv  = (const float*)d_in[8];
  const float* Wo  = (const float*)d_in[9];
  const float* bo  = (const float*)d_in[10];
  const float* W1  = (const float*)d_in[11];
  const float* b1  = (const float*)d_in[12];
  const float* W2  = (const float*)d_in[13];
  const float* b2  = (const float*)d_in[14];
  const float* W3  = (const float*)d_in[15];
  const float* b3  = (const float*)d_in[16];
  const float* lnw = (const float*)d_in[17];
  const float* lnb = (const float*)d_in[18];
  const float* Wf  = (const float*)d_in[19];
  const float* bf  = (const float*)d_in[20];

  unsigned short* wsb = (unsigned short*)d_ws;
  unsigned short* wpT   = wsb + WP;
  unsigned short* wqkvT = wsb + WQKV;
  unsigned short* woT   = wsb + WO;
  unsigned short* w1T   = wsb + W1T;
  unsigned short* w2T   = wsb + W2T;
  unsigned short* w3T   = wsb + W3T;
  unsigned short* wfT   = wsb + WFT;
  unsigned short* h     = wsb + HB;
  unsigned short* h2    = wsb + H2B;
  unsigned short* obuf  = wsb + OBUF;
  unsigned short* xb    = wsb + BIG;
  unsigned short* qkvb  = wsb + BIG;
  unsigned short* f1    = wsb + BIG;
  unsigned short* f2    = wsb + BIG + (size_t)4096 * 640;
  float* bcat  = (float*)((char*)d_ws + FBYTE);
  float* part2 = bcat + LLl * 672;
  float* stats = part2 + 512;     // 128 floats: 8 layers x 2 slots x (4 batches x 2)

  // ---- prep ----
  zero_stats<<<1, 128, 0, stream>>>(stats);
  hipMemsetAsync(wqkvT, 0, (size_t)LLl * 704 * 256 * 2, stream);
  prep_x<<<3072, 256, 0, stream>>>(x, xb);
  prep_wt2<<<dim3(192, 1), 256, 0, stream>>>(Wp, wpT, 768, 224, 768, 256, 0, 0);
  prep_wqkv<<<dim3(1568, 1), 256, 0, stream>>>(Wq, Wk, Wv, bq, bk, bv, wqkvT, bcat);
  prep_wt2<<<dim3(64, 8), 256, 0, stream>>>(Wo, woT, 224, 224, 256, 256,
                                            (size_t)224 * 224, (size_t)256 * 256);
  prep_wt2<<<dim3(160, 8), 256, 0, stream>>>(W1, w1T, 224, 600, 256, 640,
                                             (size_t)224 * 600, (size_t)640 * 256);
  prep_wt2<<<dim3(400, 8), 256, 0, stream>>>(W2, w2T, 600, 600, 640, 640,
                                             (size_t)600 * 600, (size_t)640 * 640);
  prep_wt2<<<dim3(160, 8), 256, 0, stream>>>(W3, w3T, 600, 224, 640, 256,
                                             (size_t)600 * 224, (size_t)256 * 640);
  prep_wt2<<<dim3(2016, 1), 256, 0, stream>>>(Wf, wfT, 224, 8000, 256, 8064, 0, 0);

  // ---- proj + posenc: h = x @ Wp + bp + pe ----
  gemm_mfma<32, 64, GF_BIAS | GF_POSENC><<<dim3(4, 128), 256, 0, stream>>>(
      xb, wpT, bp, nullptr, h, 768, 224, 256, nullptr);

  for (int l = 0; l < LLl; ++l) {
    float* stA = stats + (size_t)(l * 2) * 8;
    float* stB = stats + (size_t)(l * 2 + 1) * 8;
    gemm_mfma<64, 64, GF_BIAS><<<dim3(11, 64), 256, 0, stream>>>(
        h, wqkvT + (size_t)l * 704 * 256, bcat + l * 672, nullptr, qkvb, 256, 672, 704, nullptr);
    attn_mfma<<<dim3(BB * 8, SS / 64), 256, 0, stream>>>(qkvb, obuf);
    gemm_mfma<32, 64, GF_BIAS | GF_RESID | GF_STAT><<<dim3(4, 128), 256, 0, stream>>>(
        obuf, woT + (size_t)l * 256 * 256, bo + (size_t)l * 224, h, h2, 256, 224, 256, stA);
    ln_apply<<<448, 256, 0, stream>>>(h2, lnw + (size_t)l * SD, lnb + (size_t)l * SD, stA, h);
    gemm_mfma<64, 64, GF_BIAS | GF_RELU><<<dim3(10, 64), 256, 0, stream>>>(
        h, w1T + (size_t)l * 640 * 256, b1 + (size_t)l * 600, nullptr, f1, 256, 600, 640, nullptr);
    gemm_mfma<64, 64, GF_BIAS | GF_RELU><<<dim3(10, 64), 256, 0, stream>>>(
        f1, w2T + (size_t)l * 640 * 640, b2 + (size_t)l * 600, nullptr, f2, 640, 600, 640, nullptr);
    gemm_mfma<32, 64, GF_BIAS | GF_RESID | GF_STAT><<<dim3(4, 128), 256, 0, stream>>>(
        f2, w3T + (size_t)l * 256 * 640, b3 + (size_t)l * 224, h, h2, 640, 224, 256, stB);
    ln_part2<<<dim3(64, BB), 256, 0, stream>>>(h2, lnw + (size_t)l * SD, lnb + (size_t)l * SD,
                                               stB, part2);
    ln_apply2<<<448, 256, 0, stream>>>(h2, lnw + (size_t)l * SD, lnb + (size_t)l * SD,
                                       stB, part2, h);
  }

  // ---- logits (fp32 out, m-fastest block order) + softmax ----
  gemm_mfma<128, 128, GF_BIAS | GF_F32OUT | GF_SWAP><<<dim3(32, 63), 256, 0, stream>>>(
      h, wfT, bf, nullptr, (float*)d_out, 256, 8000, 8000, nullptr);
  softmax_rows<<<4096, 256, 0, stream>>>((float*)d_out);
}

// Round 8
// 1342.288 us; speedup vs baseline: 1.2684x; 1.2455x over previous
//
#include <hip/hip_runtime.h>
#include <math.h>

#define GF_BIAS   1
#define GF_RELU   2
#define GF_RESID  4
#define GF_POSENC 8
#define GF_F32OUT 16
#define GF_STAT6  32
#define GF_SWAP   64
#define GF_LNA    128
#define GF_LNA2   256
#define GF_LNRES  512
#define GF_LNRES2 1024

namespace {
constexpr int BB = 4, SS = 1024, DD = 224, FFF = 600, VV = 8000, LLl = 8;
constexpr int SD = SS * DD;  // 229376
constexpr float INV_SD = 1.0f / (float)SD;

// workspace layout, bf16 element offsets
constexpr size_t WP   = 0;                         // [256][768]
constexpr size_t WQKV = WP + (size_t)256 * 768;    // L x [704][256]
constexpr size_t WO   = WQKV + (size_t)LLl * 704 * 256;
constexpr size_t W1T  = WO + (size_t)LLl * 256 * 256;
constexpr size_t W2T  = W1T + (size_t)LLl * 640 * 256;
constexpr size_t W3T  = W2T + (size_t)LLl * 640 * 640;
constexpr size_t WFT  = W3T + (size_t)LLl * 256 * 640;   // [8064][256]
constexpr size_t HB   = WFT + (size_t)8064 * 256;        // X (pre-LN state)
constexpr size_t H2B  = HB + (size_t)4096 * 256;         // h2a / hF
constexpr size_t OBUF = H2B + (size_t)4096 * 256;
constexpr size_t BIG  = OBUF + (size_t)4096 * 256;       // xb | qkv | f1,f2
constexpr size_t ENDB = BIG + (size_t)2 * 4096 * 640;
constexpr size_t FBYTE = ENDB * 2;                       // float region byte offset
}

using short8 = __attribute__((ext_vector_type(8))) short;
using f32x4  = __attribute__((ext_vector_type(4))) float;

__device__ __forceinline__ float bits2f(unsigned u) {
  union { unsigned u; float f; } v; v.u = u; return v.f;
}
__device__ __forceinline__ unsigned short f2b(float f) {
  union { float f; unsigned u; } v; v.f = f;
  unsigned r = v.u + 0x7FFFu + ((v.u >> 16) & 1u);
  return (unsigned short)(r >> 16);
}
__device__ __forceinline__ float b2f(unsigned short b) {
  return bits2f((unsigned)b << 16);
}

// LN-transform 8 bf16 elements (one 16B chunk) with per-element w,b.
__device__ __forceinline__ uint4 ln8(uint4 raw, const float* __restrict__ wp,
                                     const float* __restrict__ bp,
                                     float mu1, float rs1, float mu2, float rs2,
                                     bool dbl) {
  float4 w0 = *(const float4*)wp, w1v = *(const float4*)(wp + 4);
  float4 b0 = *(const float4*)bp, b1v = *(const float4*)(bp + 4);
  float wv[8] = {w0.x, w0.y, w0.z, w0.w, w1v.x, w1v.y, w1v.z, w1v.w};
  float bv[8] = {b0.x, b0.y, b0.z, b0.w, b1v.x, b1v.y, b1v.z, b1v.w};
  const unsigned* u = (const unsigned*)&raw;
  uint4 out;
  unsigned* ou = (unsigned*)&out;
#pragma unroll
  for (int q = 0; q < 4; ++q) {
    float x0 = bits2f(u[q] << 16), x1 = bits2f(u[q] & 0xFFFF0000u);
    float y0 = (x0 - mu1) * rs1 * wv[q * 2] + bv[q * 2];
    float y1 = (x1 - mu1) * rs1 * wv[q * 2 + 1] + bv[q * 2 + 1];
    if (dbl) {
      y0 = (y0 - mu2) * rs2 * wv[q * 2] + bv[q * 2];
      y1 = (y1 - mu2) * rs2 * wv[q * 2 + 1] + bv[q * 2 + 1];
    }
    ou[q] = (unsigned)f2b(y0) | ((unsigned)f2b(y1) << 16);
  }
  return out;
}

// ---------------------------------------------------------------------------
// bf16 MFMA GEMM with fused LN transforms and 6-sum stat epilogue.
// C[M,Npad] = lnT(A)[M,Kp] @ Bt[Npad,Kp]^T (+bias, +lnT(resid), relu, stats)
// ---------------------------------------------------------------------------
template <int BM, int BN, int FLAGS>
__global__ __launch_bounds__(256) void gemm_mfma(
    const unsigned short* __restrict__ A, const unsigned short* __restrict__ Bt,
    const float* __restrict__ bias, const unsigned short* __restrict__ Rz,
    void* __restrict__ Cout, int Kp, int N, int ldc,
    const float* __restrict__ lnwT, const float* __restrict__ lnbT,
    const float* __restrict__ stIn, const float* __restrict__ cst,
    const float* __restrict__ lnwS, const float* __restrict__ lnbS,
    float* __restrict__ statOut)
{
  constexpr bool HASLNA = (FLAGS & (GF_LNA | GF_LNA2)) != 0;
  constexpr bool HASLNR = (FLAGS & (GF_LNRES | GF_LNRES2)) != 0;
  constexpr bool DBLA = (FLAGS & GF_LNA2) != 0;
  constexpr bool DBLR = (FLAGS & GF_LNRES2) != 0;
  constexpr int MR = BM / 32, NR = BN / 32;
  constexpr int APT = BM / 32, BPT = BN / 32;
  constexpr int ABY = BM * 128, BBY = BN * 128;   // bytes (BK=64)
  constexpr int CBY = (FLAGS & GF_F32OUT) ? (64 * (BN + 4) * 4) : (BM * (BN + 8) * 2);
  constexpr int SBY = (ABY + BBY) > CBY ? (ABY + BBY) : CBY;
  __shared__ __align__(16) char smem[SBY];
  __shared__ float red6[24];
  unsigned short* sA = (unsigned short*)smem;
  unsigned short* sB = (unsigned short*)(smem + ABY);
  const int t = threadIdx.x;
  const int l = t & 63;
  const int w = t >> 6, wr = w >> 1, wc = w & 1;
  const int m0 = ((FLAGS & GF_SWAP) ? blockIdx.x : blockIdx.y) * BM;
  const int n0 = ((FLAGS & GF_SWAP) ? blockIdx.y : blockIdx.x) * BN;
  const int nk = Kp >> 6;

  // LN stats for this block's batch (BM <= 128 so one batch per block)
  float mu1 = 0.f, rs1 = 1.f, mu2 = 0.f, rs2 = 1.f;
  if constexpr (HASLNA || HASLNR) {
    const float* st = stIn + (m0 >> 10) * 6;
    const float s0 = st[0], s1 = st[1];
    mu1 = s0 * INV_SD;
    rs1 = rsqrtf(s1 * INV_SD - mu1 * mu1 + 1e-5f);
    if constexpr (DBLA || DBLR) {
      const float swx = st[2], sw2x = st[3], sw2x2 = st[4], swbx = st[5];
      mu2 = (rs1 * (swx - mu1 * cst[0]) + cst[2]) * INV_SD;
      const float ey2 = (rs1 * rs1 * (sw2x2 - 2.f * mu1 * sw2x + mu1 * mu1 * cst[1]) +
                         2.f * rs1 * (swbx - mu1 * cst[4]) + cst[3]) * INV_SD;
      rs2 = rsqrtf(ey2 - mu2 * mu2 + 1e-5f);
    }
  }

  int aoff[APT], ar[APT], ac[APT];
#pragma unroll
  for (int p = 0; p < APT; ++p) {
    int off = (t + p * 256) * 16;
    int r = off >> 7;
    int cb = (off & 127) ^ ((r & 7) << 4);
    aoff[p] = off; ar[p] = r; ac[p] = cb >> 1;
  }
  int boff[BPT], br[BPT], bc[BPT];
#pragma unroll
  for (int p = 0; p < BPT; ++p) {
    int off = (t + p * 256) * 16;
    int r = off >> 7;
    int cb = (off & 127) ^ ((r & 7) << 4);
    boff[p] = off; br[p] = r; bc[p] = cb >> 1;
  }

  const unsigned short* Ab = A + (size_t)m0 * Kp;
  const unsigned short* Bb = Bt + (size_t)n0 * Kp;

  auto loadA = [&](int p, int kb) -> uint4 {
    const int d0 = kb + ac[p];
    uint4 raw = *(const uint4*)(Ab + (size_t)ar[p] * Kp + d0);
    if constexpr (HASLNA) {
      if (d0 >= DD) return make_uint4(0u, 0u, 0u, 0u);
      const int srow = (m0 + ar[p]) & (SS - 1);
      raw = ln8(raw, lnwT + (size_t)srow * DD + d0, lnbT + (size_t)srow * DD + d0,
                mu1, rs1, mu2, rs2, DBLA);
    }
    return raw;
  };

  uint4 ra[APT], rb[BPT];
#pragma unroll
  for (int p = 0; p < APT; ++p) ra[p] = loadA(p, 0);
#pragma unroll
  for (int p = 0; p < BPT; ++p) rb[p] = *(const uint4*)(Bb + (size_t)br[p] * Kp + bc[p]);

  f32x4 acc[MR][NR];
#pragma unroll
  for (int i = 0; i < MR; ++i)
#pragma unroll
    for (int j = 0; j < NR; ++j) acc[i][j] = {0.f, 0.f, 0.f, 0.f};

  for (int kt = 0; kt < nk; ++kt) {
#pragma unroll
    for (int p = 0; p < APT; ++p) *(uint4*)((char*)sA + aoff[p]) = ra[p];
#pragma unroll
    for (int p = 0; p < BPT; ++p) *(uint4*)((char*)sB + boff[p]) = rb[p];
    __syncthreads();
    if (kt + 1 < nk) {
      const int k1 = (kt + 1) * 64;
#pragma unroll
      for (int p = 0; p < APT; ++p) ra[p] = loadA(p, k1);
#pragma unroll
      for (int p = 0; p < BPT; ++p) rb[p] = *(const uint4*)(Bb + (size_t)br[p] * Kp + k1 + bc[p]);
    }
#pragma unroll
    for (int kh = 0; kh < 2; ++kh) {
      short8 af[MR], bfg[NR];
#pragma unroll
      for (int mi = 0; mi < MR; ++mi) {
        const int row = wr * (BM / 2) + mi * 16 + (l & 15);
        const int byte = (row * 128 + kh * 64 + (l >> 4) * 16) ^ ((row & 7) << 4);
        af[mi] = *(const short8*)((const char*)sA + byte);
      }
#pragma unroll
      for (int ni = 0; ni < NR; ++ni) {
        const int row = wc * (BN / 2) + ni * 16 + (l & 15);
        const int byte = (row * 128 + kh * 64 + (l >> 4) * 16) ^ ((row & 7) << 4);
        bfg[ni] = *(const short8*)((const char*)sB + byte);
      }
#pragma unroll
      for (int mi = 0; mi < MR; ++mi)
#pragma unroll
        for (int ni = 0; ni < NR; ++ni)
          acc[mi][ni] = __builtin_amdgcn_mfma_f32_16x16x32_bf16(af[mi], bfg[ni], acc[mi][ni], 0, 0, 0);
    }
    __syncthreads();
  }

  const int cl = l & 15, rl0 = (l >> 4) * 4;

  if constexpr ((FLAGS & GF_F32OUT) != 0) {
    constexpr int CST = BN + 4;
    float* Cs = (float*)smem;
    constexpr int NCH = BM / 64;
#pragma unroll
    for (int c = 0; c < NCH; ++c) {
      __syncthreads();
      if ((wr * (BM / 2)) / 64 == c) {
#pragma unroll
        for (int mi = 0; mi < MR; ++mi)
#pragma unroll
          for (int ni = 0; ni < NR; ++ni)
#pragma unroll
            for (int j = 0; j < 4; ++j) {
              const int rl = wr * (BM / 2) + mi * 16 + rl0 + j - c * 64;
              const int cc = wc * (BN / 2) + ni * 16 + cl;
              const int gn = n0 + cc;
              float v = acc[mi][ni][j];
              if ((FLAGS & GF_BIAS) && gn < N) v += bias[gn];
              Cs[rl * CST + cc] = v;
            }
      }
      __syncthreads();
      constexpr int CPR = BN / 4;
      constexpr int NIT = (64 * CPR) / 256;
#pragma unroll
      for (int i = 0; i < NIT; ++i) {
        const int ch = i * 256 + t;
        const int rr = ch / CPR, c4 = ch % CPR;
        const int gn = n0 + c4 * 4;
        const size_t gmr = (size_t)(m0 + c * 64 + rr);
        if (gn + 3 < N) {
          *(float4*)&((float*)Cout)[gmr * ldc + gn] = *(const float4*)&Cs[rr * CST + c4 * 4];
        } else {
#pragma unroll
          for (int c2 = 0; c2 < 4; ++c2)
            if (gn + c2 < N) ((float*)Cout)[gmr * ldc + gn + c2] = Cs[rr * CST + c4 * 4 + c2];
        }
      }
    }
  } else {
    constexpr int CST = BN + 8;
    unsigned short* Cs = (unsigned short*)smem;
    float ls0 = 0.f, ls1 = 0.f, ls2 = 0.f, ls3 = 0.f, ls4 = 0.f, ls5 = 0.f;
#pragma unroll
    for (int mi = 0; mi < MR; ++mi)
#pragma unroll
      for (int ni = 0; ni < NR; ++ni)
#pragma unroll
        for (int j = 0; j < 4; ++j) {
          const int rl = wr * (BM / 2) + mi * 16 + rl0 + j;
          const int cc = wc * (BN / 2) + ni * 16 + cl;
          const int gm = m0 + rl, gn = n0 + cc;
          const int srow = gm & (SS - 1);
          float v = acc[mi][ni][j];
          if ((FLAGS & GF_BIAS) && gn < N) v += bias[gn];
          if constexpr ((FLAGS & GF_RESID) != 0) {
            if constexpr (HASLNR) {
              if (gn < N) {
                float rv = b2f(Rz[(size_t)gm * ldc + gn]);
                const float wE = lnwT[(size_t)srow * DD + gn];
                const float bE = lnbT[(size_t)srow * DD + gn];
                rv = (rv - mu1) * rs1 * wE + bE;
                if constexpr (DBLR) rv = (rv - mu2) * rs2 * wE + bE;
                v += rv;
              }
            } else {
              v += b2f(Rz[(size_t)gm * ldc + gn]);
            }
          }
          if ((FLAGS & GF_POSENC) && gn < N) {
            float freq = expf(-(2.0f * gn / 224.0f) * 9.210340371976184f);
            float ang = (float)srow * freq;
            v += (gn & 1) ? cosf(ang) : sinf(ang);
          }
          if (FLAGS & GF_RELU) v = fmaxf(v, 0.f);
          if constexpr ((FLAGS & GF_STAT6) != 0) {
            if (gn < N) {
              const float wS = lnwS[(size_t)srow * DD + gn];
              const float bS = lnbS[(size_t)srow * DD + gn];
              const float wv = wS * v;
              ls0 += v; ls1 += v * v; ls2 += wv; ls3 += wS * wv;
              ls4 += wv * wv; ls5 += bS * wv;
            }
          }
          Cs[rl * CST + cc] = f2b(v);
        }
    __syncthreads();
#pragma unroll
    for (int it = 0; it < BM / 32; ++it) {
      const int rr = it * 32 + (t >> 3), qq = t & 7;
      const size_t gm = (size_t)(m0 + rr);
      *(uint4*)&((unsigned short*)Cout)[gm * ldc + n0 + qq * 8] =
          *(const uint4*)&Cs[rr * CST + qq * 8];
    }
    if constexpr ((FLAGS & GF_STAT6) != 0) {
      float s[6] = {ls0, ls1, ls2, ls3, ls4, ls5};
#pragma unroll
      for (int o2 = 32; o2 > 0; o2 >>= 1)
#pragma unroll
        for (int j = 0; j < 6; ++j) s[j] += __shfl_down(s[j], o2);
      if (l == 0)
#pragma unroll
        for (int j = 0; j < 6; ++j) red6[w * 6 + j] = s[j];
      __syncthreads();
      if (t < 6) {
        const float tot = red6[t] + red6[6 + t] + red6[12 + t] + red6[18 + t];
        atomicAdd(&statOut[(m0 >> 10) * 6 + t], tot);
      }
    }
  }
}

__global__ void zero_stats(float* __restrict__ st)
{
  if (threadIdx.x < 424) st[threadIdx.x] = 0.f;
}

// Per-layer LN constants: Sw, Sw2, Sb, Sb2, Swb. Grid (64, L).
__global__ __launch_bounds__(256) void lnconst(const float* __restrict__ lnw,
                                               const float* __restrict__ lnb,
                                               float* __restrict__ cst)
{
  const int ll = blockIdx.y, g = blockIdx.x;
  const float* wv = lnw + (size_t)ll * SD + g * 3584;
  const float* bv = lnb + (size_t)ll * SD + g * 3584;
  float s[5] = {0.f, 0.f, 0.f, 0.f, 0.f};
  for (int c = threadIdx.x * 4; c < 3584; c += 1024) {
    float4 w4 = *(const float4*)(wv + c);
    float4 b4 = *(const float4*)(bv + c);
    const float* wf = (const float*)&w4;
    const float* bf2 = (const float*)&b4;
#pragma unroll
    for (int e = 0; e < 4; ++e) {
      const float ww = wf[e], bb = bf2[e];
      s[0] += ww; s[1] += ww * ww; s[2] += bb; s[3] += bb * bb; s[4] += ww * bb;
    }
  }
#pragma unroll
  for (int o2 = 32; o2 > 0; o2 >>= 1)
#pragma unroll
    for (int j = 0; j < 5; ++j) s[j] += __shfl_down(s[j], o2);
  __shared__ float red[4][5];
  if ((threadIdx.x & 63) == 0)
#pragma unroll
    for (int j = 0; j < 5; ++j) red[threadIdx.x >> 6][j] = s[j];
  __syncthreads();
  if (threadIdx.x < 5) {
    const float tot = red[0][threadIdx.x] + red[1][threadIdx.x] +
                      red[2][threadIdx.x] + red[3][threadIdx.x];
    atomicAdd(&cst[ll * 5 + threadIdx.x], tot);
  }
}

// Materialize hF = LN(LN(X)) for the logits GEMM (analytic LN2 stats).
__global__ __launch_bounds__(256) void ln2mat(
    const unsigned short* __restrict__ X, const float* __restrict__ lnw,
    const float* __restrict__ lnb, const float* __restrict__ st,
    const float* __restrict__ cst, unsigned short* __restrict__ Y)
{
  const int chunk = blockIdx.x * 256 + threadIdx.x;   // 131072 = 4096*32
  const int r = chunk >> 5, cc = chunk & 31;
  if (cc >= 28) {
    *(uint4*)(Y + (size_t)r * 256 + cc * 8) = make_uint4(0u, 0u, 0u, 0u);
    return;
  }
  const int b = r >> 10, srow = r & 1023;
  const float* s = st + b * 6;
  const float mu1 = s[0] * INV_SD;
  const float rs1 = rsqrtf(s[1] * INV_SD - mu1 * mu1 + 1e-5f);
  const float mu2 = (rs1 * (s[2] - mu1 * cst[0]) + cst[2]) * INV_SD;
  const float ey2 = (rs1 * rs1 * (s[4] - 2.f * mu1 * s[3] + mu1 * mu1 * cst[1]) +
                     2.f * rs1 * (s[5] - mu1 * cst[4]) + cst[3]) * INV_SD;
  const float rs2 = rsqrtf(ey2 - mu2 * mu2 + 1e-5f);
  uint4 raw = *(const uint4*)(X + (size_t)r * 256 + cc * 8);
  uint4 out = ln8(raw, lnw + (size_t)srow * DD + cc * 8, lnb + (size_t)srow * DD + cc * 8,
                  mu1, rs1, mu2, rs2, true);
  *(uint4*)(Y + (size_t)r * 256 + cc * 8) = out;
}

// ---------------------------------------------------------------------------
// Weight prep via LDS 32x32 transpose: fp32 [K][N] -> bf16 [Np][Kp] padded.
// ---------------------------------------------------------------------------
__global__ __launch_bounds__(256) void prep_wt2(
    const float* __restrict__ W, unsigned short* __restrict__ O,
    int K, int N, int Kp, int Np, size_t sW, size_t sO)
{
  const int ll = blockIdx.y;
  const int tx = Np >> 5;
  const int tn = blockIdx.x % tx, tk = blockIdx.x / tx;
  const int n0 = tn * 32, k0 = tk * 32;
  const float* Wl = W + sW * ll;
  unsigned short* Ol = O + sO * ll;
  __shared__ float T[32][36];
  {
    const int r = threadIdx.x >> 3, c4 = (threadIdx.x & 7) * 4;
    const int k = k0 + r, n = n0 + c4;
    float4 v = make_float4(0.f, 0.f, 0.f, 0.f);
    if (k < K) {
      if (n + 3 < N) v = *(const float4*)&Wl[(size_t)k * N + n];
      else {
        if (n + 0 < N) v.x = Wl[(size_t)k * N + n + 0];
        if (n + 1 < N) v.y = Wl[(size_t)k * N + n + 1];
        if (n + 2 < N) v.z = Wl[(size_t)k * N + n + 2];
        if (n + 3 < N) v.w = Wl[(size_t)k * N + n + 3];
      }
    }
    *(float4*)&T[r][c4] = v;
  }
  __syncthreads();
  {
    const int nl = threadIdx.x >> 3, k4 = (threadIdx.x & 7) * 4;
    ushort4 u;
    u.x = f2b(T[k4 + 0][nl]); u.y = f2b(T[k4 + 1][nl]);
    u.z = f2b(T[k4 + 2][nl]); u.w = f2b(T[k4 + 3][nl]);
    *(ushort4*)&Ol[(size_t)(n0 + nl) * Kp + k0 + k4] = u;
  }
}

// Coalesced-read qkv weight repack (dest pre-zeroed so pads stay 0).
__global__ void prep_wqkv(const float* __restrict__ Wq, const float* __restrict__ Wk,
                          const float* __restrict__ Wv, const float* __restrict__ bq,
                          const float* __restrict__ bk, const float* __restrict__ bv,
                          unsigned short* __restrict__ O, float* __restrict__ bcat)
{
  const int idx = blockIdx.x * 256 + threadIdx.x;
  if (idx < LLl * 8 * 224 * 28) {
    const int kk = idx % 28;
    const int d  = (idx / 28) % 224;
    const int h  = (idx / (28 * 224)) % 8;
    const int ll = idx / (28 * 224 * 8);
    const int col = h * 28 + kk;
    const size_t base = (size_t)ll * (704 * 256);
    O[base + (size_t)col * 256 + d]         = f2b(Wq[idx]);
    O[base + (size_t)(224 + col) * 256 + d] = f2b(Wk[idx]);
    O[base + (size_t)(448 + col) * 256 + d] = f2b(Wv[idx]);
  }
  if (idx < LLl * 8 * 28) {
    const int kk = idx % 28;
    const int h  = (idx / 28) % 8;
    const int ll = idx / (28 * 8);
    const int col = h * 28 + kk;
    bcat[ll * 672 + col]       = bq[idx];
    bcat[ll * 672 + 224 + col] = bk[idx];
    bcat[ll * 672 + 448 + col] = bv[idx];
  }
}

__global__ void prep_x(const float* __restrict__ x, unsigned short* __restrict__ xb)
{
  const size_t i = ((size_t)blockIdx.x * 256 + threadIdx.x) * 4;
  float4 v = *(const float4*)(x + i);
  ushort4 o;
  o.x = f2b(v.x); o.y = f2b(v.y); o.z = f2b(v.z); o.w = f2b(v.w);
  *(ushort4*)(xb + i) = o;
}

// ---------------------------------------------------------------------------
// MFMA flash attention (unchanged from round 5/7 best).
// ---------------------------------------------------------------------------
__global__ __launch_bounds__(256) void attn_mfma(const unsigned short* __restrict__ qkv,
                                                 unsigned short* __restrict__ o)
{
  const int bh = blockIdx.x;
  const int qt = (int)gridDim.y - 1 - (int)blockIdx.y;
  const int b = bh >> 3, h = bh & 7;
  const int tid = threadIdx.x;
  const int w = tid >> 6, l = tid & 63;
  const int cl = l & 15, g = l >> 4;
  const int qbase = qt * 64 + w * 16;
  const float scale = 0.1889822365046136f;  // 1/sqrt(28)

  __shared__ unsigned short Ks[32 * 40];
  __shared__ unsigned short Vt[32 * 40];
  __shared__ unsigned short Ps[4][16 * 40];

  short8 aq;
  {
    const unsigned short* qp = qkv + ((size_t)(b * SS + qbase + cl)) * 704 + h * 28;
#pragma unroll
    for (int e = 0; e < 8; ++e) {
      const int d = g * 8 + e;
      ((unsigned short*)&aq)[e] = (d < 28) ? qp[d] : (unsigned short)0;
    }
  }

  f32x4 o0 = {0.f, 0.f, 0.f, 0.f}, o1 = {0.f, 0.f, 0.f, 0.f};
  float m[4] = {-INFINITY, -INFINITY, -INFINITY, -INFINITY};
  float lsum[4] = {0.f, 0.f, 0.f, 0.f};

  const int ntiles = qt * 2 + 2;
  const int ntw = ((qbase + 15) >> 5) + 1;

  const int sr = tid >> 3, sc4 = (tid & 7) << 2;
  const bool sact = (sc4 < 28);
  ushort4 ku = make_ushort4(0, 0, 0, 0), vu = make_ushort4(0, 0, 0, 0);
  if (sact) {
    const unsigned short* kp = qkv + ((size_t)(b * SS + sr)) * 704 + 224 + h * 28 + sc4;
    ku = *(const ushort4*)kp;
    vu = *(const ushort4*)(kp + 224);
  }

  for (int tile = 0; tile < ntiles; ++tile) {
    const int t0 = tile * 32;
    __syncthreads();
    *(ushort4*)&Ks[sr * 40 + sc4] = ku;
    Vt[(sc4 + 0) * 40 + sr] = vu.x;
    Vt[(sc4 + 1) * 40 + sr] = vu.y;
    Vt[(sc4 + 2) * 40 + sr] = vu.z;
    Vt[(sc4 + 3) * 40 + sr] = vu.w;
    __syncthreads();
    if (tile + 1 < ntiles && sact) {
      const unsigned short* kp =
          qkv + ((size_t)(b * SS + (tile + 1) * 32 + sr)) * 704 + 224 + h * 28 + sc4;
      ku = *(const ushort4*)kp;
      vu = *(const ushort4*)(kp + 224);
    }
    if (tile >= ntw) continue;

    const short8 bk0 = *(const short8*)&Ks[cl * 40 + g * 8];
    const short8 bk1 = *(const short8*)&Ks[(cl + 16) * 40 + g * 8];
    f32x4 zz = {0.f, 0.f, 0.f, 0.f};
    f32x4 s0 = __builtin_amdgcn_mfma_f32_16x16x32_bf16(aq, bk0, zz, 0, 0, 0);
    f32x4 s1 = __builtin_amdgcn_mfma_f32_16x16x32_bf16(aq, bk1, zz, 0, 0, 0);

    const bool diag = (t0 + 31 > qbase);
#pragma unroll
    for (int jj = 0; jj < 4; ++jj) {
      float v0 = s0[jj] * scale, v1 = s1[jj] * scale;
      if (diag) {
        const int qr = qbase + g * 4 + jj;
        if (t0 + cl > qr)      v0 = -INFINITY;
        if (t0 + 16 + cl > qr) v1 = -INFINITY;
      }
      float rm = fmaxf(v0, v1);
      rm = fmaxf(rm, __shfl_xor(rm, 1));
      rm = fmaxf(rm, __shfl_xor(rm, 2));
      rm = fmaxf(rm, __shfl_xor(rm, 4));
      rm = fmaxf(rm, __shfl_xor(rm, 8));
      const float mnew = fmaxf(m[jj], rm);
      const float r2 = __expf(m[jj] - mnew);
      m[jj] = mnew;
      const float e0 = __expf(v0 - mnew), e1 = __expf(v1 - mnew);
      lsum[jj] = lsum[jj] * r2 + e0 + e1;
      o0[jj] *= r2; o1[jj] *= r2;
      Ps[w][(g * 4 + jj) * 40 + cl]      = f2b(e0);
      Ps[w][(g * 4 + jj) * 40 + cl + 16] = f2b(e1);
    }
    const short8 pa  = *(const short8*)&Ps[w][cl * 40 + g * 8];
    const short8 bv0 = *(const short8*)&Vt[cl * 40 + g * 8];
    const short8 bv1 = *(const short8*)&Vt[(cl + 16) * 40 + g * 8];
    o0 = __builtin_amdgcn_mfma_f32_16x16x32_bf16(pa, bv0, o0, 0, 0, 0);
    o1 = __builtin_amdgcn_mfma_f32_16x16x32_bf16(pa, bv1, o1, 0, 0, 0);
  }

#pragma unroll
  for (int jj = 0; jj < 4; ++jj) {
    float ls = lsum[jj];
    ls += __shfl_xor(ls, 1);
    ls += __shfl_xor(ls, 2);
    ls += __shfl_xor(ls, 4);
    ls += __shfl_xor(ls, 8);
    const float inv = 1.0f / ls;
    const int row = qbase + g * 4 + jj;
    unsigned short* op = o + ((size_t)(b * SS + row)) * 256 + h * 28;
    op[cl] = f2b(o0[jj] * inv);
    if (cl < 12) op[16 + cl] = f2b(o1[jj] * inv);
  }
}

// ---------------------------------------------------------------------------
// Row softmax over V=8000, in place on d_out (fp32).
// ---------------------------------------------------------------------------
__global__ __launch_bounds__(256) void softmax_rows(float* __restrict__ logits)
{
  const int row = blockIdx.x;
  float* p = logits + (size_t)row * VV;
  __shared__ float buf[VV];
  __shared__ float red[4];
  const int tid = threadIdx.x;

  float mx = -INFINITY;
  for (int i = tid; i < VV; i += 256) { float v = p[i]; buf[i] = v; mx = fmaxf(mx, v); }
#pragma unroll
  for (int o2 = 32; o2 > 0; o2 >>= 1) mx = fmaxf(mx, __shfl_down(mx, o2));
  if ((tid & 63) == 0) red[tid >> 6] = mx;
  __syncthreads();
  mx = fmaxf(fmaxf(red[0], red[1]), fmaxf(red[2], red[3]));
  __syncthreads();

  float s = 0.f;
  for (int i = tid; i < VV; i += 256) { float e = __expf(buf[i] - mx); buf[i] = e; s += e; }
#pragma unroll
  for (int o2 = 32; o2 > 0; o2 >>= 1) s += __shfl_down(s, o2);
  if ((tid & 63) == 0) red[tid >> 6] = s;
  __syncthreads();
  s = red[0] + red[1] + red[2] + red[3];
  const float inv = 1.0f / s;
  for (int i = tid; i < VV; i += 256) p[i] = buf[i] * inv;
}

// ---------------------------------------------------------------------------
extern "C" void kernel_launch(void* const* d_in, const int* in_sizes, int n_in,
                              void* d_out, int out_size, void* d_ws, size_t ws_size,
                              hipStream_t stream) {
  const float* x   = (const float*)d_in[0];
  const float* Wp  = (const float*)d_in[1];
  const float* bp  = (const float*)d_in[2];
  const float* Wq  = (const float*)d_in[3];
  const float* bq  = (const float*)d_in[4];
  const float* Wk  = (const float*)d_in[5];
  const float* bk  = (const float*)d_in[6];
  const float* Wv  = (const float*)d_in[7];
  const float* bv  = (const float*)d_in[8];
  const float* Wo  = (const float*)d_in[9];
  const float* bo  = (const float*)d_in[10];
  const float* W1  = (const float*)d_in[11];
  const float* b1  = (const float*)d_in[12];
  const float* W2  = (const float*)d_in[13];
  const float* b2  = (const float*)d_in[14];
  const float* W3  = (const float*)d_in[15];
  const float* b3  = (const float*)d_in[16];
  const float* lnw = (const float*)d_in[17];
  const float* lnb = (const float*)d_in[18];
  const float* Wf  = (const float*)d_in[19];
  const float* bf  = (const float*)d_in[20];

  unsigned short* wsb = (unsigned short*)d_ws;
  unsigned short* wpT   = wsb + WP;
  unsigned short* wqkvT = wsb + WQKV;
  unsigned short* woT   = wsb + WO;
  unsigned short* w1T   = wsb + W1T;
  unsigned short* w2T   = wsb + W2T;
  unsigned short* w3T   = wsb + W3T;
  unsigned short* wfT   = wsb + WFT;
  unsigned short* X     = wsb + HB;    // pre-LN layer state
  unsigned short* h2a   = wsb + H2B;   // attn-block output / hF
  unsigned short* obuf  = wsb + OBUF;
  unsigned short* xb    = wsb + BIG;
  unsigned short* qkvb  = wsb + BIG;
  unsigned short* f1    = wsb + BIG;
  unsigned short* f2    = wsb + BIG + (size_t)4096 * 640;
  float* bcat  = (float*)((char*)d_ws + FBYTE);
  float* stats = bcat + LLl * 672;      // 16 slots x 24 floats = 384
  float* cstA  = stats + 384;           // 8 layers x 5 floats = 40

  // ---- prep ----
  zero_stats<<<1, 512, 0, stream>>>(stats);
  lnconst<<<dim3(64, LLl), 256, 0, stream>>>(lnw, lnb, cstA);
  hipMemsetAsync(wqkvT, 0, (size_t)LLl * 704 * 256 * 2, stream);
  prep_x<<<3072, 256, 0, stream>>>(x, xb);
  prep_wt2<<<dim3(192, 1), 256, 0, stream>>>(Wp, wpT, 768, 224, 768, 256, 0, 0);
  prep_wqkv<<<dim3(1568, 1), 256, 0, stream>>>(Wq, Wk, Wv, bq, bk, bv, wqkvT, bcat);
  prep_wt2<<<dim3(64, 8), 256, 0, stream>>>(Wo, woT, 224, 224, 256, 256,
                                            (size_t)224 * 224, (size_t)256 * 256);
  prep_wt2<<<dim3(160, 8), 256, 0, stream>>>(W1, w1T, 224, 600, 256, 640,
                                             (size_t)224 * 600, (size_t)640 * 256);
  prep_wt2<<<dim3(400, 8), 256, 0, stream>>>(W2, w2T, 600, 600, 640, 640,
                                             (size_t)600 * 600, (size_t)640 * 640);
  prep_wt2<<<dim3(160, 8), 256, 0, stream>>>(W3, w3T, 600, 224, 640, 256,
                                             (size_t)600 * 224, (size_t)256 * 640);
  prep_wt2<<<dim3(2016, 1), 256, 0, stream>>>(Wf, wfT, 224, 8000, 256, 8064, 0, 0);

  // ---- proj + posenc: X = x @ Wp + bp + pe ----
  gemm_mfma<32, 64, GF_BIAS | GF_POSENC><<<dim3(4, 128), 256, 0, stream>>>(
      xb, wpT, bp, nullptr, X, 768, 224, 256,
      nullptr, nullptr, nullptr, nullptr, nullptr, nullptr, nullptr);

  for (int l = 0; l < LLl; ++l) {
    float* stA = stats + (size_t)(2 * l) * 24;
    float* stB = stats + (size_t)(2 * l + 1) * 24;
    const float* stPrev = stats + (size_t)(2 * l - 1) * 24;   // stB_{l-1}, l>=1
    const float* lnwP = lnw + (size_t)(l - 1) * SD;           // layer l-1 params
    const float* lnbP = lnb + (size_t)(l - 1) * SD;
    const float* cstP = cstA + (l - 1) * 5;
    const float* lnwL = lnw + (size_t)l * SD;
    const float* lnbL = lnb + (size_t)l * SD;

    // 1. qkv = LNLN(X) @ Wqkv + bqkv   (layer 0: plain X)
    if (l == 0) {
      gemm_mfma<64, 64, GF_BIAS><<<dim3(11, 64), 256, 0, stream>>>(
          X, wqkvT, bcat, nullptr, qkvb, 256, 672, 704,
          nullptr, nullptr, nullptr, nullptr, nullptr, nullptr, nullptr);
    } else {
      gemm_mfma<64, 64, GF_BIAS | GF_LNA2><<<dim3(11, 64), 256, 0, stream>>>(
          X, wqkvT + (size_t)l * 704 * 256, bcat + l * 672, nullptr, qkvb, 256, 672, 704,
          lnwP, lnbP, stPrev, cstP, nullptr, nullptr, nullptr);
    }
    // 2. attention
    attn_mfma<<<dim3(BB * 8, SS / 64), 256, 0, stream>>>(qkvb, obuf);
    // 3. h2a = obuf @ Wo + bo + LNLN(X); stat6 -> stA
    if (l == 0) {
      gemm_mfma<32, 64, GF_BIAS | GF_RESID | GF_STAT6><<<dim3(4, 128), 256, 0, stream>>>(
          obuf, woT, bo, X, h2a, 256, 224, 256,
          nullptr, nullptr, nullptr, nullptr, lnwL, lnbL, stA);
    } else {
      gemm_mfma<32, 64, GF_BIAS | GF_RESID | GF_LNRES2 | GF_STAT6>
          <<<dim3(4, 128), 256, 0, stream>>>(
          obuf, woT + (size_t)l * 256 * 256, bo + (size_t)l * 224, X, h2a, 256, 224, 256,
          lnwP, lnbP, stPrev, cstP, lnwL, lnbL, stA);
    }
    // 4. f1 = relu(LN(h2a; stA) @ W1 + b1)
    gemm_mfma<64, 64, GF_BIAS | GF_RELU | GF_LNA><<<dim3(10, 64), 256, 0, stream>>>(
        h2a, w1T + (size_t)l * 640 * 256, b1 + (size_t)l * 600, nullptr, f1, 256, 600, 640,
        lnwL, lnbL, stA, nullptr, nullptr, nullptr, nullptr);
    // 5. f2 = relu(f1 @ W2 + b2)
    gemm_mfma<64, 64, GF_BIAS | GF_RELU><<<dim3(10, 64), 256, 0, stream>>>(
        f1, w2T + (size_t)l * 640 * 640, b2 + (size_t)l * 600, nullptr, f2, 640, 600, 640,
        nullptr, nullptr, nullptr, nullptr, nullptr, nullptr, nullptr);
    // 6. X = f2 @ W3 + b3 + LN(h2a; stA); stat6 -> stB
    gemm_mfma<32, 64, GF_BIAS | GF_RESID | GF_LNRES | GF_STAT6>
        <<<dim3(4, 128), 256, 0, stream>>>(
        f2, w3T + (size_t)l * 256 * 640, b3 + (size_t)l * 224, h2a, X, 640, 224, 256,
        lnwL, lnbL, stA, nullptr, lnwL, lnbL, stB);
  }

  // ---- hF = LNLN(X; stB7), logits, softmax ----
  ln2mat<<<512, 256, 0, stream>>>(X, lnw + (size_t)7 * SD, lnb + (size_t)7 * SD,
                                  stats + (size_t)15 * 24, cstA + 7 * 5, h2a);
  gemm_mfma<128, 128, GF_BIAS | GF_F32OUT | GF_SWAP><<<dim3(32, 63), 256, 0, stream>>>(
      h2a, wfT, bf, nullptr, (float*)d_out, 256, 8000, 8000,
      nullptr, nullptr, nullptr, nullptr, nullptr, nullptr, nullptr);
  softmax_rows<<<4096, 256, 0, stream>>>((float*)d_out);
}

// Round 9
// 1274.275 us; speedup vs baseline: 1.3361x; 1.0534x over previous
//
#include <hip/hip_runtime.h>
#include <math.h>

#define GF_BIAS   1
#define GF_RELU   2
#define GF_RESID  4
#define GF_POSENC 8
#define GF_F32OUT 16
#define GF_STAT6  32
#define GF_SWAP   64
#define GF_LNA    128
#define GF_LNA2   256
#define GF_LNRES  512
#define GF_LNRES2 1024

namespace {
constexpr int BB = 4, SS = 1024, DD = 224, FFF = 600, VV = 8000, LLl = 8;
constexpr int SD = SS * DD;  // 229376
constexpr float INV_SD = 1.0f / (float)SD;

// workspace layout, bf16 element offsets
constexpr size_t WP   = 0;                         // [256][768]
constexpr size_t WQKV = WP + (size_t)256 * 768;    // L x [704][256]
constexpr size_t WO   = WQKV + (size_t)LLl * 704 * 256;
constexpr size_t W1T  = WO + (size_t)LLl * 256 * 256;
constexpr size_t W2T  = W1T + (size_t)LLl * 640 * 256;
constexpr size_t W3T  = W2T + (size_t)LLl * 640 * 640;
constexpr size_t WFT  = W3T + (size_t)LLl * 256 * 640;   // [8064][256]
constexpr size_t HB   = WFT + (size_t)8064 * 256;        // X (pre-LN state)
constexpr size_t H2B  = HB + (size_t)4096 * 256;         // h2a / hF
constexpr size_t OBUF = H2B + (size_t)4096 * 256;
constexpr size_t BIG  = OBUF + (size_t)4096 * 256;       // xb | qkv
constexpr size_t ENDB = BIG + (size_t)2 * 4096 * 640;
constexpr size_t FBYTE = ENDB * 2;                       // float region byte offset
}

using short8 = __attribute__((ext_vector_type(8))) short;
using f32x4  = __attribute__((ext_vector_type(4))) float;

__device__ __forceinline__ float bits2f(unsigned u) {
  union { unsigned u; float f; } v; v.u = u; return v.f;
}
__device__ __forceinline__ unsigned short f2b(float f) {
  union { float f; unsigned u; } v; v.f = f;
  unsigned r = v.u + 0x7FFFu + ((v.u >> 16) & 1u);
  return (unsigned short)(r >> 16);
}
__device__ __forceinline__ float b2f(unsigned short b) {
  return bits2f((unsigned)b << 16);
}

// LN-transform 8 bf16 elements (one 16B chunk) with per-element w,b.
__device__ __forceinline__ uint4 ln8(uint4 raw, const float* __restrict__ wp,
                                     const float* __restrict__ bp,
                                     float mu1, float rs1, float mu2, float rs2,
                                     bool dbl) {
  float4 w0 = *(const float4*)wp, w1v = *(const float4*)(wp + 4);
  float4 b0 = *(const float4*)bp, b1v = *(const float4*)(bp + 4);
  float wv[8] = {w0.x, w0.y, w0.z, w0.w, w1v.x, w1v.y, w1v.z, w1v.w};
  float bv[8] = {b0.x, b0.y, b0.z, b0.w, b1v.x, b1v.y, b1v.z, b1v.w};
  const unsigned* u = (const unsigned*)&raw;
  uint4 out;
  unsigned* ou = (unsigned*)&out;
#pragma unroll
  for (int q = 0; q < 4; ++q) {
    float x0 = bits2f(u[q] << 16), x1 = bits2f(u[q] & 0xFFFF0000u);
    float y0 = (x0 - mu1) * rs1 * wv[q * 2] + bv[q * 2];
    float y1 = (x1 - mu1) * rs1 * wv[q * 2 + 1] + bv[q * 2 + 1];
    if (dbl) {
      y0 = (y0 - mu2) * rs2 * wv[q * 2] + bv[q * 2];
      y1 = (y1 - mu2) * rs2 * wv[q * 2 + 1] + bv[q * 2 + 1];
    }
    ou[q] = (unsigned)f2b(y0) | ((unsigned)f2b(y1) << 16);
  }
  return out;
}

// ---------------------------------------------------------------------------
// bf16 MFMA GEMM with fused LN transforms and 6-sum stat epilogue.
// ---------------------------------------------------------------------------
template <int BM, int BN, int FLAGS>
__global__ __launch_bounds__(256) void gemm_mfma(
    const unsigned short* __restrict__ A, const unsigned short* __restrict__ Bt,
    const float* __restrict__ bias, const unsigned short* __restrict__ Rz,
    void* __restrict__ Cout, int Kp, int N, int ldc,
    const float* __restrict__ lnwT, const float* __restrict__ lnbT,
    const float* __restrict__ stIn, const float* __restrict__ cst,
    const float* __restrict__ lnwS, const float* __restrict__ lnbS,
    float* __restrict__ statOut)
{
  constexpr bool HASLNA = (FLAGS & (GF_LNA | GF_LNA2)) != 0;
  constexpr bool HASLNR = (FLAGS & (GF_LNRES | GF_LNRES2)) != 0;
  constexpr bool DBLA = (FLAGS & GF_LNA2) != 0;
  constexpr bool DBLR = (FLAGS & GF_LNRES2) != 0;
  constexpr int MR = BM / 32, NR = BN / 32;
  constexpr int APT = BM / 32, BPT = BN / 32;
  constexpr int ABY = BM * 128, BBY = BN * 128;   // bytes (BK=64)
  constexpr int CBY = (FLAGS & GF_F32OUT) ? (64 * (BN + 4) * 4) : (BM * (BN + 8) * 2);
  constexpr int SBY = (ABY + BBY) > CBY ? (ABY + BBY) : CBY;
  __shared__ __align__(16) char smem[SBY];
  __shared__ float red6[24];
  unsigned short* sA = (unsigned short*)smem;
  unsigned short* sB = (unsigned short*)(smem + ABY);
  const int t = threadIdx.x;
  const int l = t & 63;
  const int w = t >> 6, wr = w >> 1, wc = w & 1;
  const int m0 = ((FLAGS & GF_SWAP) ? blockIdx.x : blockIdx.y) * BM;
  const int n0 = ((FLAGS & GF_SWAP) ? blockIdx.y : blockIdx.x) * BN;
  const int nk = Kp >> 6;

  float mu1 = 0.f, rs1 = 1.f, mu2 = 0.f, rs2 = 1.f;
  if constexpr (HASLNA || HASLNR) {
    const float* st = stIn + (m0 >> 10) * 6;
    const float s0 = st[0], s1 = st[1];
    mu1 = s0 * INV_SD;
    rs1 = rsqrtf(s1 * INV_SD - mu1 * mu1 + 1e-5f);
    if constexpr (DBLA || DBLR) {
      const float swx = st[2], sw2x = st[3], sw2x2 = st[4], swbx = st[5];
      mu2 = (rs1 * (swx - mu1 * cst[0]) + cst[2]) * INV_SD;
      const float ey2 = (rs1 * rs1 * (sw2x2 - 2.f * mu1 * sw2x + mu1 * mu1 * cst[1]) +
                         2.f * rs1 * (swbx - mu1 * cst[4]) + cst[3]) * INV_SD;
      rs2 = rsqrtf(ey2 - mu2 * mu2 + 1e-5f);
    }
  }

  int aoff[APT], ar[APT], ac[APT];
#pragma unroll
  for (int p = 0; p < APT; ++p) {
    int off = (t + p * 256) * 16;
    int r = off >> 7;
    int cb = (off & 127) ^ ((r & 7) << 4);
    aoff[p] = off; ar[p] = r; ac[p] = cb >> 1;
  }
  int boff[BPT], br[BPT], bc[BPT];
#pragma unroll
  for (int p = 0; p < BPT; ++p) {
    int off = (t + p * 256) * 16;
    int r = off >> 7;
    int cb = (off & 127) ^ ((r & 7) << 4);
    boff[p] = off; br[p] = r; bc[p] = cb >> 1;
  }

  const unsigned short* Ab = A + (size_t)m0 * Kp;
  const unsigned short* Bb = Bt + (size_t)n0 * Kp;

  auto loadA = [&](int p, int kb) -> uint4 {
    const int d0 = kb + ac[p];
    uint4 raw = *(const uint4*)(Ab + (size_t)ar[p] * Kp + d0);
    if constexpr (HASLNA) {
      if (d0 >= DD) return make_uint4(0u, 0u, 0u, 0u);
      const int srow = (m0 + ar[p]) & (SS - 1);
      raw = ln8(raw, lnwT + (size_t)srow * DD + d0, lnbT + (size_t)srow * DD + d0,
                mu1, rs1, mu2, rs2, DBLA);
    }
    return raw;
  };

  uint4 ra[APT], rb[BPT];
#pragma unroll
  for (int p = 0; p < APT; ++p) ra[p] = loadA(p, 0);
#pragma unroll
  for (int p = 0; p < BPT; ++p) rb[p] = *(const uint4*)(Bb + (size_t)br[p] * Kp + bc[p]);

  f32x4 acc[MR][NR];
#pragma unroll
  for (int i = 0; i < MR; ++i)
#pragma unroll
    for (int j = 0; j < NR; ++j) acc[i][j] = {0.f, 0.f, 0.f, 0.f};

  for (int kt = 0; kt < nk; ++kt) {
#pragma unroll
    for (int p = 0; p < APT; ++p) *(uint4*)((char*)sA + aoff[p]) = ra[p];
#pragma unroll
    for (int p = 0; p < BPT; ++p) *(uint4*)((char*)sB + boff[p]) = rb[p];
    __syncthreads();
    if (kt + 1 < nk) {
      const int k1 = (kt + 1) * 64;
#pragma unroll
      for (int p = 0; p < APT; ++p) ra[p] = loadA(p, k1);
#pragma unroll
      for (int p = 0; p < BPT; ++p) rb[p] = *(const uint4*)(Bb + (size_t)br[p] * Kp + k1 + bc[p]);
    }
#pragma unroll
    for (int kh = 0; kh < 2; ++kh) {
      short8 af[MR], bfg[NR];
#pragma unroll
      for (int mi = 0; mi < MR; ++mi) {
        const int row = wr * (BM / 2) + mi * 16 + (l & 15);
        const int byte = (row * 128 + kh * 64 + (l >> 4) * 16) ^ ((row & 7) << 4);
        af[mi] = *(const short8*)((const char*)sA + byte);
      }
#pragma unroll
      for (int ni = 0; ni < NR; ++ni) {
        const int row = wc * (BN / 2) + ni * 16 + (l & 15);
        const int byte = (row * 128 + kh * 64 + (l >> 4) * 16) ^ ((row & 7) << 4);
        bfg[ni] = *(const short8*)((const char*)sB + byte);
      }
#pragma unroll
      for (int mi = 0; mi < MR; ++mi)
#pragma unroll
        for (int ni = 0; ni < NR; ++ni)
          acc[mi][ni] = __builtin_amdgcn_mfma_f32_16x16x32_bf16(af[mi], bfg[ni], acc[mi][ni], 0, 0, 0);
    }
    __syncthreads();
  }

  const int cl = l & 15, rl0 = (l >> 4) * 4;

  if constexpr ((FLAGS & GF_F32OUT) != 0) {
    constexpr int CST = BN + 4;
    float* Cs = (float*)smem;
    constexpr int NCH = BM / 64;
#pragma unroll
    for (int c = 0; c < NCH; ++c) {
      __syncthreads();
      if ((wr * (BM / 2)) / 64 == c) {
#pragma unroll
        for (int mi = 0; mi < MR; ++mi)
#pragma unroll
          for (int ni = 0; ni < NR; ++ni)
#pragma unroll
            for (int j = 0; j < 4; ++j) {
              const int rl = wr * (BM / 2) + mi * 16 + rl0 + j - c * 64;
              const int cc = wc * (BN / 2) + ni * 16 + cl;
              const int gn = n0 + cc;
              float v = acc[mi][ni][j];
              if ((FLAGS & GF_BIAS) && gn < N) v += bias[gn];
              Cs[rl * CST + cc] = v;
            }
      }
      __syncthreads();
      constexpr int CPR = BN / 4;
      constexpr int NIT = (64 * CPR) / 256;
#pragma unroll
      for (int i = 0; i < NIT; ++i) {
        const int ch = i * 256 + t;
        const int rr = ch / CPR, c4 = ch % CPR;
        const int gn = n0 + c4 * 4;
        const size_t gmr = (size_t)(m0 + c * 64 + rr);
        if (gn + 3 < N) {
          *(float4*)&((float*)Cout)[gmr * ldc + gn] = *(const float4*)&Cs[rr * CST + c4 * 4];
        } else {
#pragma unroll
          for (int c2 = 0; c2 < 4; ++c2)
            if (gn + c2 < N) ((float*)Cout)[gmr * ldc + gn + c2] = Cs[rr * CST + c4 * 4 + c2];
        }
      }
    }
  } else {
    constexpr int CST = BN + 8;
    unsigned short* Cs = (unsigned short*)smem;
    float ls0 = 0.f, ls1 = 0.f, ls2 = 0.f, ls3 = 0.f, ls4 = 0.f, ls5 = 0.f;
#pragma unroll
    for (int mi = 0; mi < MR; ++mi)
#pragma unroll
      for (int ni = 0; ni < NR; ++ni)
#pragma unroll
        for (int j = 0; j < 4; ++j) {
          const int rl = wr * (BM / 2) + mi * 16 + rl0 + j;
          const int cc = wc * (BN / 2) + ni * 16 + cl;
          const int gm = m0 + rl, gn = n0 + cc;
          const int srow = gm & (SS - 1);
          float v = acc[mi][ni][j];
          if ((FLAGS & GF_BIAS) && gn < N) v += bias[gn];
          if constexpr ((FLAGS & GF_RESID) != 0) {
            if constexpr (HASLNR) {
              if (gn < N) {
                float rv = b2f(Rz[(size_t)gm * ldc + gn]);
                const float wE = lnwT[(size_t)srow * DD + gn];
                const float bE = lnbT[(size_t)srow * DD + gn];
                rv = (rv - mu1) * rs1 * wE + bE;
                if constexpr (DBLR) rv = (rv - mu2) * rs2 * wE + bE;
                v += rv;
              }
            } else {
              v += b2f(Rz[(size_t)gm * ldc + gn]);
            }
          }
          if ((FLAGS & GF_POSENC) && gn < N) {
            float freq = expf(-(2.0f * gn / 224.0f) * 9.210340371976184f);
            float ang = (float)srow * freq;
            v += (gn & 1) ? cosf(ang) : sinf(ang);
          }
          if (FLAGS & GF_RELU) v = fmaxf(v, 0.f);
          if constexpr ((FLAGS & GF_STAT6) != 0) {
            if (gn < N) {
              const float wS = lnwS[(size_t)srow * DD + gn];
              const float bS = lnbS[(size_t)srow * DD + gn];
              const float wv = wS * v;
              ls0 += v; ls1 += v * v; ls2 += wv; ls3 += wS * wv;
              ls4 += wv * wv; ls5 += bS * wv;
            }
          }
          Cs[rl * CST + cc] = f2b(v);
        }
    __syncthreads();
#pragma unroll
    for (int it = 0; it < BM / 32; ++it) {
      const int rr = it * 32 + (t >> 3), qq = t & 7;
      const size_t gm = (size_t)(m0 + rr);
      *(uint4*)&((unsigned short*)Cout)[gm * ldc + n0 + qq * 8] =
          *(const uint4*)&Cs[rr * CST + qq * 8];
    }
    if constexpr ((FLAGS & GF_STAT6) != 0) {
      float s[6] = {ls0, ls1, ls2, ls3, ls4, ls5};
#pragma unroll
      for (int o2 = 32; o2 > 0; o2 >>= 1)
#pragma unroll
        for (int j = 0; j < 6; ++j) s[j] += __shfl_down(s[j], o2);
      if (l == 0)
#pragma unroll
        for (int j = 0; j < 6; ++j) red6[w * 6 + j] = s[j];
      __syncthreads();
      if (t < 6) {
        const float tot = red6[t] + red6[6 + t] + red6[12 + t] + red6[18 + t];
        atomicAdd(&statOut[(m0 >> 10) * 6 + t], tot);
      }
    }
  }
}

// ---------------------------------------------------------------------------
// Fused FFN: one block = 16 rows; f1,f2 live in LDS; B-fragments streamed from
// L2-resident weight panels. X = relu(relu(LN(h2a)@W1+b1)@W2+b2)@W3 + b3 +
// LN(h2a); 6-sum stats -> stB.
// ---------------------------------------------------------------------------
__global__ __launch_bounds__(256) void ffn_fused(
    const unsigned short* __restrict__ h2a,
    const unsigned short* __restrict__ W1t, const unsigned short* __restrict__ W2t,
    const unsigned short* __restrict__ W3t,
    const float* __restrict__ b1, const float* __restrict__ b2,
    const float* __restrict__ b3,
    const float* __restrict__ lnw, const float* __restrict__ lnb,
    const float* __restrict__ stA, float* __restrict__ statOut,
    unsigned short* __restrict__ Xout)
{
  __shared__ __align__(16) unsigned short sA[16 * 280];
  __shared__ __align__(16) unsigned short f1s[16 * 648];
  __shared__ __align__(16) unsigned short f2s[16 * 648];
  __shared__ float red6[24];
  const int t = threadIdx.x;
  const int l = t & 63, w = t >> 6;
  const int cl = l & 15, g8 = (l >> 4) * 8, rl0 = (l >> 4) * 4;
  const int m0 = blockIdx.x * 16;
  const float* st = stA + (m0 >> 10) * 6;
  const float mu1 = st[0] * INV_SD;
  const float rs1 = rsqrtf(st[1] * INV_SD - mu1 * mu1 + 1e-5f);

  // stage sA = LN(h2a rows m0..m0+15); cols >= 224 zero
  for (int c = t; c < 512; c += 256) {
    const int r = c >> 5, col = (c & 31) * 8;
    uint4 v = make_uint4(0u, 0u, 0u, 0u);
    if (col < DD) {
      const int srow = (m0 + r) & (SS - 1);
      uint4 raw = *(const uint4*)(h2a + (size_t)(m0 + r) * 256 + col);
      v = ln8(raw, lnw + (size_t)srow * DD + col, lnb + (size_t)srow * DD + col,
              mu1, rs1, 0.f, 1.f, false);
    }
    *(uint4*)(sA + r * 280 + col) = v;
  }
  __syncthreads();

  // phase 1: f1 = relu(LN(h2a) @ W1^T + b1), wave n-slice 160
  {
    f32x4 acc[10];
#pragma unroll
    for (int i = 0; i < 10; ++i) acc[i] = {0.f, 0.f, 0.f, 0.f};
    for (int ks = 0; ks < 8; ++ks) {
      const short8 af = *(const short8*)(sA + cl * 280 + ks * 32 + g8);
#pragma unroll
      for (int ni = 0; ni < 10; ++ni) {
        const int n = w * 160 + ni * 16 + cl;
        const short8 bf = *(const short8*)(W1t + (size_t)n * 256 + ks * 32 + g8);
        acc[ni] = __builtin_amdgcn_mfma_f32_16x16x32_bf16(af, bf, acc[ni], 0, 0, 0);
      }
    }
#pragma unroll
    for (int ni = 0; ni < 10; ++ni) {
      const int col = w * 160 + ni * 16 + cl;
      const float bias = (col < FFF) ? b1[col] : 0.f;
#pragma unroll
      for (int j = 0; j < 4; ++j)
        f1s[(rl0 + j) * 648 + col] = f2b(fmaxf(acc[ni][j] + bias, 0.f));
    }
  }
  __syncthreads();

  // phase 2: f2 = relu(f1 @ W2^T + b2)
  {
    f32x4 acc[10];
#pragma unroll
    for (int i = 0; i < 10; ++i) acc[i] = {0.f, 0.f, 0.f, 0.f};
    for (int ks = 0; ks < 20; ++ks) {
      const short8 af = *(const short8*)(f1s + cl * 648 + ks * 32 + g8);
#pragma unroll
      for (int ni = 0; ni < 10; ++ni) {
        const int n = w * 160 + ni * 16 + cl;
        const short8 bf = *(const short8*)(W2t + (size_t)n * 640 + ks * 32 + g8);
        acc[ni] = __builtin_amdgcn_mfma_f32_16x16x32_bf16(af, bf, acc[ni], 0, 0, 0);
      }
    }
#pragma unroll
    for (int ni = 0; ni < 10; ++ni) {
      const int col = w * 160 + ni * 16 + cl;
      const float bias = (col < FFF) ? b2[col] : 0.f;
#pragma unroll
      for (int j = 0; j < 4; ++j)
        f2s[(rl0 + j) * 648 + col] = f2b(fmaxf(acc[ni][j] + bias, 0.f));
    }
  }
  __syncthreads();

  // phase 3: X = f2 @ W3^T + b3 + LN(h2a) (fp32 from global); stats -> stB
  float s6[6] = {0.f, 0.f, 0.f, 0.f, 0.f, 0.f};
  {
    f32x4 acc[4];
#pragma unroll
    for (int i = 0; i < 4; ++i) acc[i] = {0.f, 0.f, 0.f, 0.f};
    for (int ks = 0; ks < 20; ++ks) {
      const short8 af = *(const short8*)(f2s + cl * 648 + ks * 32 + g8);
#pragma unroll
      for (int ni = 0; ni < 4; ++ni) {
        const int n = w * 64 + ni * 16 + cl;
        const short8 bf = *(const short8*)(W3t + (size_t)n * 640 + ks * 32 + g8);
        acc[ni] = __builtin_amdgcn_mfma_f32_16x16x32_bf16(af, bf, acc[ni], 0, 0, 0);
      }
    }
    unsigned short* Cs = sA;  // reuse (stride 280), safe: last read phase 1
#pragma unroll
    for (int ni = 0; ni < 4; ++ni) {
      const int col = w * 64 + ni * 16 + cl;
      const float bias = (col < DD) ? b3[col] : 0.f;
#pragma unroll
      for (int j = 0; j < 4; ++j) {
        const int gm = m0 + rl0 + j;
        const int srow = gm & (SS - 1);
        float v = acc[ni][j] + bias;
        if (col < DD) {
          const float wE = lnw[(size_t)srow * DD + col];
          const float bE = lnb[(size_t)srow * DD + col];
          v += (b2f(h2a[(size_t)gm * 256 + col]) - mu1) * rs1 * wE + bE;
          const float wv = wE * v;
          s6[0] += v; s6[1] += v * v; s6[2] += wv; s6[3] += wE * wv;
          s6[4] += wv * wv; s6[5] += bE * wv;
        }
        Cs[(rl0 + j) * 280 + col] = f2b(v);
      }
    }
  }
#pragma unroll
  for (int o2 = 32; o2 > 0; o2 >>= 1)
#pragma unroll
    for (int j2 = 0; j2 < 6; ++j2) s6[j2] += __shfl_down(s6[j2], o2);
  if (l == 0)
#pragma unroll
    for (int j2 = 0; j2 < 6; ++j2) red6[w * 6 + j2] = s6[j2];
  __syncthreads();
  if (t < 6)
    atomicAdd(&statOut[(m0 >> 10) * 6 + t],
              red6[t] + red6[6 + t] + red6[12 + t] + red6[18 + t]);
  for (int c = t; c < 512; c += 256) {
    const int r = c >> 5, col = (c & 31) * 8;
    *(uint4*)(Xout + (size_t)(m0 + r) * 256 + col) = *(const uint4*)(sA + r * 280 + col);
  }
}

__global__ void zero_stats(float* __restrict__ st)
{
  if (threadIdx.x < 424) st[threadIdx.x] = 0.f;
}

// Per-layer LN constants: Sw, Sw2, Sb, Sb2, Swb. Grid (64, L).
__global__ __launch_bounds__(256) void lnconst(const float* __restrict__ lnw,
                                               const float* __restrict__ lnb,
                                               float* __restrict__ cst)
{
  const int ll = blockIdx.y, g = blockIdx.x;
  const float* wv = lnw + (size_t)ll * SD + g * 3584;
  const float* bv = lnb + (size_t)ll * SD + g * 3584;
  float s[5] = {0.f, 0.f, 0.f, 0.f, 0.f};
  for (int c = threadIdx.x * 4; c < 3584; c += 1024) {
    float4 w4 = *(const float4*)(wv + c);
    float4 b4 = *(const float4*)(bv + c);
    const float* wf = (const float*)&w4;
    const float* bf2 = (const float*)&b4;
#pragma unroll
    for (int e = 0; e < 4; ++e) {
      const float ww = wf[e], bb = bf2[e];
      s[0] += ww; s[1] += ww * ww; s[2] += bb; s[3] += bb * bb; s[4] += ww * bb;
    }
  }
#pragma unroll
  for (int o2 = 32; o2 > 0; o2 >>= 1)
#pragma unroll
    for (int j = 0; j < 5; ++j) s[j] += __shfl_down(s[j], o2);
  __shared__ float red[4][5];
  if ((threadIdx.x & 63) == 0)
#pragma unroll
    for (int j = 0; j < 5; ++j) red[threadIdx.x >> 6][j] = s[j];
  __syncthreads();
  if (threadIdx.x < 5) {
    const float tot = red[0][threadIdx.x] + red[1][threadIdx.x] +
                      red[2][threadIdx.x] + red[3][threadIdx.x];
    atomicAdd(&cst[ll * 5 + threadIdx.x], tot);
  }
}

// Materialize hF = LN(LN(X)) for the logits GEMM (analytic LN2 stats).
__global__ __launch_bounds__(256) void ln2mat(
    const unsigned short* __restrict__ X, const float* __restrict__ lnw,
    const float* __restrict__ lnb, const float* __restrict__ st,
    const float* __restrict__ cst, unsigned short* __restrict__ Y)
{
  const int chunk = blockIdx.x * 256 + threadIdx.x;   // 131072 = 4096*32
  const int r = chunk >> 5, cc = chunk & 31;
  if (cc >= 28) {
    *(uint4*)(Y + (size_t)r * 256 + cc * 8) = make_uint4(0u, 0u, 0u, 0u);
    return;
  }
  const int b = r >> 10, srow = r & 1023;
  const float* s = st + b * 6;
  const float mu1 = s[0] * INV_SD;
  const float rs1 = rsqrtf(s[1] * INV_SD - mu1 * mu1 + 1e-5f);
  const float mu2 = (rs1 * (s[2] - mu1 * cst[0]) + cst[2]) * INV_SD;
  const float ey2 = (rs1 * rs1 * (s[4] - 2.f * mu1 * s[3] + mu1 * mu1 * cst[1]) +
                     2.f * rs1 * (s[5] - mu1 * cst[4]) + cst[3]) * INV_SD;
  const float rs2 = rsqrtf(ey2 - mu2 * mu2 + 1e-5f);
  uint4 raw = *(const uint4*)(X + (size_t)r * 256 + cc * 8);
  uint4 out = ln8(raw, lnw + (size_t)srow * DD + cc * 8, lnb + (size_t)srow * DD + cc * 8,
                  mu1, rs1, mu2, rs2, true);
  *(uint4*)(Y + (size_t)r * 256 + cc * 8) = out;
}

// ---------------------------------------------------------------------------
// Weight prep via LDS 32x32 transpose: fp32 [K][N] -> bf16 [Np][Kp] padded.
// ---------------------------------------------------------------------------
__global__ __launch_bounds__(256) void prep_wt2(
    const float* __restrict__ W, unsigned short* __restrict__ O,
    int K, int N, int Kp, int Np, size_t sW, size_t sO)
{
  const int ll = blockIdx.y;
  const int tx = Np >> 5;
  const int tn = blockIdx.x % tx, tk = blockIdx.x / tx;
  const int n0 = tn * 32, k0 = tk * 32;
  const float* Wl = W + sW * ll;
  unsigned short* Ol = O + sO * ll;
  __shared__ float T[32][36];
  {
    const int r = threadIdx.x >> 3, c4 = (threadIdx.x & 7) * 4;
    const int k = k0 + r, n = n0 + c4;
    float4 v = make_float4(0.f, 0.f, 0.f, 0.f);
    if (k < K) {
      if (n + 3 < N) v = *(const float4*)&Wl[(size_t)k * N + n];
      else {
        if (n + 0 < N) v.x = Wl[(size_t)k * N + n + 0];
        if (n + 1 < N) v.y = Wl[(size_t)k * N + n + 1];
        if (n + 2 < N) v.z = Wl[(size_t)k * N + n + 2];
        if (n + 3 < N) v.w = Wl[(size_t)k * N + n + 3];
      }
    }
    *(float4*)&T[r][c4] = v;
  }
  __syncthreads();
  {
    const int nl = threadIdx.x >> 3, k4 = (threadIdx.x & 7) * 4;
    ushort4 u;
    u.x = f2b(T[k4 + 0][nl]); u.y = f2b(T[k4 + 1][nl]);
    u.z = f2b(T[k4 + 2][nl]); u.w = f2b(T[k4 + 3][nl]);
    *(ushort4*)&Ol[(size_t)(n0 + nl) * Kp + k0 + k4] = u;
  }
}

// Coalesced-read qkv weight repack (dest pre-zeroed so pads stay 0).
__global__ void prep_wqkv(const float* __restrict__ Wq, const float* __restrict__ Wk,
                          const float* __restrict__ Wv, const float* __restrict__ bq,
                          const float* __restrict__ bk, const float* __restrict__ bv,
                          unsigned short* __restrict__ O, float* __restrict__ bcat)
{
  const int idx = blockIdx.x * 256 + threadIdx.x;
  if (idx < LLl * 8 * 224 * 28) {
    const int kk = idx % 28;
    const int d  = (idx / 28) % 224;
    const int h  = (idx / (28 * 224)) % 8;
    const int ll = idx / (28 * 224 * 8);
    const int col = h * 28 + kk;
    const size_t base = (size_t)ll * (704 * 256);
    O[base + (size_t)col * 256 + d]         = f2b(Wq[idx]);
    O[base + (size_t)(224 + col) * 256 + d] = f2b(Wk[idx]);
    O[base + (size_t)(448 + col) * 256 + d] = f2b(Wv[idx]);
  }
  if (idx < LLl * 8 * 28) {
    const int kk = idx % 28;
    const int h  = (idx / 28) % 8;
    const int ll = idx / (28 * 8);
    const int col = h * 28 + kk;
    bcat[ll * 672 + col]       = bq[idx];
    bcat[ll * 672 + 224 + col] = bk[idx];
    bcat[ll * 672 + 448 + col] = bv[idx];
  }
}

__global__ void prep_x(const float* __restrict__ x, unsigned short* __restrict__ xb)
{
  const size_t i = ((size_t)blockIdx.x * 256 + threadIdx.x) * 4;
  float4 v = *(const float4*)(x + i);
  ushort4 o;
  o.x = f2b(v.x); o.y = f2b(v.y); o.z = f2b(v.z); o.w = f2b(v.w);
  *(ushort4*)(xb + i) = o;
}

// ---------------------------------------------------------------------------
// MFMA flash attention (unchanged).
// ---------------------------------------------------------------------------
__global__ __launch_bounds__(256) void attn_mfma(const unsigned short* __restrict__ qkv,
                                                 unsigned short* __restrict__ o)
{
  const int bh = blockIdx.x;
  const int qt = (int)gridDim.y - 1 - (int)blockIdx.y;
  const int b = bh >> 3, h = bh & 7;
  const int tid = threadIdx.x;
  const int w = tid >> 6, l = tid & 63;
  const int cl = l & 15, g = l >> 4;
  const int qbase = qt * 64 + w * 16;
  const float scale = 0.1889822365046136f;  // 1/sqrt(28)

  __shared__ unsigned short Ks[32 * 40];
  __shared__ unsigned short Vt[32 * 40];
  __shared__ unsigned short Ps[4][16 * 40];

  short8 aq;
  {
    const unsigned short* qp = qkv + ((size_t)(b * SS + qbase + cl)) * 704 + h * 28;
#pragma unroll
    for (int e = 0; e < 8; ++e) {
      const int d = g * 8 + e;
      ((unsigned short*)&aq)[e] = (d < 28) ? qp[d] : (unsigned short)0;
    }
  }

  f32x4 o0 = {0.f, 0.f, 0.f, 0.f}, o1 = {0.f, 0.f, 0.f, 0.f};
  float m[4] = {-INFINITY, -INFINITY, -INFINITY, -INFINITY};
  float lsum[4] = {0.f, 0.f, 0.f, 0.f};

  const int ntiles = qt * 2 + 2;
  const int ntw = ((qbase + 15) >> 5) + 1;

  const int sr = tid >> 3, sc4 = (tid & 7) << 2;
  const bool sact = (sc4 < 28);
  ushort4 ku = make_ushort4(0, 0, 0, 0), vu = make_ushort4(0, 0, 0, 0);
  if (sact) {
    const unsigned short* kp = qkv + ((size_t)(b * SS + sr)) * 704 + 224 + h * 28 + sc4;
    ku = *(const ushort4*)kp;
    vu = *(const ushort4*)(kp + 224);
  }

  for (int tile = 0; tile < ntiles; ++tile) {
    const int t0 = tile * 32;
    __syncthreads();
    *(ushort4*)&Ks[sr * 40 + sc4] = ku;
    Vt[(sc4 + 0) * 40 + sr] = vu.x;
    Vt[(sc4 + 1) * 40 + sr] = vu.y;
    Vt[(sc4 + 2) * 40 + sr] = vu.z;
    Vt[(sc4 + 3) * 40 + sr] = vu.w;
    __syncthreads();
    if (tile + 1 < ntiles && sact) {
      const unsigned short* kp =
          qkv + ((size_t)(b * SS + (tile + 1) * 32 + sr)) * 704 + 224 + h * 28 + sc4;
      ku = *(const ushort4*)kp;
      vu = *(const ushort4*)(kp + 224);
    }
    if (tile >= ntw) continue;

    const short8 bk0 = *(const short8*)&Ks[cl * 40 + g * 8];
    const short8 bk1 = *(const short8*)&Ks[(cl + 16) * 40 + g * 8];
    f32x4 zz = {0.f, 0.f, 0.f, 0.f};
    f32x4 s0 = __builtin_amdgcn_mfma_f32_16x16x32_bf16(aq, bk0, zz, 0, 0, 0);
    f32x4 s1 = __builtin_amdgcn_mfma_f32_16x16x32_bf16(aq, bk1, zz, 0, 0, 0);

    const bool diag = (t0 + 31 > qbase);
#pragma unroll
    for (int jj = 0; jj < 4; ++jj) {
      float v0 = s0[jj] * scale, v1 = s1[jj] * scale;
      if (diag) {
        const int qr = qbase + g * 4 + jj;
        if (t0 + cl > qr)      v0 = -INFINITY;
        if (t0 + 16 + cl > qr) v1 = -INFINITY;
      }
      float rm = fmaxf(v0, v1);
      rm = fmaxf(rm, __shfl_xor(rm, 1));
      rm = fmaxf(rm, __shfl_xor(rm, 2));
      rm = fmaxf(rm, __shfl_xor(rm, 4));
      rm = fmaxf(rm, __shfl_xor(rm, 8));
      const float mnew = fmaxf(m[jj], rm);
      const float r2 = __expf(m[jj] - mnew);
      m[jj] = mnew;
      const float e0 = __expf(v0 - mnew), e1 = __expf(v1 - mnew);
      lsum[jj] = lsum[jj] * r2 + e0 + e1;
      o0[jj] *= r2; o1[jj] *= r2;
      Ps[w][(g * 4 + jj) * 40 + cl]      = f2b(e0);
      Ps[w][(g * 4 + jj) * 40 + cl + 16] = f2b(e1);
    }
    const short8 pa  = *(const short8*)&Ps[w][cl * 40 + g * 8];
    const short8 bv0 = *(const short8*)&Vt[cl * 40 + g * 8];
    const short8 bv1 = *(const short8*)&Vt[(cl + 16) * 40 + g * 8];
    o0 = __builtin_amdgcn_mfma_f32_16x16x32_bf16(pa, bv0, o0, 0, 0, 0);
    o1 = __builtin_amdgcn_mfma_f32_16x16x32_bf16(pa, bv1, o1, 0, 0, 0);
  }

#pragma unroll
  for (int jj = 0; jj < 4; ++jj) {
    float ls = lsum[jj];
    ls += __shfl_xor(ls, 1);
    ls += __shfl_xor(ls, 2);
    ls += __shfl_xor(ls, 4);
    ls += __shfl_xor(ls, 8);
    const float inv = 1.0f / ls;
    const int row = qbase + g * 4 + jj;
    unsigned short* op = o + ((size_t)(b * SS + row)) * 256 + h * 28;
    op[cl] = f2b(o0[jj] * inv);
    if (cl < 12) op[16 + cl] = f2b(o1[jj] * inv);
  }
}

// ---------------------------------------------------------------------------
// Row softmax over V=8000, in place on d_out (fp32).
// ---------------------------------------------------------------------------
__global__ __launch_bounds__(256) void softmax_rows(float* __restrict__ logits)
{
  const int row = blockIdx.x;
  float* p = logits + (size_t)row * VV;
  __shared__ float buf[VV];
  __shared__ float red[4];
  const int tid = threadIdx.x;

  float mx = -INFINITY;
  for (int i = tid; i < VV; i += 256) { float v = p[i]; buf[i] = v; mx = fmaxf(mx, v); }
#pragma unroll
  for (int o2 = 32; o2 > 0; o2 >>= 1) mx = fmaxf(mx, __shfl_down(mx, o2));
  if ((tid & 63) == 0) red[tid >> 6] = mx;
  __syncthreads();
  mx = fmaxf(fmaxf(red[0], red[1]), fmaxf(red[2], red[3]));
  __syncthreads();

  float s = 0.f;
  for (int i = tid; i < VV; i += 256) { float e = __expf(buf[i] - mx); buf[i] = e; s += e; }
#pragma unroll
  for (int o2 = 32; o2 > 0; o2 >>= 1) s += __shfl_down(s, o2);
  if ((tid & 63) == 0) red[tid >> 6] = s;
  __syncthreads();
  s = red[0] + red[1] + red[2] + red[3];
  const float inv = 1.0f / s;
  for (int i = tid; i < VV; i += 256) p[i] = buf[i] * inv;
}

// ---------------------------------------------------------------------------
extern "C" void kernel_launch(void* const* d_in, const int* in_sizes, int n_in,
                              void* d_out, int out_size, void* d_ws, size_t ws_size,
                              hipStream_t stream) {
  const float* x   = (const float*)d_in[0];
  const float* Wp  = (const float*)d_in[1];
  const float* bp  = (const float*)d_in[2];
  const float* Wq  = (const float*)d_in[3];
  const float* bq  = (const float*)d_in[4];
  const float* Wk  = (const float*)d_in[5];
  const float* bk  = (const float*)d_in[6];
  const float* Wv  = (const float*)d_in[7];
  const float* bv  = (const float*)d_in[8];
  const float* Wo  = (const float*)d_in[9];
  const float* bo  = (const float*)d_in[10];
  const float* W1  = (const float*)d_in[11];
  const float* b1  = (const float*)d_in[12];
  const float* W2  = (const float*)d_in[13];
  const float* b2  = (const float*)d_in[14];
  const float* W3  = (const float*)d_in[15];
  const float* b3  = (const float*)d_in[16];
  const float* lnw = (const float*)d_in[17];
  const float* lnb = (const float*)d_in[18];
  const float* Wf  = (const float*)d_in[19];
  const float* bf  = (const float*)d_in[20];

  unsigned short* wsb = (unsigned short*)d_ws;
  unsigned short* wpT   = wsb + WP;
  unsigned short* wqkvT = wsb + WQKV;
  unsigned short* woT   = wsb + WO;
  unsigned short* w1T   = wsb + W1T;
  unsigned short* w2T   = wsb + W2T;
  unsigned short* w3T   = wsb + W3T;
  unsigned short* wfT   = wsb + WFT;
  unsigned short* X     = wsb + HB;    // pre-LN layer state
  unsigned short* h2a   = wsb + H2B;   // attn-block output / hF
  unsigned short* obuf  = wsb + OBUF;
  unsigned short* xb    = wsb + BIG;
  unsigned short* qkvb  = wsb + BIG;
  float* bcat  = (float*)((char*)d_ws + FBYTE);
  float* stats = bcat + LLl * 672;      // 16 slots x 24 floats = 384
  float* cstA  = stats + 384;           // 8 layers x 5 floats = 40

  // ---- prep ----
  zero_stats<<<1, 512, 0, stream>>>(stats);
  lnconst<<<dim3(64, LLl), 256, 0, stream>>>(lnw, lnb, cstA);
  hipMemsetAsync(wqkvT, 0, (size_t)LLl * 704 * 256 * 2, stream);
  prep_x<<<3072, 256, 0, stream>>>(x, xb);
  prep_wt2<<<dim3(192, 1), 256, 0, stream>>>(Wp, wpT, 768, 224, 768, 256, 0, 0);
  prep_wqkv<<<dim3(1568, 1), 256, 0, stream>>>(Wq, Wk, Wv, bq, bk, bv, wqkvT, bcat);
  prep_wt2<<<dim3(64, 8), 256, 0, stream>>>(Wo, woT, 224, 224, 256, 256,
                                            (size_t)224 * 224, (size_t)256 * 256);
  prep_wt2<<<dim3(160, 8), 256, 0, stream>>>(W1, w1T, 224, 600, 256, 640,
                                             (size_t)224 * 600, (size_t)640 * 256);
  prep_wt2<<<dim3(400, 8), 256, 0, stream>>>(W2, w2T, 600, 600, 640, 640,
                                             (size_t)600 * 600, (size_t)640 * 640);
  prep_wt2<<<dim3(160, 8), 256, 0, stream>>>(W3, w3T, 600, 224, 640, 256,
                                             (size_t)600 * 224, (size_t)256 * 640);
  prep_wt2<<<dim3(2016, 1), 256, 0, stream>>>(Wf, wfT, 224, 8000, 256, 8064, 0, 0);

  // ---- proj + posenc: X = x @ Wp + bp + pe ----
  gemm_mfma<32, 64, GF_BIAS | GF_POSENC><<<dim3(4, 128), 256, 0, stream>>>(
      xb, wpT, bp, nullptr, X, 768, 224, 256,
      nullptr, nullptr, nullptr, nullptr, nullptr, nullptr, nullptr);

  for (int l = 0; l < LLl; ++l) {
    float* stA = stats + (size_t)(2 * l) * 24;
    float* stB = stats + (size_t)(2 * l + 1) * 24;
    const float* stPrev = stats + (size_t)(2 * l - 1) * 24;   // stB_{l-1}, l>=1
    const float* lnwP = lnw + (size_t)(l - 1) * SD;           // layer l-1 params
    const float* lnbP = lnb + (size_t)(l - 1) * SD;
    const float* cstP = cstA + (l - 1) * 5;
    const float* lnwL = lnw + (size_t)l * SD;
    const float* lnbL = lnb + (size_t)l * SD;

    // 1. qkv = LNLN(X) @ Wqkv + bqkv   (layer 0: plain X)
    if (l == 0) {
      gemm_mfma<64, 64, GF_BIAS><<<dim3(11, 64), 256, 0, stream>>>(
          X, wqkvT, bcat, nullptr, qkvb, 256, 672, 704,
          nullptr, nullptr, nullptr, nullptr, nullptr, nullptr, nullptr);
    } else {
      gemm_mfma<64, 64, GF_BIAS | GF_LNA2><<<dim3(11, 64), 256, 0, stream>>>(
          X, wqkvT + (size_t)l * 704 * 256, bcat + l * 672, nullptr, qkvb, 256, 672, 704,
          lnwP, lnbP, stPrev, cstP, nullptr, nullptr, nullptr);
    }
    // 2. attention
    attn_mfma<<<dim3(BB * 8, SS / 64), 256, 0, stream>>>(qkvb, obuf);
    // 3. h2a = obuf @ Wo + bo + LNLN(X); stat6 -> stA
    if (l == 0) {
      gemm_mfma<32, 64, GF_BIAS | GF_RESID | GF_STAT6><<<dim3(4, 128), 256, 0, stream>>>(
          obuf, woT, bo, X, h2a, 256, 224, 256,
          nullptr, nullptr, nullptr, nullptr, lnwL, lnbL, stA);
    } else {
      gemm_mfma<32, 64, GF_BIAS | GF_RESID | GF_LNRES2 | GF_STAT6>
          <<<dim3(4, 128), 256, 0, stream>>>(
          obuf, woT + (size_t)l * 256 * 256, bo + (size_t)l * 224, X, h2a, 256, 224, 256,
          lnwP, lnbP, stPrev, cstP, lnwL, lnbL, stA);
    }
    // 4. fused FFN: X = relu(relu(LN(h2a)@W1)@W2)@W3 + b3 + LN(h2a); stat6 -> stB
    ffn_fused<<<256, 256, 0, stream>>>(
        h2a, w1T + (size_t)l * 640 * 256, w2T + (size_t)l * 640 * 640,
        w3T + (size_t)l * 256 * 640, b1 + (size_t)l * 600, b2 + (size_t)l * 600,
        b3 + (size_t)l * 224, lnwL, lnbL, stA, stB, X);
  }

  // ---- hF = LNLN(X; stB7), logits, softmax ----
  ln2mat<<<512, 256, 0, stream>>>(X, lnw + (size_t)7 * SD, lnb + (size_t)7 * SD,
                                  stats + (size_t)15 * 24, cstA + 7 * 5, h2a);
  gemm_mfma<128, 128, GF_BIAS | GF_F32OUT | GF_SWAP><<<dim3(32, 63), 256, 0, stream>>>(
      h2a, wfT, bf, nullptr, (float*)d_out, 256, 8000, 8000,
      nullptr, nullptr, nullptr, nullptr, nullptr, nullptr, nullptr);
  softmax_rows<<<4096, 256, 0, stream>>>((float*)d_out);
}

// Round 11
// 1219.222 us; speedup vs baseline: 1.3964x; 1.0452x over previous
//
#include <hip/hip_runtime.h>
#include <math.h>

#define GF_BIAS   1
#define GF_RELU   2
#define GF_RESID  4
#define GF_POSENC 8
#define GF_F32OUT 16
#define GF_STAT6  32
#define GF_SWAP   64
#define GF_LNA    128
#define GF_LNA2   256
#define GF_LNRES  512
#define GF_LNRES2 1024

namespace {
constexpr int BB = 4, SS = 1024, DD = 224, FFF = 600, VV = 8000, LLl = 8;
constexpr int SD = SS * DD;  // 229376
constexpr float INV_SD = 1.0f / (float)SD;

// workspace layout, bf16 element offsets
constexpr size_t WP   = 0;                         // [256][768]
constexpr size_t WQKV = WP + (size_t)256 * 768;    // L x [704][256]
constexpr size_t WO   = WQKV + (size_t)LLl * 704 * 256;
constexpr size_t W1T  = WO + (size_t)LLl * 256 * 256;
constexpr size_t W2T  = W1T + (size_t)LLl * 640 * 256;
constexpr size_t W3T  = W2T + (size_t)LLl * 640 * 640;
constexpr size_t WFT  = W3T + (size_t)LLl * 256 * 640;   // [8064][256]
constexpr size_t HB   = WFT + (size_t)8064 * 256;        // X (pre-LN state)
constexpr size_t H2B  = HB + (size_t)4096 * 256;         // h2a
constexpr size_t OBUF = H2B + (size_t)4096 * 256;
constexpr size_t BIG  = OBUF + (size_t)4096 * 256;       // xb | qkv
constexpr size_t ENDB = BIG + (size_t)2 * 4096 * 640;
constexpr size_t FBYTE = ENDB * 2;                       // float region byte offset
}

using short8 = __attribute__((ext_vector_type(8))) short;
using f32x4  = __attribute__((ext_vector_type(4))) float;

__device__ __forceinline__ float bits2f(unsigned u) {
  union { unsigned u; float f; } v; v.u = u; return v.f;
}
__device__ __forceinline__ unsigned short f2b(float f) {
  union { float f; unsigned u; } v; v.f = f;
  unsigned r = v.u + 0x7FFFu + ((v.u >> 16) & 1u);
  return (unsigned short)(r >> 16);
}
__device__ __forceinline__ float b2f(unsigned short b) {
  return bits2f((unsigned)b << 16);
}

// LN-transform 8 bf16 elements (one 16B chunk) with per-element w,b.
__device__ __forceinline__ uint4 ln8(uint4 raw, const float* __restrict__ wp,
                                     const float* __restrict__ bp,
                                     float mu1, float rs1, float mu2, float rs2,
                                     bool dbl) {
  float4 w0 = *(const float4*)wp, w1v = *(const float4*)(wp + 4);
  float4 b0 = *(const float4*)bp, b1v = *(const float4*)(bp + 4);
  float wv[8] = {w0.x, w0.y, w0.z, w0.w, w1v.x, w1v.y, w1v.z, w1v.w};
  float bv[8] = {b0.x, b0.y, b0.z, b0.w, b1v.x, b1v.y, b1v.z, b1v.w};
  const unsigned* u = (const unsigned*)&raw;
  uint4 out;
  unsigned* ou = (unsigned*)&out;
#pragma unroll
  for (int q = 0; q < 4; ++q) {
    float x0 = bits2f(u[q] << 16), x1 = bits2f(u[q] & 0xFFFF0000u);
    float y0 = (x0 - mu1) * rs1 * wv[q * 2] + bv[q * 2];
    float y1 = (x1 - mu1) * rs1 * wv[q * 2 + 1] + bv[q * 2 + 1];
    if (dbl) {
      y0 = (y0 - mu2) * rs2 * wv[q * 2] + bv[q * 2];
      y1 = (y1 - mu2) * rs2 * wv[q * 2 + 1] + bv[q * 2 + 1];
    }
    ou[q] = (unsigned)f2b(y0) | ((unsigned)f2b(y1) << 16);
  }
  return out;
}

// ---------------------------------------------------------------------------
// bf16 MFMA GEMM with fused LN transforms and 6-sum stat epilogue.
// ---------------------------------------------------------------------------
template <int BM, int BN, int FLAGS>
__global__ __launch_bounds__(256) void gemm_mfma(
    const unsigned short* __restrict__ A, const unsigned short* __restrict__ Bt,
    const float* __restrict__ bias, const unsigned short* __restrict__ Rz,
    void* __restrict__ Cout, int Kp, int N, int ldc,
    const float* __restrict__ lnwT, const float* __restrict__ lnbT,
    const float* __restrict__ stIn, const float* __restrict__ cst,
    const float* __restrict__ lnwS, const float* __restrict__ lnbS,
    float* __restrict__ statOut)
{
  constexpr bool HASLNA = (FLAGS & (GF_LNA | GF_LNA2)) != 0;
  constexpr bool HASLNR = (FLAGS & (GF_LNRES | GF_LNRES2)) != 0;
  constexpr bool DBLA = (FLAGS & GF_LNA2) != 0;
  constexpr bool DBLR = (FLAGS & GF_LNRES2) != 0;
  constexpr int MR = BM / 32, NR = BN / 32;
  constexpr int APT = BM / 32, BPT = BN / 32;
  constexpr int ABY = BM * 128, BBY = BN * 128;   // bytes (BK=64)
  constexpr int CBY = (FLAGS & GF_F32OUT) ? (64 * (BN + 4) * 4) : (BM * (BN + 8) * 2);
  constexpr int SBY = (ABY + BBY) > CBY ? (ABY + BBY) : CBY;
  __shared__ __align__(16) char smem[SBY];
  __shared__ float red6[24];
  unsigned short* sA = (unsigned short*)smem;
  unsigned short* sB = (unsigned short*)(smem + ABY);
  const int t = threadIdx.x;
  const int l = t & 63;
  const int w = t >> 6, wr = w >> 1, wc = w & 1;
  const int m0 = ((FLAGS & GF_SWAP) ? blockIdx.x : blockIdx.y) * BM;
  const int n0 = ((FLAGS & GF_SWAP) ? blockIdx.y : blockIdx.x) * BN;
  const int nk = Kp >> 6;

  float mu1 = 0.f, rs1 = 1.f, mu2 = 0.f, rs2 = 1.f;
  if constexpr (HASLNA || HASLNR) {
    const float* st = stIn + (m0 >> 10) * 6;
    const float s0 = st[0], s1 = st[1];
    mu1 = s0 * INV_SD;
    rs1 = rsqrtf(s1 * INV_SD - mu1 * mu1 + 1e-5f);
    if constexpr (DBLA || DBLR) {
      const float swx = st[2], sw2x = st[3], sw2x2 = st[4], swbx = st[5];
      mu2 = (rs1 * (swx - mu1 * cst[0]) + cst[2]) * INV_SD;
      const float ey2 = (rs1 * rs1 * (sw2x2 - 2.f * mu1 * sw2x + mu1 * mu1 * cst[1]) +
                         2.f * rs1 * (swbx - mu1 * cst[4]) + cst[3]) * INV_SD;
      rs2 = rsqrtf(ey2 - mu2 * mu2 + 1e-5f);
    }
  }

  int aoff[APT], ar[APT], ac[APT];
#pragma unroll
  for (int p = 0; p < APT; ++p) {
    int off = (t + p * 256) * 16;
    int r = off >> 7;
    int cb = (off & 127) ^ ((r & 7) << 4);
    aoff[p] = off; ar[p] = r; ac[p] = cb >> 1;
  }
  int boff[BPT], br[BPT], bc[BPT];
#pragma unroll
  for (int p = 0; p < BPT; ++p) {
    int off = (t + p * 256) * 16;
    int r = off >> 7;
    int cb = (off & 127) ^ ((r & 7) << 4);
    boff[p] = off; br[p] = r; bc[p] = cb >> 1;
  }

  const unsigned short* Ab = A + (size_t)m0 * Kp;
  const unsigned short* Bb = Bt + (size_t)n0 * Kp;

  auto loadA = [&](int p, int kb) -> uint4 {
    const int d0 = kb + ac[p];
    uint4 raw = *(const uint4*)(Ab + (size_t)ar[p] * Kp + d0);
    if constexpr (HASLNA) {
      if (d0 >= DD) return make_uint4(0u, 0u, 0u, 0u);
      const int srow = (m0 + ar[p]) & (SS - 1);
      raw = ln8(raw, lnwT + (size_t)srow * DD + d0, lnbT + (size_t)srow * DD + d0,
                mu1, rs1, mu2, rs2, DBLA);
    }
    return raw;
  };

  uint4 ra[APT], rb[BPT];
#pragma unroll
  for (int p = 0; p < APT; ++p) ra[p] = loadA(p, 0);
#pragma unroll
  for (int p = 0; p < BPT; ++p) rb[p] = *(const uint4*)(Bb + (size_t)br[p] * Kp + bc[p]);

  f32x4 acc[MR][NR];
#pragma unroll
  for (int i = 0; i < MR; ++i)
#pragma unroll
    for (int j = 0; j < NR; ++j) acc[i][j] = {0.f, 0.f, 0.f, 0.f};

  for (int kt = 0; kt < nk; ++kt) {
#pragma unroll
    for (int p = 0; p < APT; ++p) *(uint4*)((char*)sA + aoff[p]) = ra[p];
#pragma unroll
    for (int p = 0; p < BPT; ++p) *(uint4*)((char*)sB + boff[p]) = rb[p];
    __syncthreads();
    if (kt + 1 < nk) {
      const int k1 = (kt + 1) * 64;
#pragma unroll
      for (int p = 0; p < APT; ++p) ra[p] = loadA(p, k1);
#pragma unroll
      for (int p = 0; p < BPT; ++p) rb[p] = *(const uint4*)(Bb + (size_t)br[p] * Kp + k1 + bc[p]);
    }
#pragma unroll
    for (int kh = 0; kh < 2; ++kh) {
      short8 af[MR], bfg[NR];
#pragma unroll
      for (int mi = 0; mi < MR; ++mi) {
        const int row = wr * (BM / 2) + mi * 16 + (l & 15);
        const int byte = (row * 128 + kh * 64 + (l >> 4) * 16) ^ ((row & 7) << 4);
        af[mi] = *(const short8*)((const char*)sA + byte);
      }
#pragma unroll
      for (int ni = 0; ni < NR; ++ni) {
        const int row = wc * (BN / 2) + ni * 16 + (l & 15);
        const int byte = (row * 128 + kh * 64 + (l >> 4) * 16) ^ ((row & 7) << 4);
        bfg[ni] = *(const short8*)((const char*)sB + byte);
      }
#pragma unroll
      for (int mi = 0; mi < MR; ++mi)
#pragma unroll
        for (int ni = 0; ni < NR; ++ni)
          acc[mi][ni] = __builtin_amdgcn_mfma_f32_16x16x32_bf16(af[mi], bfg[ni], acc[mi][ni], 0, 0, 0);
    }
    __syncthreads();
  }

  const int cl = l & 15, rl0 = (l >> 4) * 4;

  if constexpr ((FLAGS & GF_F32OUT) != 0) {
    constexpr int CST = BN + 4;
    float* Cs = (float*)smem;
    constexpr int NCH = BM / 64;
#pragma unroll
    for (int c = 0; c < NCH; ++c) {
      __syncthreads();
      if ((wr * (BM / 2)) / 64 == c) {
#pragma unroll
        for (int mi = 0; mi < MR; ++mi)
#pragma unroll
          for (int ni = 0; ni < NR; ++ni)
#pragma unroll
            for (int j = 0; j < 4; ++j) {
              const int rl = wr * (BM / 2) + mi * 16 + rl0 + j - c * 64;
              const int cc = wc * (BN / 2) + ni * 16 + cl;
              const int gn = n0 + cc;
              float v = acc[mi][ni][j];
              if ((FLAGS & GF_BIAS) && gn < N) v += bias[gn];
              Cs[rl * CST + cc] = v;
            }
      }
      __syncthreads();
      constexpr int CPR = BN / 4;
      constexpr int NIT = (64 * CPR) / 256;
#pragma unroll
      for (int i = 0; i < NIT; ++i) {
        const int ch = i * 256 + t;
        const int rr = ch / CPR, c4 = ch % CPR;
        const int gn = n0 + c4 * 4;
        const size_t gmr = (size_t)(m0 + c * 64 + rr);
        if (gn + 3 < N) {
          *(float4*)&((float*)Cout)[gmr * ldc + gn] = *(const float4*)&Cs[rr * CST + c4 * 4];
        } else {
#pragma unroll
          for (int c2 = 0; c2 < 4; ++c2)
            if (gn + c2 < N) ((float*)Cout)[gmr * ldc + gn + c2] = Cs[rr * CST + c4 * 4 + c2];
        }
      }
    }
  } else {
    constexpr int CST = BN + 8;
    unsigned short* Cs = (unsigned short*)smem;
    float ls0 = 0.f, ls1 = 0.f, ls2 = 0.f, ls3 = 0.f, ls4 = 0.f, ls5 = 0.f;
#pragma unroll
    for (int mi = 0; mi < MR; ++mi)
#pragma unroll
      for (int ni = 0; ni < NR; ++ni)
#pragma unroll
        for (int j = 0; j < 4; ++j) {
          const int rl = wr * (BM / 2) + mi * 16 + rl0 + j;
          const int cc = wc * (BN / 2) + ni * 16 + cl;
          const int gm = m0 + rl, gn = n0 + cc;
          const int srow = gm & (SS - 1);
          float v = acc[mi][ni][j];
          if ((FLAGS & GF_BIAS) && gn < N) v += bias[gn];
          if constexpr ((FLAGS & GF_RESID) != 0) {
            if constexpr (HASLNR) {
              if (gn < N) {
                float rv = b2f(Rz[(size_t)gm * ldc + gn]);
                const float wE = lnwT[(size_t)srow * DD + gn];
                const float bE = lnbT[(size_t)srow * DD + gn];
                rv = (rv - mu1) * rs1 * wE + bE;
                if constexpr (DBLR) rv = (rv - mu2) * rs2 * wE + bE;
                v += rv;
              }
            } else {
              v += b2f(Rz[(size_t)gm * ldc + gn]);
            }
          }
          if ((FLAGS & GF_POSENC) && gn < N) {
            float freq = expf(-(2.0f * gn / 224.0f) * 9.210340371976184f);
            float ang = (float)srow * freq;
            v += (gn & 1) ? cosf(ang) : sinf(ang);
          }
          if (FLAGS & GF_RELU) v = fmaxf(v, 0.f);
          if constexpr ((FLAGS & GF_STAT6) != 0) {
            if (gn < N) {
              const float wS = lnwS[(size_t)srow * DD + gn];
              const float bS = lnbS[(size_t)srow * DD + gn];
              const float wv = wS * v;
              ls0 += v; ls1 += v * v; ls2 += wv; ls3 += wS * wv;
              ls4 += wv * wv; ls5 += bS * wv;
            }
          }
          Cs[rl * CST + cc] = f2b(v);
        }
    __syncthreads();
#pragma unroll
    for (int it = 0; it < BM / 32; ++it) {
      const int rr = it * 32 + (t >> 3), qq = t & 7;
      const size_t gm = (size_t)(m0 + rr);
      *(uint4*)&((unsigned short*)Cout)[gm * ldc + n0 + qq * 8] =
          *(const uint4*)&Cs[rr * CST + qq * 8];
    }
    if constexpr ((FLAGS & GF_STAT6) != 0) {
      float s[6] = {ls0, ls1, ls2, ls3, ls4, ls5};
#pragma unroll
      for (int o2 = 32; o2 > 0; o2 >>= 1)
#pragma unroll
        for (int j = 0; j < 6; ++j) s[j] += __shfl_down(s[j], o2);
      if (l == 0)
#pragma unroll
        for (int j = 0; j < 6; ++j) red6[w * 6 + j] = s[j];
      __syncthreads();
      if (t < 6) {
        const float tot = red6[t] + red6[6 + t] + red6[12 + t] + red6[18 + t];
        atomicAdd(&statOut[(m0 >> 10) * 6 + t], tot);
      }
    }
  }
}

// ---------------------------------------------------------------------------
// Fused FFN, 512 threads = 8 waves, n-slices 80/80/32 per wave.
// ---------------------------------------------------------------------------
__global__ __launch_bounds__(512) void ffn_fused(
    const unsigned short* __restrict__ h2a,
    const unsigned short* __restrict__ W1t, const unsigned short* __restrict__ W2t,
    const unsigned short* __restrict__ W3t,
    const float* __restrict__ b1, const float* __restrict__ b2,
    const float* __restrict__ b3,
    const float* __restrict__ lnw, const float* __restrict__ lnb,
    const float* __restrict__ stA, float* __restrict__ statOut,
    unsigned short* __restrict__ Xout)
{
  __shared__ __align__(16) unsigned short sA[16 * 280];
  __shared__ __align__(16) unsigned short f1s[16 * 648];
  __shared__ __align__(16) unsigned short f2s[16 * 648];
  __shared__ float red6[48];
  const int t = threadIdx.x;
  const int l = t & 63, w = t >> 6;           // w in [0,8)
  const int cl = l & 15, g8 = (l >> 4) * 8, rl0 = (l >> 4) * 4;
  const int m0 = blockIdx.x * 16;
  const float* st = stA + (m0 >> 10) * 6;
  const float mu1 = st[0] * INV_SD;
  const float rs1 = rsqrtf(st[1] * INV_SD - mu1 * mu1 + 1e-5f);

  // stage sA = LN(h2a rows m0..m0+15); cols >= 224 zero (512 thr = 1 pass)
  {
    const int r = t >> 5, col = (t & 31) * 8;
    uint4 v = make_uint4(0u, 0u, 0u, 0u);
    if (col < DD) {
      const int srow = (m0 + r) & (SS - 1);
      uint4 raw = *(const uint4*)(h2a + (size_t)(m0 + r) * 256 + col);
      v = ln8(raw, lnw + (size_t)srow * DD + col, lnb + (size_t)srow * DD + col,
              mu1, rs1, 0.f, 1.f, false);
    }
    *(uint4*)(sA + r * 280 + col) = v;
  }
  __syncthreads();

  // phase 1: f1 = relu(LN(h2a) @ W1^T + b1), wave n-slice 80
  {
    f32x4 acc[5];
#pragma unroll
    for (int i = 0; i < 5; ++i) acc[i] = {0.f, 0.f, 0.f, 0.f};
    for (int ks = 0; ks < 8; ++ks) {
      const short8 af = *(const short8*)(sA + cl * 280 + ks * 32 + g8);
#pragma unroll
      for (int ni = 0; ni < 5; ++ni) {
        const int n = w * 80 + ni * 16 + cl;
        const short8 bf = *(const short8*)(W1t + (size_t)n * 256 + ks * 32 + g8);
        acc[ni] = __builtin_amdgcn_mfma_f32_16x16x32_bf16(af, bf, acc[ni], 0, 0, 0);
      }
    }
#pragma unroll
    for (int ni = 0; ni < 5; ++ni) {
      const int col = w * 80 + ni * 16 + cl;
      const float bias = (col < FFF) ? b1[col] : 0.f;
#pragma unroll
      for (int j = 0; j < 4; ++j)
        f1s[(rl0 + j) * 648 + col] = f2b(fmaxf(acc[ni][j] + bias, 0.f));
    }
  }
  __syncthreads();

  // phase 2: f2 = relu(f1 @ W2^T + b2)
  {
    f32x4 acc[5];
#pragma unroll
    for (int i = 0; i < 5; ++i) acc[i] = {0.f, 0.f, 0.f, 0.f};
    for (int ks = 0; ks < 20; ++ks) {
      const short8 af = *(const short8*)(f1s + cl * 648 + ks * 32 + g8);
#pragma unroll
      for (int ni = 0; ni < 5; ++ni) {
        const int n = w * 80 + ni * 16 + cl;
        const short8 bf = *(const short8*)(W2t + (size_t)n * 640 + ks * 32 + g8);
        acc[ni] = __builtin_amdgcn_mfma_f32_16x16x32_bf16(af, bf, acc[ni], 0, 0, 0);
      }
    }
#pragma unroll
    for (int ni = 0; ni < 5; ++ni) {
      const int col = w * 80 + ni * 16 + cl;
      const float bias = (col < FFF) ? b2[col] : 0.f;
#pragma unroll
      for (int j = 0; j < 4; ++j)
        f2s[(rl0 + j) * 648 + col] = f2b(fmaxf(acc[ni][j] + bias, 0.f));
    }
  }
  __syncthreads();

  // phase 3: X = f2 @ W3^T + b3 + LN(h2a) (fp32 from global); stats -> stB
  float s6[6] = {0.f, 0.f, 0.f, 0.f, 0.f, 0.f};
  {
    f32x4 acc[2];
#pragma unroll
    for (int i = 0; i < 2; ++i) acc[i] = {0.f, 0.f, 0.f, 0.f};
    for (int ks = 0; ks < 20; ++ks) {
      const short8 af = *(const short8*)(f2s + cl * 648 + ks * 32 + g8);
#pragma unroll
      for (int ni = 0; ni < 2; ++ni) {
        const int n = w * 32 + ni * 16 + cl;
        const short8 bf = *(const short8*)(W3t + (size_t)n * 640 + ks * 32 + g8);
        acc[ni] = __builtin_amdgcn_mfma_f32_16x16x32_bf16(af, bf, acc[ni], 0, 0, 0);
      }
    }
    unsigned short* Cs = sA;  // reuse (stride 280); last read was phase 1
#pragma unroll
    for (int ni = 0; ni < 2; ++ni) {
      const int col = w * 32 + ni * 16 + cl;
      const float bias = (col < DD) ? b3[col] : 0.f;
#pragma unroll
      for (int j = 0; j < 4; ++j) {
        const int gm = m0 + rl0 + j;
        const int srow = gm & (SS - 1);
        float v = acc[ni][j] + bias;
        if (col < DD) {
          const float wE = lnw[(size_t)srow * DD + col];
          const float bE = lnb[(size_t)srow * DD + col];
          v += (b2f(h2a[(size_t)gm * 256 + col]) - mu1) * rs1 * wE + bE;
          const float wv = wE * v;
          s6[0] += v; s6[1] += v * v; s6[2] += wv; s6[3] += wE * wv;
          s6[4] += wv * wv; s6[5] += bE * wv;
        }
        Cs[(rl0 + j) * 280 + col] = f2b(v);
      }
    }
  }
#pragma unroll
  for (int o2 = 32; o2 > 0; o2 >>= 1)
#pragma unroll
    for (int j2 = 0; j2 < 6; ++j2) s6[j2] += __shfl_down(s6[j2], o2);
  if (l == 0)
#pragma unroll
    for (int j2 = 0; j2 < 6; ++j2) red6[w * 6 + j2] = s6[j2];
  __syncthreads();
  if (t < 6) {
    float tot = 0.f;
#pragma unroll
    for (int ww = 0; ww < 8; ++ww) tot += red6[ww * 6 + t];
    atomicAdd(&statOut[(m0 >> 10) * 6 + t], tot);
  }
  {
    const int r = t >> 5, col = (t & 31) * 8;
    *(uint4*)(Xout + (size_t)(m0 + r) * 256 + col) = *(const uint4*)(sA + r * 280 + col);
  }
}

// ---------------------------------------------------------------------------
// Unified weight prep (6 tensors + lnconst) in one flat-grid dispatch.
// ---------------------------------------------------------------------------
__device__ __forceinline__ void prep_wt2_body(
    const float* __restrict__ W, unsigned short* __restrict__ O,
    int K, int N, int Kp, int Np, size_t sW, size_t sO, int tile, int ll,
    float* __restrict__ T /* [32][36] */)
{
  const int tx = Np >> 5;
  const int tn = tile % tx, tk = tile / tx;
  const int n0 = tn * 32, k0 = tk * 32;
  const float* Wl = W + sW * ll;
  unsigned short* Ol = O + sO * ll;
  {
    const int r = threadIdx.x >> 3, c4 = (threadIdx.x & 7) * 4;
    const int k = k0 + r, n = n0 + c4;
    float4 v = make_float4(0.f, 0.f, 0.f, 0.f);
    if (k < K) {
      if (n + 3 < N) v = *(const float4*)&Wl[(size_t)k * N + n];
      else {
        if (n + 0 < N) v.x = Wl[(size_t)k * N + n + 0];
        if (n + 1 < N) v.y = Wl[(size_t)k * N + n + 1];
        if (n + 2 < N) v.z = Wl[(size_t)k * N + n + 2];
        if (n + 3 < N) v.w = Wl[(size_t)k * N + n + 3];
      }
    }
    *(float4*)&T[r * 36 + c4] = v;
  }
  __syncthreads();
  {
    const int nl = threadIdx.x >> 3, k4 = (threadIdx.x & 7) * 4;
    ushort4 u;
    u.x = f2b(T[(k4 + 0) * 36 + nl]); u.y = f2b(T[(k4 + 1) * 36 + nl]);
    u.z = f2b(T[(k4 + 2) * 36 + nl]); u.w = f2b(T[(k4 + 3) * 36 + nl]);
    *(ushort4*)&Ol[(size_t)(n0 + nl) * Kp + k0 + k4] = u;
  }
}

__global__ __launch_bounds__(256) void prep_weights(
    const float* __restrict__ Wp, const float* __restrict__ Wo,
    const float* __restrict__ W1, const float* __restrict__ W2,
    const float* __restrict__ W3, const float* __restrict__ Wf,
    const float* __restrict__ lnw, const float* __restrict__ lnb,
    unsigned short* __restrict__ wpT, unsigned short* __restrict__ woT,
    unsigned short* __restrict__ w1T, unsigned short* __restrict__ w2T,
    unsigned short* __restrict__ w3T, unsigned short* __restrict__ wfT,
    float* __restrict__ cst)
{
  __shared__ float T[32 * 36];
  const int b = blockIdx.x;
  if (b < 192) {
    prep_wt2_body(Wp, wpT, 768, 224, 768, 256, 0, 0, b, 0, T);
  } else if (b < 704) {
    const int f = b - 192;
    prep_wt2_body(Wo, woT, 224, 224, 256, 256, (size_t)224 * 224, (size_t)256 * 256,
                  f % 64, f / 64, T);
  } else if (b < 1984) {
    const int f = b - 704;
    prep_wt2_body(W1, w1T, 224, 600, 256, 640, (size_t)224 * 600, (size_t)640 * 256,
                  f % 160, f / 160, T);
  } else if (b < 5184) {
    const int f = b - 1984;
    prep_wt2_body(W2, w2T, 600, 600, 640, 640, (size_t)600 * 600, (size_t)640 * 640,
                  f % 400, f / 400, T);
  } else if (b < 6464) {
    const int f = b - 5184;
    prep_wt2_body(W3, w3T, 600, 224, 640, 256, (size_t)600 * 224, (size_t)256 * 640,
                  f % 160, f / 160, T);
  } else if (b < 8480) {
    prep_wt2_body(Wf, wfT, 224, 8000, 256, 8064, 0, 0, b - 6464, 0, T);
  } else {
    // lnconst: per-layer Sw, Sw2, Sb, Sb2, Swb
    const int f = b - 8480;             // 512 blocks: g in [0,64), ll in [0,8)
    const int g = f & 63, ll = f >> 6;
    const float* wv = lnw + (size_t)ll * SD + g * 3584;
    const float* bv = lnb + (size_t)ll * SD + g * 3584;
    float s[5] = {0.f, 0.f, 0.f, 0.f, 0.f};
    for (int c = threadIdx.x * 4; c < 3584; c += 1024) {
      float4 w4 = *(const float4*)(wv + c);
      float4 b4 = *(const float4*)(bv + c);
      const float* wf2 = (const float*)&w4;
      const float* bf2 = (const float*)&b4;
#pragma unroll
      for (int e = 0; e < 4; ++e) {
        const float ww = wf2[e], bb = bf2[e];
        s[0] += ww; s[1] += ww * ww; s[2] += bb; s[3] += bb * bb; s[4] += ww * bb;
      }
    }
#pragma unroll
    for (int o2 = 32; o2 > 0; o2 >>= 1)
#pragma unroll
      for (int j = 0; j < 5; ++j) s[j] += __shfl_down(s[j], o2);
    float* red = T;   // reuse
    if ((threadIdx.x & 63) == 0)
#pragma unroll
      for (int j = 0; j < 5; ++j) red[(threadIdx.x >> 6) * 5 + j] = s[j];
    __syncthreads();
    if (threadIdx.x < 5) {
      const float tot = red[threadIdx.x] + red[5 + threadIdx.x] +
                        red[10 + threadIdx.x] + red[15 + threadIdx.x];
      atomicAdd(&cst[ll * 5 + threadIdx.x], tot);
    }
  }
}

// Coalesced-read qkv weight repack (dest pre-zeroed so pads stay 0).
__global__ void prep_wqkv(const float* __restrict__ Wq, const float* __restrict__ Wk,
                          const float* __restrict__ Wv, const float* __restrict__ bq,
                          const float* __restrict__ bk, const float* __restrict__ bv,
                          unsigned short* __restrict__ O, float* __restrict__ bcat)
{
  const int idx = blockIdx.x * 256 + threadIdx.x;
  if (idx < LLl * 8 * 224 * 28) {
    const int kk = idx % 28;
    const int d  = (idx / 28) % 224;
    const int h  = (idx / (28 * 224)) % 8;
    const int ll = idx / (28 * 224 * 8);
    const int col = h * 28 + kk;
    const size_t base = (size_t)ll * (704 * 256);
    O[base + (size_t)col * 256 + d]         = f2b(Wq[idx]);
    O[base + (size_t)(224 + col) * 256 + d] = f2b(Wk[idx]);
    O[base + (size_t)(448 + col) * 256 + d] = f2b(Wv[idx]);
  }
  if (idx < LLl * 8 * 28) {
    const int kk = idx % 28;
    const int h  = (idx / 28) % 8;
    const int ll = idx / (28 * 8);
    const int col = h * 28 + kk;
    bcat[ll * 672 + col]       = bq[idx];
    bcat[ll * 672 + 224 + col] = bk[idx];
    bcat[ll * 672 + 448 + col] = bv[idx];
  }
}

// x -> bf16; block 0 also zeros the stats/cst region (424 floats).
// NOTE: strided loop — blockDim is 256, region is 424 floats. A plain
// `threadIdx.x < 424` guard leaves stats[256..424) un-zeroed, which makes
// the atomicAdd accumulators grow across graph replays (round-10 failure).
__global__ void prep_x(const float* __restrict__ x, unsigned short* __restrict__ xb,
                       float* __restrict__ st)
{
  if (blockIdx.x == 0) {
    for (int i = threadIdx.x; i < 424; i += 256) st[i] = 0.f;
  }
  const size_t i = ((size_t)blockIdx.x * 256 + threadIdx.x) * 4;
  float4 v = *(const float4*)(x + i);
  ushort4 o;
  o.x = f2b(v.x); o.y = f2b(v.y); o.z = f2b(v.z); o.w = f2b(v.w);
  *(ushort4*)(xb + i) = o;
}

// ---------------------------------------------------------------------------
// MFMA flash attention (unchanged).
// ---------------------------------------------------------------------------
__global__ __launch_bounds__(256) void attn_mfma(const unsigned short* __restrict__ qkv,
                                                 unsigned short* __restrict__ o)
{
  const int bh = blockIdx.x;
  const int qt = (int)gridDim.y - 1 - (int)blockIdx.y;
  const int b = bh >> 3, h = bh & 7;
  const int tid = threadIdx.x;
  const int w = tid >> 6, l = tid & 63;
  const int cl = l & 15, g = l >> 4;
  const int qbase = qt * 64 + w * 16;
  const float scale = 0.1889822365046136f;  // 1/sqrt(28)

  __shared__ unsigned short Ks[32 * 40];
  __shared__ unsigned short Vt[32 * 40];
  __shared__ unsigned short Ps[4][16 * 40];

  short8 aq;
  {
    const unsigned short* qp = qkv + ((size_t)(b * SS + qbase + cl)) * 704 + h * 28;
#pragma unroll
    for (int e = 0; e < 8; ++e) {
      const int d = g * 8 + e;
      ((unsigned short*)&aq)[e] = (d < 28) ? qp[d] : (unsigned short)0;
    }
  }

  f32x4 o0 = {0.f, 0.f, 0.f, 0.f}, o1 = {0.f, 0.f, 0.f, 0.f};
  float m[4] = {-INFINITY, -INFINITY, -INFINITY, -INFINITY};
  float lsum[4] = {0.f, 0.f, 0.f, 0.f};

  const int ntiles = qt * 2 + 2;
  const int ntw = ((qbase + 15) >> 5) + 1;

  const int sr = tid >> 3, sc4 = (tid & 7) << 2;
  const bool sact = (sc4 < 28);
  ushort4 ku = make_ushort4(0, 0, 0, 0), vu = make_ushort4(0, 0, 0, 0);
  if (sact) {
    const unsigned short* kp = qkv + ((size_t)(b * SS + sr)) * 704 + 224 + h * 28 + sc4;
    ku = *(const ushort4*)kp;
    vu = *(const ushort4*)(kp + 224);
  }

  for (int tile = 0; tile < ntiles; ++tile) {
    const int t0 = tile * 32;
    __syncthreads();
    *(ushort4*)&Ks[sr * 40 + sc4] = ku;
    Vt[(sc4 + 0) * 40 + sr] = vu.x;
    Vt[(sc4 + 1) * 40 + sr] = vu.y;
    Vt[(sc4 + 2) * 40 + sr] = vu.z;
    Vt[(sc4 + 3) * 40 + sr] = vu.w;
    __syncthreads();
    if (tile + 1 < ntiles && sact) {
      const unsigned short* kp =
          qkv + ((size_t)(b * SS + (tile + 1) * 32 + sr)) * 704 + 224 + h * 28 + sc4;
      ku = *(const ushort4*)kp;
      vu = *(const ushort4*)(kp + 224);
    }
    if (tile >= ntw) continue;

    const short8 bk0 = *(const short8*)&Ks[cl * 40 + g * 8];
    const short8 bk1 = *(const short8*)&Ks[(cl + 16) * 40 + g * 8];
    f32x4 zz = {0.f, 0.f, 0.f, 0.f};
    f32x4 s0 = __builtin_amdgcn_mfma_f32_16x16x32_bf16(aq, bk0, zz, 0, 0, 0);
    f32x4 s1 = __builtin_amdgcn_mfma_f32_16x16x32_bf16(aq, bk1, zz, 0, 0, 0);

    const bool diag = (t0 + 31 > qbase);
#pragma unroll
    for (int jj = 0; jj < 4; ++jj) {
      float v0 = s0[jj] * scale, v1 = s1[jj] * scale;
      if (diag) {
        const int qr = qbase + g * 4 + jj;
        if (t0 + cl > qr)      v0 = -INFINITY;
        if (t0 + 16 + cl > qr) v1 = -INFINITY;
      }
      float rm = fmaxf(v0, v1);
      rm = fmaxf(rm, __shfl_xor(rm, 1));
      rm = fmaxf(rm, __shfl_xor(rm, 2));
      rm = fmaxf(rm, __shfl_xor(rm, 4));
      rm = fmaxf(rm, __shfl_xor(rm, 8));
      const float mnew = fmaxf(m[jj], rm);
      const float r2 = __expf(m[jj] - mnew);
      m[jj] = mnew;
      const float e0 = __expf(v0 - mnew), e1 = __expf(v1 - mnew);
      lsum[jj] = lsum[jj] * r2 + e0 + e1;
      o0[jj] *= r2; o1[jj] *= r2;
      Ps[w][(g * 4 + jj) * 40 + cl]      = f2b(e0);
      Ps[w][(g * 4 + jj) * 40 + cl + 16] = f2b(e1);
    }
    const short8 pa  = *(const short8*)&Ps[w][cl * 40 + g * 8];
    const short8 bv0 = *(const short8*)&Vt[cl * 40 + g * 8];
    const short8 bv1 = *(const short8*)&Vt[(cl + 16) * 40 + g * 8];
    o0 = __builtin_amdgcn_mfma_f32_16x16x32_bf16(pa, bv0, o0, 0, 0, 0);
    o1 = __builtin_amdgcn_mfma_f32_16x16x32_bf16(pa, bv1, o1, 0, 0, 0);
  }

#pragma unroll
  for (int jj = 0; jj < 4; ++jj) {
    float ls = lsum[jj];
    ls += __shfl_xor(ls, 1);
    ls += __shfl_xor(ls, 2);
    ls += __shfl_xor(ls, 4);
    ls += __shfl_xor(ls, 8);
    const float inv = 1.0f / ls;
    const int row = qbase + g * 4 + jj;
    unsigned short* op = o + ((size_t)(b * SS + row)) * 256 + h * 28;
    op[cl] = f2b(o0[jj] * inv);
    if (cl < 12) op[16 + cl] = f2b(o1[jj] * inv);
  }
}

// ---------------------------------------------------------------------------
// Row softmax over V=8000, in place on d_out (fp32), float4 path.
// ---------------------------------------------------------------------------
__global__ __launch_bounds__(256) void softmax_rows(float* __restrict__ logits)
{
  const int row = blockIdx.x;
  float* p = logits + (size_t)row * VV;
  __shared__ float4 buf[VV / 4];
  __shared__ float red[4];
  const int tid = threadIdx.x;

  float mx = -INFINITY;
  for (int i = tid; i < VV / 4; i += 256) {
    float4 v = *(const float4*)(p + i * 4);
    buf[i] = v;
    mx = fmaxf(fmaxf(fmaxf(mx, v.x), fmaxf(v.y, v.z)), v.w);
  }
#pragma unroll
  for (int o2 = 32; o2 > 0; o2 >>= 1) mx = fmaxf(mx, __shfl_down(mx, o2));
  if ((tid & 63) == 0) red[tid >> 6] = mx;
  __syncthreads();
  mx = fmaxf(fmaxf(red[0], red[1]), fmaxf(red[2], red[3]));
  __syncthreads();

  float s = 0.f;
  for (int i = tid; i < VV / 4; i += 256) {
    float4 v = buf[i];
    v.x = __expf(v.x - mx); v.y = __expf(v.y - mx);
    v.z = __expf(v.z - mx); v.w = __expf(v.w - mx);
    buf[i] = v;
    s += v.x + v.y + v.z + v.w;
  }
#pragma unroll
  for (int o2 = 32; o2 > 0; o2 >>= 1) s += __shfl_down(s, o2);
  if ((tid & 63) == 0) red[tid >> 6] = s;
  __syncthreads();
  s = red[0] + red[1] + red[2] + red[3];
  const float inv = 1.0f / s;
  for (int i = tid; i < VV / 4; i += 256) {
    float4 v = buf[i];
    v.x *= inv; v.y *= inv; v.z *= inv; v.w *= inv;
    *(float4*)(p + i * 4) = v;
  }
}

// ---------------------------------------------------------------------------
extern "C" void kernel_launch(void* const* d_in, const int* in_sizes, int n_in,
                              void* d_out, int out_size, void* d_ws, size_t ws_size,
                              hipStream_t stream) {
  const float* x   = (const float*)d_in[0];
  const float* Wp  = (const float*)d_in[1];
  const float* bp  = (const float*)d_in[2];
  const float* Wq  = (const float*)d_in[3];
  const float* bq  = (const float*)d_in[4];
  const float* Wk  = (const float*)d_in[5];
  const float* bk  = (const float*)d_in[6];
  const float* Wv  = (const float*)d_in[7];
  const float* bv  = (const float*)d_in[8];
  const float* Wo  = (const float*)d_in[9];
  const float* bo  = (const float*)d_in[10];
  const float* W1  = (const float*)d_in[11];
  const float* b1  = (const float*)d_in[12];
  const float* W2  = (const float*)d_in[13];
  const float* b2  = (const float*)d_in[14];
  const float* W3  = (const float*)d_in[15];
  const float* b3  = (const float*)d_in[16];
  const float* lnw = (const float*)d_in[17];
  const float* lnb = (const float*)d_in[18];
  const float* Wf  = (const float*)d_in[19];
  const float* bf  = (const float*)d_in[20];

  unsigned short* wsb = (unsigned short*)d_ws;
  unsigned short* wpT   = wsb + WP;
  unsigned short* wqkvT = wsb + WQKV;
  unsigned short* woT   = wsb + WO;
  unsigned short* w1T   = wsb + W1T;
  unsigned short* w2T   = wsb + W2T;
  unsigned short* w3T   = wsb + W3T;
  unsigned short* wfT   = wsb + WFT;
  unsigned short* X     = wsb + HB;    // pre-LN layer state
  unsigned short* h2a   = wsb + H2B;   // attn-block output
  unsigned short* obuf  = wsb + OBUF;
  unsigned short* xb    = wsb + BIG;
  unsigned short* qkvb  = wsb + BIG;
  float* bcat  = (float*)((char*)d_ws + FBYTE);
  float* stats = bcat + LLl * 672;      // 16 slots x 24 floats = 384
  float* cstA  = stats + 384;           // 8 layers x 5 floats = 40

  // ---- prep (3 dispatches + memset) ----
  hipMemsetAsync(wqkvT, 0, (size_t)LLl * 704 * 256 * 2, stream);
  prep_x<<<3072, 256, 0, stream>>>(x, xb, stats);   // block 0 zeros stats+cst (424)
  prep_wqkv<<<1568, 256, 0, stream>>>(Wq, Wk, Wv, bq, bk, bv, wqkvT, bcat);
  prep_weights<<<8992, 256, 0, stream>>>(Wp, Wo, W1, W2, W3, Wf, lnw, lnb,
                                         wpT, woT, w1T, w2T, w3T, wfT, cstA);

  // ---- proj + posenc: X = x @ Wp + bp + pe ----
  gemm_mfma<32, 64, GF_BIAS | GF_POSENC><<<dim3(4, 128), 256, 0, stream>>>(
      xb, wpT, bp, nullptr, X, 768, 224, 256,
      nullptr, nullptr, nullptr, nullptr, nullptr, nullptr, nullptr);

  for (int l = 0; l < LLl; ++l) {
    float* stA = stats + (size_t)(2 * l) * 24;
    float* stB = stats + (size_t)(2 * l + 1) * 24;
    const float* stPrev = stats + (size_t)(2 * l - 1) * 24;   // stB_{l-1}, l>=1
    const float* lnwP = lnw + (size_t)(l - 1) * SD;           // layer l-1 params
    const float* lnbP = lnb + (size_t)(l - 1) * SD;
    const float* cstP = cstA + (l - 1) * 5;
    const float* lnwL = lnw + (size_t)l * SD;
    const float* lnbL = lnb + (size_t)l * SD;

    // 1. qkv = LNLN(X) @ Wqkv + bqkv   (layer 0: plain X)
    if (l == 0) {
      gemm_mfma<64, 64, GF_BIAS><<<dim3(11, 64), 256, 0, stream>>>(
          X, wqkvT, bcat, nullptr, qkvb, 256, 672, 704,
          nullptr, nullptr, nullptr, nullptr, nullptr, nullptr, nullptr);
    } else {
      gemm_mfma<64, 64, GF_BIAS | GF_LNA2><<<dim3(11, 64), 256, 0, stream>>>(
          X, wqkvT + (size_t)l * 704 * 256, bcat + l * 672, nullptr, qkvb, 256, 672, 704,
          lnwP, lnbP, stPrev, cstP, nullptr, nullptr, nullptr);
    }
    // 2. attention
    attn_mfma<<<dim3(BB * 8, SS / 64), 256, 0, stream>>>(qkvb, obuf);
    // 3. h2a = obuf @ Wo + bo + LNLN(X); stat6 -> stA
    if (l == 0) {
      gemm_mfma<32, 64, GF_BIAS | GF_RESID | GF_STAT6><<<dim3(4, 128), 256, 0, stream>>>(
          obuf, woT, bo, X, h2a, 256, 224, 256,
          nullptr, nullptr, nullptr, nullptr, lnwL, lnbL, stA);
    } else {
      gemm_mfma<32, 64, GF_BIAS | GF_RESID | GF_LNRES2 | GF_STAT6>
          <<<dim3(4, 128), 256, 0, stream>>>(
          obuf, woT + (size_t)l * 256 * 256, bo + (size_t)l * 224, X, h2a, 256, 224, 256,
          lnwP, lnbP, stPrev, cstP, lnwL, lnbL, stA);
    }
    // 4. fused FFN: X = relu(relu(LN(h2a)@W1)@W2)@W3 + b3 + LN(h2a); stat6 -> stB
    ffn_fused<<<256, 512, 0, stream>>>(
        h2a, w1T + (size_t)l * 640 * 256, w2T + (size_t)l * 640 * 640,
        w3T + (size_t)l * 256 * 640, b1 + (size_t)l * 600, b2 + (size_t)l * 600,
        b3 + (size_t)l * 224, lnwL, lnbL, stA, stB, X);
  }

  // ---- logits = LNLN(X) @ Wf + bf (fused LN in A-staging), softmax ----
  gemm_mfma<128, 128, GF_BIAS | GF_F32OUT | GF_SWAP | GF_LNA2>
      <<<dim3(32, 63), 256, 0, stream>>>(
      X, wfT, bf, nullptr, (float*)d_out, 256, 8000, 8000,
      lnw + (size_t)7 * SD, lnb + (size_t)7 * SD, stats + (size_t)15 * 24,
      cstA + 7 * 5, nullptr, nullptr, nullptr);
  softmax_rows<<<4096, 256, 0, stream>>>((float*)d_out);
}